// Round 8
// baseline (770.079 us; speedup 1.0000x reference)
//
#include <hip/hip_runtime.h>
#include <math.h>

#define B_GRAPHS 8192
#define OUT_DIM 1024
#define NU 128
#define NS 8
#define IN_DIM 1160          // OUT_DIM + NU + NS
#define KPAD1 1216           // IN_DIM padded to multiple of 64
#define HID 256
#define NSEG (B_GRAPHS * NU)        // 1048576 = 2^20
#define EDGES (B_GRAPHS * OUT_DIM)  // 8388608 = 2^23

// ---- binning parameters ----
#define BINS 2048
#define SEGS_PER_BIN 512
#define HALF (EDGES / 2)            // 4194304 edges per pass
#define BIN_CAP 2432                // mean 2048 + 8.5 sigma; 2048*2432*4B = 19.0MiB
#define SCHUNK 16384                // edges per scatter block

typedef __attribute__((ext_vector_type(8))) short short8;
typedef __attribute__((ext_vector_type(4))) float f32x4;

__device__ __forceinline__ unsigned short f2bf(float f) {
    unsigned u = __float_as_uint(f);
    const unsigned r = (u >> 16) & 1u;
    return (unsigned short)((u + 0x7fffu + r) >> 16);   // RNE
}
__device__ __forceinline__ float bf2f(unsigned short b) {
    return __uint_as_float((unsigned)b << 16);
}

// ================= prep: fp32 -> bf16 conversions ==========================
__global__ __launch_bounds__(256) void convert_feats_kernel(
    const float* __restrict__ u2s, const float* __restrict__ usr,
    const float* __restrict__ srv, unsigned short* __restrict__ F)
{
    const int t = blockIdx.x * 256 + threadIdx.x;   // 8192*152 threads
    const int row = t / 152;
    const int g = t - row * 152;
    const int col = g * 8;
    float v[8];
    if (g < 128) {
        const float4 a = *(const float4*)&u2s[(size_t)row * OUT_DIM + col];
        const float4 b = *(const float4*)&u2s[(size_t)row * OUT_DIM + col + 4];
        v[0]=a.x; v[1]=a.y; v[2]=a.z; v[3]=a.w; v[4]=b.x; v[5]=b.y; v[6]=b.z; v[7]=b.w;
    } else if (g < 144) {
        const int c = col - OUT_DIM;
        const float4 a = *(const float4*)&usr[(size_t)row * NU + c];
        const float4 b = *(const float4*)&usr[(size_t)row * NU + c + 4];
        v[0]=a.x; v[1]=a.y; v[2]=a.z; v[3]=a.w; v[4]=b.x; v[5]=b.y; v[6]=b.z; v[7]=b.w;
    } else if (g == 144) {
        const float4 a = *(const float4*)&srv[(size_t)row * NS];
        const float4 b = *(const float4*)&srv[(size_t)row * NS + 4];
        v[0]=a.x; v[1]=a.y; v[2]=a.z; v[3]=a.w; v[4]=b.x; v[5]=b.y; v[6]=b.z; v[7]=b.w;
    } else {
        for (int i = 0; i < 8; ++i) v[i] = 0.f;
    }
    unsigned short o[8];
    for (int i = 0; i < 8; ++i) o[i] = f2bf(v[i]);
    *reinterpret_cast<short8*>(&F[(size_t)row * KPAD1 + col]) =
        *reinterpret_cast<const short8*>(o);
}

__global__ __launch_bounds__(256) void convert_wT_kernel(
    const float* __restrict__ W, unsigned short* __restrict__ WT,
    int K, int N, int Kpad)
{
    const int t = blockIdx.x * 256 + threadIdx.x;
    if (t >= N * Kpad) return;
    const int n = t / Kpad;
    const int k = t - n * Kpad;
    WT[t] = (k < K) ? f2bf(W[(size_t)k * N + n]) : (unsigned short)0;
}

// ================= bf16 MFMA GEMM (r5-proven) ==============================
template <int EPI>
__global__ __launch_bounds__(256) void gemm_bf16_kernel(
    const unsigned short* __restrict__ A, const unsigned short* __restrict__ BT,
    const float* __restrict__ bias, void* __restrict__ outv, int N, int K)
{
    __shared__ unsigned short As[128 * 64];
    __shared__ unsigned short Bs[64 * 64];

    const int tid = threadIdx.x;
    const int lane = tid & 63;
    const int wid = tid >> 6;
    const int wm = wid >> 1;
    const int wn = wid & 1;
    const int m0 = blockIdx.y * 128;
    const int n0 = blockIdx.x * 64;

    const int srow = lane >> 3;
    const int schunk = lane & 7;
    const int sswz = schunk ^ srow;

    f32x4 acc[4][2];
#pragma unroll
    for (int i = 0; i < 4; ++i)
#pragma unroll
        for (int j = 0; j < 2; ++j) acc[i][j] = (f32x4)0.f;

    for (int k0 = 0; k0 < K; k0 += 64) {
#pragma unroll
        for (int i = 0; i < 4; ++i) {
            const int r = wid * 32 + i * 8 + srow;
            const short8 v = *reinterpret_cast<const short8*>(
                &A[(size_t)(m0 + r) * K + k0 + sswz * 8]);
            *reinterpret_cast<short8*>(&As[r * 64 + schunk * 8]) = v;
        }
#pragma unroll
        for (int i = 0; i < 2; ++i) {
            const int r = wid * 16 + i * 8 + srow;
            const short8 v = *reinterpret_cast<const short8*>(
                &BT[(size_t)(n0 + r) * K + k0 + sswz * 8]);
            *reinterpret_cast<short8*>(&Bs[r * 64 + schunk * 8]) = v;
        }
        __syncthreads();

#pragma unroll
        for (int ks = 0; ks < 2; ++ks) {
            short8 af[4], bf[2];
            const int c = ks * 4 + (lane >> 4);
#pragma unroll
            for (int fm = 0; fm < 4; ++fm) {
                const int r = wm * 64 + fm * 16 + (lane & 15);
                af[fm] = *reinterpret_cast<const short8*>(
                    &As[r * 64 + (c ^ (r & 7)) * 8]);
            }
#pragma unroll
            for (int fn = 0; fn < 2; ++fn) {
                const int r = wn * 32 + fn * 16 + (lane & 15);
                bf[fn] = *reinterpret_cast<const short8*>(
                    &Bs[r * 64 + (c ^ (r & 7)) * 8]);
            }
#pragma unroll
            for (int fm = 0; fm < 4; ++fm)
#pragma unroll
                for (int fn = 0; fn < 2; ++fn)
                    acc[fm][fn] = __builtin_amdgcn_mfma_f32_16x16x32_bf16(
                        af[fm], bf[fn], acc[fm][fn], 0, 0, 0);
        }
        __syncthreads();
    }

    // C/D layout: col = lane&15, row = (lane>>4)*4 + reg
#pragma unroll
    for (int fn = 0; fn < 2; ++fn) {
        const int col = n0 + wn * 32 + fn * 16 + (lane & 15);
        const float bv = bias[col];
#pragma unroll
        for (int fm = 0; fm < 4; ++fm) {
            const int rbase = m0 + wm * 64 + fm * 16 + (lane >> 4) * 4;
#pragma unroll
            for (int e = 0; e < 4; ++e) {
                const float v = acc[fm][fn][e] + bv;
                if (EPI == 0) {
                    unsigned short* h = (unsigned short*)outv;
                    h[(size_t)(rbase + e) * N + col] = f2bf(fmaxf(v, 0.f));
                } else {
                    float* out = (float*)outv;
                    const int p = col >> 10;
                    const int w = col & 1023;
                    out[(size_t)p * EDGES + (size_t)(rbase + e) * OUT_DIM + w] =
                        __expf(v);
                }
            }
        }
    }
}

// ======= scatter: value-carrying u32 record = seg_low(9) << 16 | bf16(e) ===
__global__ __launch_bounds__(256) void scatter_val_kernel(
    const int* __restrict__ idx, const float* __restrict__ vals, int w0,
    unsigned* __restrict__ P, unsigned* __restrict__ cursor)
{
    __shared__ unsigned hist[BINS];
    __shared__ unsigned offs[BINS];
    const int tid = threadIdx.x;
    const int base = w0 + blockIdx.x * SCHUNK;

    for (int b = tid; b < BINS; b += 256) { hist[b] = 0; offs[b] = 0; }
    __syncthreads();

#pragma unroll 4
    for (int i = 0; i < SCHUNK / 256; ++i) {
        const int seg = idx[base + i * 256 + tid];
        atomicAdd(&hist[seg >> 9], 1u);
    }
    __syncthreads();

    for (int b = tid; b < BINS; b += 256)
        hist[b] = atomicAdd(&cursor[b], hist[b]);   // reserve; hist := base
    __syncthreads();

#pragma unroll 4
    for (int i = 0; i < SCHUNK / 256; ++i) {
        const int w = base + i * 256 + tid;
        const int seg = idx[w];                      // second read: L2 hit
        const int b = seg >> 9;
        const float e = vals[w];                     // coalesced
        const unsigned o = atomicAdd(&offs[b], 1u);
        const unsigned pos = hist[b] + o;
        if (pos < BIN_CAP)                           // overflow guard
            P[(size_t)b * BIN_CAP + pos] =
                ((unsigned)(seg & 511) << 16) | f2bf(e);
    }
}

// ======= per-bin reduce: coalesced records + LDS only; no random access ====
// mode 0: s_self = sub (first half)
// mode 1: s_self += sub (section-0 final sum)
// mode 2: r01 = pack(bf16(1/s_other), bf16(1/(sub+s_self)))   (section 1 last)
// mode 3: r2  = bf16(1/(sub+s_self))                          (section 2 last)
__global__ __launch_bounds__(256) void reduce_val_kernel(
    const unsigned* __restrict__ P, const unsigned* __restrict__ cursor,
    float* __restrict__ s_self, const float* __restrict__ s_other,
    unsigned* __restrict__ r01, unsigned short* __restrict__ r2, int mode)
{
    __shared__ float sub[SEGS_PER_BIN];
    const int b = blockIdx.x;
    const int tid = threadIdx.x;
    for (int i = tid; i < SEGS_PER_BIN; i += 256) sub[i] = 0.f;
    __syncthreads();

    const int cnt = min((int)cursor[b], BIN_CAP);
    const unsigned* rec = &P[(size_t)b * BIN_CAP];
    for (int i = tid; i < cnt; i += 256) {
        const unsigned r = rec[i];
        atomicAdd(&sub[r >> 16], __uint_as_float(r << 16));
    }
    __syncthreads();

    for (int i = tid; i < SEGS_PER_BIN; i += 256) {
        const int seg = b * SEGS_PER_BIN + i;
        if (mode == 0) {
            s_self[seg] = sub[i];
        } else if (mode == 1) {
            s_self[seg] += sub[i];
        } else if (mode == 2) {
            const float s1f = sub[i] + s_self[seg];
            r01[seg] = ((unsigned)f2bf(1.f / s_other[seg]) << 16) |
                       f2bf(1.f / s1f);
        } else {
            r2[seg] = f2bf(1.f / (sub[i] + s_self[seg]));
        }
    }
}

// ============ normalize, split per table for L2 residency ==================
__global__ __launch_bounds__(256) void segdiv01_kernel(
    float* __restrict__ vals, const int* __restrict__ idx0,
    const unsigned* __restrict__ r01)
{
    const int w4 = (blockIdx.x * 256 + threadIdx.x) * 4;
    if (w4 >= EDGES) return;
    const int4 iv = *reinterpret_cast<const int4*>(&idx0[w4]);
    const int idx[4] = {iv.x, iv.y, iv.z, iv.w};
    float4 a = *reinterpret_cast<const float4*>(&vals[w4]);
    float4 b = *reinterpret_cast<const float4*>(&vals[(size_t)EDGES + w4]);
    float r0[4], r1[4];
#pragma unroll
    for (int j = 0; j < 4; ++j) {
        const unsigned p = r01[idx[j]];
        r0[j] = __uint_as_float(p & 0xffff0000u);
        r1[j] = __uint_as_float(p << 16);
    }
    a.x *= r0[0]; a.y *= r0[1]; a.z *= r0[2]; a.w *= r0[3];
    b.x *= r1[0]; b.y *= r1[1]; b.z *= r1[2]; b.w *= r1[3];
    *reinterpret_cast<float4*>(&vals[w4]) = a;
    *reinterpret_cast<float4*>(&vals[(size_t)EDGES + w4]) = b;
}

__global__ __launch_bounds__(256) void segdiv2_kernel(
    float* __restrict__ vals, const int* __restrict__ idx1,
    const unsigned short* __restrict__ r2)
{
    const int w4 = (blockIdx.x * 256 + threadIdx.x) * 4;
    if (w4 >= EDGES) return;
    const int4 iv = *reinterpret_cast<const int4*>(&idx1[w4]);
    const int idx[4] = {iv.x, iv.y, iv.z, iv.w};
    float4 c = *reinterpret_cast<const float4*>(&vals[2 * (size_t)EDGES + w4]);
    c.x *= bf2f(r2[idx[0]]);
    c.y *= bf2f(r2[idx[1]]);
    c.z *= bf2f(r2[idx[2]]);
    c.w *= bf2f(r2[idx[3]]);
    *reinterpret_cast<float4*>(&vals[2 * (size_t)EDGES + w4]) = c;
}

// ===========================================================================
extern "C" void kernel_launch(void* const* d_in, const int* in_sizes, int n_in,
                              void* d_out, int out_size, void* d_ws,
                              size_t ws_size, hipStream_t stream) {
    const float* u2s = (const float*)d_in[0];
    const float* usr = (const float*)d_in[1];
    const float* srv = (const float*)d_in[2];
    const int* edge = (const int*)d_in[3];
    const float* W1 = (const float*)d_in[4];
    const float* b1 = (const float*)d_in[5];
    const float* W2 = (const float*)d_in[6];
    const float* b2 = (const float*)d_in[7];
    const float* W3 = (const float*)d_in[8];
    const float* b3 = (const float*)d_in[9];
    const float* W4 = (const float*)d_in[10];
    const float* b4 = (const float*)d_in[11];

    const int* idx0 = edge;
    const int* idx1 = edge + EDGES;

    // ws layout (peak 38 MiB; ws >= 38 MiB proven in r5):
    //  phase1: F [0,19.9) | h1 [20,24) | h2 [24,28) | h3 [28,32) | wT [32,34.4)
    //  phase2: P [0,19.0) | cursor @19.5 | s0 [20,24) | s1 [24,28) | s2 [28,32)
    //          r01 [32,36) | r2 [36,38)
    //  (every phase2 write happens after its phase1 occupant is dead)
    char* ws = (char*)d_ws;
    unsigned short* F = (unsigned short*)ws;
    unsigned short* h1 = (unsigned short*)(ws + 20ull * 1024 * 1024);
    unsigned short* h2 = (unsigned short*)(ws + 24ull * 1024 * 1024);
    unsigned short* h3 = (unsigned short*)(ws + 28ull * 1024 * 1024);
    unsigned short* w1t = (unsigned short*)(ws + 32ull * 1024 * 1024);
    unsigned short* w2t = w1t + (size_t)HID * KPAD1;
    unsigned short* w3t = w2t + (size_t)HID * HID;
    unsigned short* w4t = w3t + (size_t)HID * HID;

    unsigned* P = (unsigned*)ws;
    unsigned* cursor = (unsigned*)(ws + 19968ull * 1024);   // 19.5 MiB
    float* s0 = (float*)(ws + 20ull * 1024 * 1024);
    float* s1 = (float*)(ws + 24ull * 1024 * 1024);
    float* s2 = (float*)(ws + 28ull * 1024 * 1024);
    unsigned* r01 = (unsigned*)(ws + 32ull * 1024 * 1024);
    unsigned short* r2 = (unsigned short*)(ws + 36ull * 1024 * 1024);

    float* outp = (float*)d_out;
    const dim3 blk(256);

    // ---- prep: conversions ----
    convert_feats_kernel<<<(B_GRAPHS * 152) / 256, blk, 0, stream>>>(u2s, usr,
                                                                     srv, F);
    convert_wT_kernel<<<(HID * KPAD1 + 255) / 256, blk, 0, stream>>>(
        W1, w1t, IN_DIM, HID, KPAD1);
    convert_wT_kernel<<<(HID * HID + 255) / 256, blk, 0, stream>>>(
        W2, w2t, HID, HID, HID);
    convert_wT_kernel<<<(HID * HID + 255) / 256, blk, 0, stream>>>(
        W3, w3t, HID, HID, HID);
    convert_wT_kernel<<<(3 * OUT_DIM * HID + 255) / 256, blk, 0, stream>>>(
        W4, w4t, HID, 3 * OUT_DIM, HID);

    // ---- MLP (bf16 MFMA) ----
    gemm_bf16_kernel<0><<<dim3(HID / 64, B_GRAPHS / 128), blk, 0, stream>>>(
        F, w1t, b1, h1, HID, KPAD1);
    gemm_bf16_kernel<0><<<dim3(HID / 64, B_GRAPHS / 128), blk, 0, stream>>>(
        h1, w2t, b2, h2, HID, HID);
    gemm_bf16_kernel<0><<<dim3(HID / 64, B_GRAPHS / 128), blk, 0, stream>>>(
        h2, w3t, b3, h3, HID, HID);
    gemm_bf16_kernel<1><<<dim3(3 * OUT_DIM / 64, B_GRAPHS / 128), blk, 0,
                          stream>>>(h3, w4t, b4, outp, 3 * OUT_DIM, HID);

    // ---- segment sums: per-section value-carrying scatter + LDS reduce ----
    // section 0 (idx0)
    for (int h = 0; h < 2; ++h) {
        hipMemsetAsync(cursor, 0, BINS * sizeof(unsigned), stream);
        scatter_val_kernel<<<HALF / SCHUNK, blk, 0, stream>>>(
            idx0, outp, h * HALF, P, cursor);
        reduce_val_kernel<<<BINS, blk, 0, stream>>>(P, cursor, s0, nullptr,
                                                    nullptr, nullptr, h);
    }
    // section 1 (idx0); last pass packs r01 from s0 (final) and s1
    for (int h = 0; h < 2; ++h) {
        hipMemsetAsync(cursor, 0, BINS * sizeof(unsigned), stream);
        scatter_val_kernel<<<HALF / SCHUNK, blk, 0, stream>>>(
            idx0, outp + (size_t)EDGES, h * HALF, P, cursor);
        reduce_val_kernel<<<BINS, blk, 0, stream>>>(P, cursor, s1, s0, r01,
                                                    nullptr, h == 0 ? 0 : 2);
    }
    // section 2 (idx1); last pass writes r2
    for (int h = 0; h < 2; ++h) {
        hipMemsetAsync(cursor, 0, BINS * sizeof(unsigned), stream);
        scatter_val_kernel<<<HALF / SCHUNK, blk, 0, stream>>>(
            idx1, outp + 2 * (size_t)EDGES, h * HALF, P, cursor);
        reduce_val_kernel<<<BINS, blk, 0, stream>>>(P, cursor, s2, nullptr,
                                                    nullptr, r2, h == 0 ? 0 : 3);
    }

    // ---- normalize (split so each pass's random table fits one L2) ----
    segdiv01_kernel<<<EDGES / 1024, blk, 0, stream>>>(outp, idx0, r01);
    segdiv2_kernel<<<EDGES / 1024, blk, 0, stream>>>(outp, idx1, r2);
}

// Round 9
// 666.993 us; speedup vs baseline: 1.1546x; 1.1546x over previous
//
#include <hip/hip_runtime.h>
#include <math.h>

#define B_GRAPHS 8192
#define OUT_DIM 1024
#define NU 128
#define NS 8
#define IN_DIM 1160          // OUT_DIM + NU + NS
#define KPAD1 1216           // IN_DIM padded to multiple of 64
#define HID 256
#define NSEG (B_GRAPHS * NU)        // 1048576 = 2^20
#define EDGES (B_GRAPHS * OUT_DIM)  // 8388608 = 2^23

// ---- binning parameters ----
#define BINS 512                    // seg >> 11
#define SEGS_PER_BIN 2048
#define HALF (EDGES / 2)            // 4194304 edges per pass
#define BIN_CAP 8928                // mean 8192 + ~8 sigma; 512*8928*4B = 17.4MiB
#define SCHUNK 8192                 // edges per scatter block -> 512 blocks/pass

typedef __attribute__((ext_vector_type(8))) short short8;
typedef __attribute__((ext_vector_type(4))) float f32x4;

__device__ __forceinline__ unsigned short f2bf(float f) {
    unsigned u = __float_as_uint(f);
    const unsigned r = (u >> 16) & 1u;
    return (unsigned short)((u + 0x7fffu + r) >> 16);   // RNE
}
__device__ __forceinline__ float bf2f(unsigned short b) {
    return __uint_as_float((unsigned)b << 16);
}

// ================= prep: fp32 -> bf16 conversions ==========================
__global__ __launch_bounds__(256) void convert_feats_kernel(
    const float* __restrict__ u2s, const float* __restrict__ usr,
    const float* __restrict__ srv, unsigned short* __restrict__ F)
{
    const int t = blockIdx.x * 256 + threadIdx.x;   // 8192*152 threads
    const int row = t / 152;
    const int g = t - row * 152;
    const int col = g * 8;
    float v[8];
    if (g < 128) {
        const float4 a = *(const float4*)&u2s[(size_t)row * OUT_DIM + col];
        const float4 b = *(const float4*)&u2s[(size_t)row * OUT_DIM + col + 4];
        v[0]=a.x; v[1]=a.y; v[2]=a.z; v[3]=a.w; v[4]=b.x; v[5]=b.y; v[6]=b.z; v[7]=b.w;
    } else if (g < 144) {
        const int c = col - OUT_DIM;
        const float4 a = *(const float4*)&usr[(size_t)row * NU + c];
        const float4 b = *(const float4*)&usr[(size_t)row * NU + c + 4];
        v[0]=a.x; v[1]=a.y; v[2]=a.z; v[3]=a.w; v[4]=b.x; v[5]=b.y; v[6]=b.z; v[7]=b.w;
    } else if (g == 144) {
        const float4 a = *(const float4*)&srv[(size_t)row * NS];
        const float4 b = *(const float4*)&srv[(size_t)row * NS + 4];
        v[0]=a.x; v[1]=a.y; v[2]=a.z; v[3]=a.w; v[4]=b.x; v[5]=b.y; v[6]=b.z; v[7]=b.w;
    } else {
        for (int i = 0; i < 8; ++i) v[i] = 0.f;
    }
    unsigned short o[8];
    for (int i = 0; i < 8; ++i) o[i] = f2bf(v[i]);
    *reinterpret_cast<short8*>(&F[(size_t)row * KPAD1 + col]) =
        *reinterpret_cast<const short8*>(o);
}

__global__ __launch_bounds__(256) void convert_wT_kernel(
    const float* __restrict__ W, unsigned short* __restrict__ WT,
    int K, int N, int Kpad)
{
    const int t = blockIdx.x * 256 + threadIdx.x;
    if (t >= N * Kpad) return;
    const int n = t / Kpad;
    const int k = t - n * Kpad;
    WT[t] = (k < K) ? f2bf(W[(size_t)k * N + n]) : (unsigned short)0;
}

// ================= bf16 MFMA GEMM (r5-proven) ==============================
template <int EPI>
__global__ __launch_bounds__(256) void gemm_bf16_kernel(
    const unsigned short* __restrict__ A, const unsigned short* __restrict__ BT,
    const float* __restrict__ bias, void* __restrict__ outv, int N, int K)
{
    __shared__ unsigned short As[128 * 64];
    __shared__ unsigned short Bs[64 * 64];

    const int tid = threadIdx.x;
    const int lane = tid & 63;
    const int wid = tid >> 6;
    const int wm = wid >> 1;
    const int wn = wid & 1;
    const int m0 = blockIdx.y * 128;
    const int n0 = blockIdx.x * 64;

    const int srow = lane >> 3;
    const int schunk = lane & 7;
    const int sswz = schunk ^ srow;

    f32x4 acc[4][2];
#pragma unroll
    for (int i = 0; i < 4; ++i)
#pragma unroll
        for (int j = 0; j < 2; ++j) acc[i][j] = (f32x4)0.f;

    for (int k0 = 0; k0 < K; k0 += 64) {
#pragma unroll
        for (int i = 0; i < 4; ++i) {
            const int r = wid * 32 + i * 8 + srow;
            const short8 v = *reinterpret_cast<const short8*>(
                &A[(size_t)(m0 + r) * K + k0 + sswz * 8]);
            *reinterpret_cast<short8*>(&As[r * 64 + schunk * 8]) = v;
        }
#pragma unroll
        for (int i = 0; i < 2; ++i) {
            const int r = wid * 16 + i * 8 + srow;
            const short8 v = *reinterpret_cast<const short8*>(
                &BT[(size_t)(n0 + r) * K + k0 + sswz * 8]);
            *reinterpret_cast<short8*>(&Bs[r * 64 + schunk * 8]) = v;
        }
        __syncthreads();

#pragma unroll
        for (int ks = 0; ks < 2; ++ks) {
            short8 af[4], bf[2];
            const int c = ks * 4 + (lane >> 4);
#pragma unroll
            for (int fm = 0; fm < 4; ++fm) {
                const int r = wm * 64 + fm * 16 + (lane & 15);
                af[fm] = *reinterpret_cast<const short8*>(
                    &As[r * 64 + (c ^ (r & 7)) * 8]);
            }
#pragma unroll
            for (int fn = 0; fn < 2; ++fn) {
                const int r = wn * 32 + fn * 16 + (lane & 15);
                bf[fn] = *reinterpret_cast<const short8*>(
                    &Bs[r * 64 + (c ^ (r & 7)) * 8]);
            }
#pragma unroll
            for (int fm = 0; fm < 4; ++fm)
#pragma unroll
                for (int fn = 0; fn < 2; ++fn)
                    acc[fm][fn] = __builtin_amdgcn_mfma_f32_16x16x32_bf16(
                        af[fm], bf[fn], acc[fm][fn], 0, 0, 0);
        }
        __syncthreads();
    }

    // C/D layout: col = lane&15, row = (lane>>4)*4 + reg
#pragma unroll
    for (int fn = 0; fn < 2; ++fn) {
        const int col = n0 + wn * 32 + fn * 16 + (lane & 15);
        const float bv = bias[col];
#pragma unroll
        for (int fm = 0; fm < 4; ++fm) {
            const int rbase = m0 + wm * 64 + fm * 16 + (lane >> 4) * 4;
#pragma unroll
            for (int e = 0; e < 4; ++e) {
                const float v = acc[fm][fn][e] + bv;
                if (EPI == 0) {
                    unsigned short* h = (unsigned short*)outv;
                    h[(size_t)(rbase + e) * N + col] = f2bf(fmaxf(v, 0.f));
                } else {
                    float* out = (float*)outv;
                    const int p = col >> 10;
                    const int w = col & 1023;
                    out[(size_t)p * EDGES + (size_t)(rbase + e) * OUT_DIM + w] =
                        __expf(v);
                }
            }
        }
    }
}

// ======= scatter: value-carrying u32 record = seg_low(11) << 16 | bf16(e) ==
__global__ __launch_bounds__(256) void scatter_val_kernel(
    const int* __restrict__ idx, const float* __restrict__ vals, int w0,
    unsigned* __restrict__ P, unsigned* __restrict__ cursor)
{
    __shared__ unsigned hist[BINS];
    __shared__ unsigned offs[BINS];
    const int tid = threadIdx.x;
    const int base = w0 + blockIdx.x * SCHUNK;

    for (int b = tid; b < BINS; b += 256) { hist[b] = 0; offs[b] = 0; }
    __syncthreads();

#pragma unroll 4
    for (int i = 0; i < SCHUNK / 256; ++i) {
        const int seg = idx[base + i * 256 + tid];
        atomicAdd(&hist[seg >> 11], 1u);
    }
    __syncthreads();

    for (int b = tid; b < BINS; b += 256)
        hist[b] = atomicAdd(&cursor[b], hist[b]);   // reserve; hist := base
    __syncthreads();

#pragma unroll 4
    for (int i = 0; i < SCHUNK / 256; ++i) {
        const int w = base + i * 256 + tid;
        const int seg = idx[w];                      // second read: L2 hit
        const int b = seg >> 11;
        const float e = vals[w];                     // coalesced
        const unsigned o = atomicAdd(&offs[b], 1u);
        const unsigned pos = hist[b] + o;
        if (pos < BIN_CAP)                           // overflow guard
            P[(size_t)b * BIN_CAP + pos] =
                ((unsigned)(seg & 2047) << 16) | f2bf(e);
    }
}

// ======= per-bin reduce: coalesced records + LDS only; no random access ====
// mode 0: s_self = sub (first half)
// mode 1: s_self += sub (section-0 final sum)
// mode 2: r01 = pack(bf16(1/s_other), bf16(1/(sub+s_self)))   (section 1 last)
// mode 3: r2  = bf16(1/(sub+s_self))                          (section 2 last)
__global__ __launch_bounds__(256) void reduce_val_kernel(
    const unsigned* __restrict__ P, const unsigned* __restrict__ cursor,
    float* __restrict__ s_self, const float* __restrict__ s_other,
    unsigned* __restrict__ r01, unsigned short* __restrict__ r2, int mode)
{
    __shared__ float sub[SEGS_PER_BIN];
    const int b = blockIdx.x;
    const int tid = threadIdx.x;
    for (int i = tid; i < SEGS_PER_BIN; i += 256) sub[i] = 0.f;
    __syncthreads();

    const int cnt = min((int)cursor[b], BIN_CAP);
    const unsigned* rec = &P[(size_t)b * BIN_CAP];
    for (int i = tid; i < cnt; i += 256) {
        const unsigned r = rec[i];
        atomicAdd(&sub[r >> 16], __uint_as_float(r << 16));
    }
    __syncthreads();

    for (int i = tid; i < SEGS_PER_BIN; i += 256) {
        const int seg = b * SEGS_PER_BIN + i;
        if (mode == 0) {
            s_self[seg] = sub[i];
        } else if (mode == 1) {
            s_self[seg] += sub[i];
        } else if (mode == 2) {
            const float s1f = sub[i] + s_self[seg];
            r01[seg] = ((unsigned)f2bf(1.f / s_other[seg]) << 16) |
                       f2bf(1.f / s1f);
        } else {
            r2[seg] = f2bf(1.f / (sub[i] + s_self[seg]));
        }
    }
}

// ============ normalize, split per table for L2 residency ==================
__global__ __launch_bounds__(256) void segdiv01_kernel(
    float* __restrict__ vals, const int* __restrict__ idx0,
    const unsigned* __restrict__ r01)
{
    const int w4 = (blockIdx.x * 256 + threadIdx.x) * 4;
    if (w4 >= EDGES) return;
    const int4 iv = *reinterpret_cast<const int4*>(&idx0[w4]);
    const int idx[4] = {iv.x, iv.y, iv.z, iv.w};
    float4 a = *reinterpret_cast<const float4*>(&vals[w4]);
    float4 b = *reinterpret_cast<const float4*>(&vals[(size_t)EDGES + w4]);
    float r0[4], r1[4];
#pragma unroll
    for (int j = 0; j < 4; ++j) {
        const unsigned p = r01[idx[j]];
        r0[j] = __uint_as_float(p & 0xffff0000u);
        r1[j] = __uint_as_float(p << 16);
    }
    a.x *= r0[0]; a.y *= r0[1]; a.z *= r0[2]; a.w *= r0[3];
    b.x *= r1[0]; b.y *= r1[1]; b.z *= r1[2]; b.w *= r1[3];
    *reinterpret_cast<float4*>(&vals[w4]) = a;
    *reinterpret_cast<float4*>(&vals[(size_t)EDGES + w4]) = b;
}

__global__ __launch_bounds__(256) void segdiv2_kernel(
    float* __restrict__ vals, const int* __restrict__ idx1,
    const unsigned short* __restrict__ r2)
{
    const int w4 = (blockIdx.x * 256 + threadIdx.x) * 4;
    if (w4 >= EDGES) return;
    const int4 iv = *reinterpret_cast<const int4*>(&idx1[w4]);
    const int idx[4] = {iv.x, iv.y, iv.z, iv.w};
    float4 c = *reinterpret_cast<const float4*>(&vals[2 * (size_t)EDGES + w4]);
    c.x *= bf2f(r2[idx[0]]);
    c.y *= bf2f(r2[idx[1]]);
    c.z *= bf2f(r2[idx[2]]);
    c.w *= bf2f(r2[idx[3]]);
    *reinterpret_cast<float4*>(&vals[2 * (size_t)EDGES + w4]) = c;
}

// ===========================================================================
extern "C" void kernel_launch(void* const* d_in, const int* in_sizes, int n_in,
                              void* d_out, int out_size, void* d_ws,
                              size_t ws_size, hipStream_t stream) {
    const float* u2s = (const float*)d_in[0];
    const float* usr = (const float*)d_in[1];
    const float* srv = (const float*)d_in[2];
    const int* edge = (const int*)d_in[3];
    const float* W1 = (const float*)d_in[4];
    const float* b1 = (const float*)d_in[5];
    const float* W2 = (const float*)d_in[6];
    const float* b2 = (const float*)d_in[7];
    const float* W3 = (const float*)d_in[8];
    const float* b3 = (const float*)d_in[9];
    const float* W4 = (const float*)d_in[10];
    const float* b4 = (const float*)d_in[11];

    const int* idx0 = edge;
    const int* idx1 = edge + EDGES;

    // ws layout (peak 38 MiB; proven available):
    //  phase1: F [0,19.9) | h1 [20,24) | h2 [24,28) | h3 [28,32) | wT [32,34.4)
    //  phase2: P [0,17.4) | cursor @19.5 | s0 [20,24) | s1 [24,28) | s2 [28,32)
    //          r01 [32,36) | r2 [36,38)
    char* ws = (char*)d_ws;
    unsigned short* F = (unsigned short*)ws;
    unsigned short* h1 = (unsigned short*)(ws + 20ull * 1024 * 1024);
    unsigned short* h2 = (unsigned short*)(ws + 24ull * 1024 * 1024);
    unsigned short* h3 = (unsigned short*)(ws + 28ull * 1024 * 1024);
    unsigned short* w1t = (unsigned short*)(ws + 32ull * 1024 * 1024);
    unsigned short* w2t = w1t + (size_t)HID * KPAD1;
    unsigned short* w3t = w2t + (size_t)HID * HID;
    unsigned short* w4t = w3t + (size_t)HID * HID;

    unsigned* P = (unsigned*)ws;
    unsigned* cursor = (unsigned*)(ws + 19968ull * 1024);   // 19.5 MiB
    float* s0 = (float*)(ws + 20ull * 1024 * 1024);
    float* s1 = (float*)(ws + 24ull * 1024 * 1024);
    float* s2 = (float*)(ws + 28ull * 1024 * 1024);
    unsigned* r01 = (unsigned*)(ws + 32ull * 1024 * 1024);
    unsigned short* r2 = (unsigned short*)(ws + 36ull * 1024 * 1024);

    float* outp = (float*)d_out;
    const dim3 blk(256);

    // ---- prep: conversions ----
    convert_feats_kernel<<<(B_GRAPHS * 152) / 256, blk, 0, stream>>>(u2s, usr,
                                                                     srv, F);
    convert_wT_kernel<<<(HID * KPAD1 + 255) / 256, blk, 0, stream>>>(
        W1, w1t, IN_DIM, HID, KPAD1);
    convert_wT_kernel<<<(HID * HID + 255) / 256, blk, 0, stream>>>(
        W2, w2t, HID, HID, HID);
    convert_wT_kernel<<<(HID * HID + 255) / 256, blk, 0, stream>>>(
        W3, w3t, HID, HID, HID);
    convert_wT_kernel<<<(3 * OUT_DIM * HID + 255) / 256, blk, 0, stream>>>(
        W4, w4t, HID, 3 * OUT_DIM, HID);

    // ---- MLP (bf16 MFMA) ----
    gemm_bf16_kernel<0><<<dim3(HID / 64, B_GRAPHS / 128), blk, 0, stream>>>(
        F, w1t, b1, h1, HID, KPAD1);
    gemm_bf16_kernel<0><<<dim3(HID / 64, B_GRAPHS / 128), blk, 0, stream>>>(
        h1, w2t, b2, h2, HID, HID);
    gemm_bf16_kernel<0><<<dim3(HID / 64, B_GRAPHS / 128), blk, 0, stream>>>(
        h2, w3t, b3, h3, HID, HID);
    gemm_bf16_kernel<1><<<dim3(3 * OUT_DIM / 64, B_GRAPHS / 128), blk, 0,
                          stream>>>(h3, w4t, b4, outp, 3 * OUT_DIM, HID);

    // ---- segment sums: per-section value-carrying scatter + LDS reduce ----
    // section 0 (idx0)
    for (int h = 0; h < 2; ++h) {
        hipMemsetAsync(cursor, 0, BINS * sizeof(unsigned), stream);
        scatter_val_kernel<<<HALF / SCHUNK, blk, 0, stream>>>(
            idx0, outp, h * HALF, P, cursor);
        reduce_val_kernel<<<BINS, blk, 0, stream>>>(P, cursor, s0, nullptr,
                                                    nullptr, nullptr, h);
    }
    // section 1 (idx0); last pass packs r01 from s0 (final) and s1
    for (int h = 0; h < 2; ++h) {
        hipMemsetAsync(cursor, 0, BINS * sizeof(unsigned), stream);
        scatter_val_kernel<<<HALF / SCHUNK, blk, 0, stream>>>(
            idx0, outp + (size_t)EDGES, h * HALF, P, cursor);
        reduce_val_kernel<<<BINS, blk, 0, stream>>>(P, cursor, s1, s0, r01,
                                                    nullptr, h == 0 ? 0 : 2);
    }
    // section 2 (idx1); last pass writes r2
    for (int h = 0; h < 2; ++h) {
        hipMemsetAsync(cursor, 0, BINS * sizeof(unsigned), stream);
        scatter_val_kernel<<<HALF / SCHUNK, blk, 0, stream>>>(
            idx1, outp + 2 * (size_t)EDGES, h * HALF, P, cursor);
        reduce_val_kernel<<<BINS, blk, 0, stream>>>(P, cursor, s2, nullptr,
                                                    nullptr, r2, h == 0 ? 0 : 3);
    }

    // ---- normalize (split so each pass's random table fits one L2) ----
    segdiv01_kernel<<<EDGES / 1024, blk, 0, stream>>>(outp, idx0, r01);
    segdiv2_kernel<<<EDGES / 1024, blk, 0, stream>>>(outp, idx1, r2);
}

// Round 10
// 476.045 us; speedup vs baseline: 1.6177x; 1.4011x over previous
//
#include <hip/hip_runtime.h>
#include <math.h>

#define B_GRAPHS 8192
#define OUT_DIM 1024
#define NU 128
#define NS 8
#define IN_DIM 1160          // OUT_DIM + NU + NS
#define KPAD1 1216           // IN_DIM padded to multiple of 64
#define HID 256
#define NSEG (B_GRAPHS * NU)        // 1048576 = 2^20
#define EDGES (B_GRAPHS * OUT_DIM)  // 8388608 = 2^23

// ---- binning parameters ----
#define BINS 512                    // seg >> 11
#define SEGS_PER_BIN 2048
#define HALF (EDGES / 2)            // 4194304 edges per pass
#define SCHUNK 8192                 // edges per scatter block -> 512 blocks
#define SBLOCKS (HALF / SCHUNK)     // 512
#define EPT (SCHUNK / 256)          // 32 edges per thread

typedef __attribute__((ext_vector_type(8))) short short8;
typedef __attribute__((ext_vector_type(4))) float f32x4;

__device__ __forceinline__ unsigned short f2bf(float f) {
    unsigned u = __float_as_uint(f);
    const unsigned r = (u >> 16) & 1u;
    return (unsigned short)((u + 0x7fffu + r) >> 16);   // RNE
}
__device__ __forceinline__ float bf2f(unsigned short b) {
    return __uint_as_float((unsigned)b << 16);
}

// ================= prep: fp32 -> bf16 conversions ==========================
__global__ __launch_bounds__(256) void convert_feats_kernel(
    const float* __restrict__ u2s, const float* __restrict__ usr,
    const float* __restrict__ srv, unsigned short* __restrict__ F)
{
    const int t = blockIdx.x * 256 + threadIdx.x;   // 8192*152 threads
    const int row = t / 152;
    const int g = t - row * 152;
    const int col = g * 8;
    float v[8];
    if (g < 128) {
        const float4 a = *(const float4*)&u2s[(size_t)row * OUT_DIM + col];
        const float4 b = *(const float4*)&u2s[(size_t)row * OUT_DIM + col + 4];
        v[0]=a.x; v[1]=a.y; v[2]=a.z; v[3]=a.w; v[4]=b.x; v[5]=b.y; v[6]=b.z; v[7]=b.w;
    } else if (g < 144) {
        const int c = col - OUT_DIM;
        const float4 a = *(const float4*)&usr[(size_t)row * NU + c];
        const float4 b = *(const float4*)&usr[(size_t)row * NU + c + 4];
        v[0]=a.x; v[1]=a.y; v[2]=a.z; v[3]=a.w; v[4]=b.x; v[5]=b.y; v[6]=b.z; v[7]=b.w;
    } else if (g == 144) {
        const float4 a = *(const float4*)&srv[(size_t)row * NS];
        const float4 b = *(const float4*)&srv[(size_t)row * NS + 4];
        v[0]=a.x; v[1]=a.y; v[2]=a.z; v[3]=a.w; v[4]=b.x; v[5]=b.y; v[6]=b.z; v[7]=b.w;
    } else {
        for (int i = 0; i < 8; ++i) v[i] = 0.f;
    }
    unsigned short o[8];
    for (int i = 0; i < 8; ++i) o[i] = f2bf(v[i]);
    *reinterpret_cast<short8*>(&F[(size_t)row * KPAD1 + col]) =
        *reinterpret_cast<const short8*>(o);
}

__global__ __launch_bounds__(256) void convert_wT_kernel(
    const float* __restrict__ W, unsigned short* __restrict__ WT,
    int K, int N, int Kpad)
{
    const int t = blockIdx.x * 256 + threadIdx.x;
    if (t >= N * Kpad) return;
    const int n = t / Kpad;
    const int k = t - n * Kpad;
    WT[t] = (k < K) ? f2bf(W[(size_t)k * N + n]) : (unsigned short)0;
}

// ================= bf16 MFMA GEMM (r5-proven) ==============================
template <int EPI>
__global__ __launch_bounds__(256) void gemm_bf16_kernel(
    const unsigned short* __restrict__ A, const unsigned short* __restrict__ BT,
    const float* __restrict__ bias, void* __restrict__ outv, int N, int K)
{
    __shared__ unsigned short As[128 * 64];
    __shared__ unsigned short Bs[64 * 64];

    const int tid = threadIdx.x;
    const int lane = tid & 63;
    const int wid = tid >> 6;
    const int wm = wid >> 1;
    const int wn = wid & 1;
    const int m0 = blockIdx.y * 128;
    const int n0 = blockIdx.x * 64;

    const int srow = lane >> 3;
    const int schunk = lane & 7;
    const int sswz = schunk ^ srow;

    f32x4 acc[4][2];
#pragma unroll
    for (int i = 0; i < 4; ++i)
#pragma unroll
        for (int j = 0; j < 2; ++j) acc[i][j] = (f32x4)0.f;

    for (int k0 = 0; k0 < K; k0 += 64) {
#pragma unroll
        for (int i = 0; i < 4; ++i) {
            const int r = wid * 32 + i * 8 + srow;
            const short8 v = *reinterpret_cast<const short8*>(
                &A[(size_t)(m0 + r) * K + k0 + sswz * 8]);
            *reinterpret_cast<short8*>(&As[r * 64 + schunk * 8]) = v;
        }
#pragma unroll
        for (int i = 0; i < 2; ++i) {
            const int r = wid * 16 + i * 8 + srow;
            const short8 v = *reinterpret_cast<const short8*>(
                &BT[(size_t)(n0 + r) * K + k0 + sswz * 8]);
            *reinterpret_cast<short8*>(&Bs[r * 64 + schunk * 8]) = v;
        }
        __syncthreads();

#pragma unroll
        for (int ks = 0; ks < 2; ++ks) {
            short8 af[4], bf[2];
            const int c = ks * 4 + (lane >> 4);
#pragma unroll
            for (int fm = 0; fm < 4; ++fm) {
                const int r = wm * 64 + fm * 16 + (lane & 15);
                af[fm] = *reinterpret_cast<const short8*>(
                    &As[r * 64 + (c ^ (r & 7)) * 8]);
            }
#pragma unroll
            for (int fn = 0; fn < 2; ++fn) {
                const int r = wn * 32 + fn * 16 + (lane & 15);
                bf[fn] = *reinterpret_cast<const short8*>(
                    &Bs[r * 64 + (c ^ (r & 7)) * 8]);
            }
#pragma unroll
            for (int fm = 0; fm < 4; ++fm)
#pragma unroll
                for (int fn = 0; fn < 2; ++fn)
                    acc[fm][fn] = __builtin_amdgcn_mfma_f32_16x16x32_bf16(
                        af[fm], bf[fn], acc[fm][fn], 0, 0, 0);
        }
        __syncthreads();
    }

    // C/D layout: col = lane&15, row = (lane>>4)*4 + reg
#pragma unroll
    for (int fn = 0; fn < 2; ++fn) {
        const int col = n0 + wn * 32 + fn * 16 + (lane & 15);
        const float bv = bias[col];
#pragma unroll
        for (int fm = 0; fm < 4; ++fm) {
            const int rbase = m0 + wm * 64 + fm * 16 + (lane >> 4) * 4;
#pragma unroll
            for (int e = 0; e < 4; ++e) {
                const float v = acc[fm][fn][e] + bv;
                if (EPI == 0) {
                    unsigned short* h = (unsigned short*)outv;
                    h[(size_t)(rbase + e) * N + col] = f2bf(fmaxf(v, 0.f));
                } else {
                    float* out = (float*)outv;
                    const int p = col >> 10;
                    const int w = col & 1023;
                    out[(size_t)p * EDGES + (size_t)(rbase + e) * OUT_DIM + w] =
                        __expf(v);
                }
            }
        }
    }
}

// ======= scatter: block-local counting sort -> dense coalesced write =======
// record u32 = seg_low(11) << 16 | bf16(e).  P[blk*SCHUNK ...] sorted by bin;
// offs[blk][bin] = within-block start of bin's run.  No global atomics.
__global__ __launch_bounds__(256) void scatter_sort_kernel(
    const int* __restrict__ idx, const float* __restrict__ vals, int w0,
    unsigned* __restrict__ P, unsigned* __restrict__ offs)
{
    __shared__ unsigned hist[BINS];            // counts -> bases
    __shared__ unsigned lofs[BINS];
    __shared__ unsigned scanbuf[256];
    __shared__ alignas(16) unsigned recs[SCHUNK];   // 32 KB

    const int tid = threadIdx.x;
    const int blk = blockIdx.x;
    const int base = w0 + blk * SCHUNK;

    for (int b = tid; b < BINS; b += 256) hist[b] = 0;
    __syncthreads();

    // ---- read edges once; histogram; keep records in registers ----
    unsigned rec_r[EPT];
    unsigned short bin_r[EPT];
#pragma unroll
    for (int i = 0; i < EPT; ++i) {
        const int w = base + i * 256 + tid;
        const int seg = idx[w];
        const float e = vals[w];
        bin_r[i] = (unsigned short)(seg >> 11);
        rec_r[i] = ((unsigned)(seg & 2047) << 16) | f2bf(e);
        atomicAdd(&hist[bin_r[i]], 1u);
    }
    __syncthreads();

    // ---- exclusive scan over 512 bins (pairs per thread) ----
    const unsigned h0 = hist[2 * tid];
    const unsigned h1 = hist[2 * tid + 1];
    const unsigned pairsum = h0 + h1;
    scanbuf[tid] = pairsum;
    __syncthreads();
    for (int d = 1; d < 256; d <<= 1) {
        const unsigned v = (tid >= d) ? scanbuf[tid - d] : 0u;
        __syncthreads();
        scanbuf[tid] += v;
        __syncthreads();
    }
    const unsigned excl = scanbuf[tid] - pairsum;
    hist[2 * tid] = excl;                 // bin bases
    hist[2 * tid + 1] = excl + h0;
    lofs[2 * tid] = 0;
    lofs[2 * tid + 1] = 0;
    offs[(size_t)blk * BINS + 2 * tid] = excl;          // offset row (coalesced)
    offs[(size_t)blk * BINS + 2 * tid + 1] = excl + h0;
    __syncthreads();

    // ---- place records into LDS in bin order ----
#pragma unroll
    for (int i = 0; i < EPT; ++i) {
        const unsigned p = hist[bin_r[i]] + atomicAdd(&lofs[bin_r[i]], 1u);
        recs[p] = rec_r[i];
    }
    __syncthreads();

    // ---- dense coalesced write-out (uint4) ----
    const uint4* rs = reinterpret_cast<const uint4*>(recs);
    uint4* dst = reinterpret_cast<uint4*>(&P[(size_t)blk * SCHUNK]);
#pragma unroll
    for (int i = 0; i < SCHUNK / 1024; ++i)     // 8 iters
        dst[i * 256 + tid] = rs[i * 256 + tid];
}

// ======= per-bin reduce over sorted runs; no random value access ===========
// mode 0: s_self = sub; 1: s_self += sub (sec-0 final);
// 2: r01 = pack(bf16(1/s_other), bf16(1/(sub+s_self)));  3: r2 = bf16(1/(sub+s_self))
__global__ __launch_bounds__(256) void reduce_sorted_kernel(
    const unsigned* __restrict__ P, const unsigned* __restrict__ offs,
    float* __restrict__ s_self, const float* __restrict__ s_other,
    unsigned* __restrict__ r01, unsigned short* __restrict__ r2, int mode)
{
    __shared__ float sub[SEGS_PER_BIN];
    const int b = blockIdx.x;
    const int tid = threadIdx.x;
    for (int i = tid; i < SEGS_PER_BIN; i += 256) sub[i] = 0.f;
    __syncthreads();

    for (int blk = tid; blk < SBLOCKS; blk += 256) {
        const unsigned st = offs[(size_t)blk * BINS + b];
        const unsigned en =
            (b == BINS - 1) ? SCHUNK : offs[(size_t)blk * BINS + b + 1];
        const unsigned* rec = &P[(size_t)blk * SCHUNK];
        for (unsigned i = st; i < en; ++i) {
            const unsigned r = rec[i];
            atomicAdd(&sub[r >> 16], __uint_as_float(r << 16));
        }
    }
    __syncthreads();

    for (int i = tid; i < SEGS_PER_BIN; i += 256) {
        const int seg = b * SEGS_PER_BIN + i;
        if (mode == 0) {
            s_self[seg] = sub[i];
        } else if (mode == 1) {
            s_self[seg] += sub[i];
        } else if (mode == 2) {
            const float s1f = sub[i] + s_self[seg];
            r01[seg] = ((unsigned)f2bf(1.f / s_other[seg]) << 16) |
                       f2bf(1.f / s1f);
        } else {
            r2[seg] = f2bf(1.f / (sub[i] + s_self[seg]));
        }
    }
}

// ============ normalize, split per table for L2 residency ==================
__global__ __launch_bounds__(256) void segdiv01_kernel(
    float* __restrict__ vals, const int* __restrict__ idx0,
    const unsigned* __restrict__ r01)
{
    const int w4 = (blockIdx.x * 256 + threadIdx.x) * 4;
    if (w4 >= EDGES) return;
    const int4 iv = *reinterpret_cast<const int4*>(&idx0[w4]);
    const int idx[4] = {iv.x, iv.y, iv.z, iv.w};
    float4 a = *reinterpret_cast<const float4*>(&vals[w4]);
    float4 b = *reinterpret_cast<const float4*>(&vals[(size_t)EDGES + w4]);
    float r0[4], r1[4];
#pragma unroll
    for (int j = 0; j < 4; ++j) {
        const unsigned p = r01[idx[j]];
        r0[j] = __uint_as_float(p & 0xffff0000u);
        r1[j] = __uint_as_float(p << 16);
    }
    a.x *= r0[0]; a.y *= r0[1]; a.z *= r0[2]; a.w *= r0[3];
    b.x *= r1[0]; b.y *= r1[1]; b.z *= r1[2]; b.w *= r1[3];
    *reinterpret_cast<float4*>(&vals[w4]) = a;
    *reinterpret_cast<float4*>(&vals[(size_t)EDGES + w4]) = b;
}

__global__ __launch_bounds__(256) void segdiv2_kernel(
    float* __restrict__ vals, const int* __restrict__ idx1,
    const unsigned short* __restrict__ r2)
{
    const int w4 = (blockIdx.x * 256 + threadIdx.x) * 4;
    if (w4 >= EDGES) return;
    const int4 iv = *reinterpret_cast<const int4*>(&idx1[w4]);
    const int idx[4] = {iv.x, iv.y, iv.z, iv.w};
    float4 c = *reinterpret_cast<const float4*>(&vals[2 * (size_t)EDGES + w4]);
    c.x *= bf2f(r2[idx[0]]);
    c.y *= bf2f(r2[idx[1]]);
    c.z *= bf2f(r2[idx[2]]);
    c.w *= bf2f(r2[idx[3]]);
    *reinterpret_cast<float4*>(&vals[2 * (size_t)EDGES + w4]) = c;
}

// ===========================================================================
extern "C" void kernel_launch(void* const* d_in, const int* in_sizes, int n_in,
                              void* d_out, int out_size, void* d_ws,
                              size_t ws_size, hipStream_t stream) {
    const float* u2s = (const float*)d_in[0];
    const float* usr = (const float*)d_in[1];
    const float* srv = (const float*)d_in[2];
    const int* edge = (const int*)d_in[3];
    const float* W1 = (const float*)d_in[4];
    const float* b1 = (const float*)d_in[5];
    const float* W2 = (const float*)d_in[6];
    const float* b2 = (const float*)d_in[7];
    const float* W3 = (const float*)d_in[8];
    const float* b3 = (const float*)d_in[9];
    const float* W4 = (const float*)d_in[10];
    const float* b4 = (const float*)d_in[11];

    const int* idx0 = edge;
    const int* idx1 = edge + EDGES;

    // ws layout (peak 38 MiB; proven available):
    //  phase1: F [0,19.9) | h1 [20,24) | h2 [24,28) | h3 [28,32) | wT [32,34.4)
    //  phase2: P [0,16) | offs [16.5,17.5) | s0 [20,24) | s1 [24,28) | s2 [28,32)
    //          r01 [32,36) | r2 [36,38)
    char* ws = (char*)d_ws;
    unsigned short* F = (unsigned short*)ws;
    unsigned short* h1 = (unsigned short*)(ws + 20ull * 1024 * 1024);
    unsigned short* h2 = (unsigned short*)(ws + 24ull * 1024 * 1024);
    unsigned short* h3 = (unsigned short*)(ws + 28ull * 1024 * 1024);
    unsigned short* w1t = (unsigned short*)(ws + 32ull * 1024 * 1024);
    unsigned short* w2t = w1t + (size_t)HID * KPAD1;
    unsigned short* w3t = w2t + (size_t)HID * HID;
    unsigned short* w4t = w3t + (size_t)HID * HID;

    unsigned* P = (unsigned*)ws;
    unsigned* offs = (unsigned*)(ws + 16896ull * 1024);     // 16.5 MiB, 1 MiB
    float* s0 = (float*)(ws + 20ull * 1024 * 1024);
    float* s1 = (float*)(ws + 24ull * 1024 * 1024);
    float* s2 = (float*)(ws + 28ull * 1024 * 1024);
    unsigned* r01 = (unsigned*)(ws + 32ull * 1024 * 1024);
    unsigned short* r2 = (unsigned short*)(ws + 36ull * 1024 * 1024);

    float* outp = (float*)d_out;
    const dim3 blk(256);

    // ---- prep: conversions ----
    convert_feats_kernel<<<(B_GRAPHS * 152) / 256, blk, 0, stream>>>(u2s, usr,
                                                                     srv, F);
    convert_wT_kernel<<<(HID * KPAD1 + 255) / 256, blk, 0, stream>>>(
        W1, w1t, IN_DIM, HID, KPAD1);
    convert_wT_kernel<<<(HID * HID + 255) / 256, blk, 0, stream>>>(
        W2, w2t, HID, HID, HID);
    convert_wT_kernel<<<(HID * HID + 255) / 256, blk, 0, stream>>>(
        W3, w3t, HID, HID, HID);
    convert_wT_kernel<<<(3 * OUT_DIM * HID + 255) / 256, blk, 0, stream>>>(
        W4, w4t, HID, 3 * OUT_DIM, HID);

    // ---- MLP (bf16 MFMA) ----
    gemm_bf16_kernel<0><<<dim3(HID / 64, B_GRAPHS / 128), blk, 0, stream>>>(
        F, w1t, b1, h1, HID, KPAD1);
    gemm_bf16_kernel<0><<<dim3(HID / 64, B_GRAPHS / 128), blk, 0, stream>>>(
        h1, w2t, b2, h2, HID, HID);
    gemm_bf16_kernel<0><<<dim3(HID / 64, B_GRAPHS / 128), blk, 0, stream>>>(
        h2, w3t, b3, h3, HID, HID);
    gemm_bf16_kernel<1><<<dim3(3 * OUT_DIM / 64, B_GRAPHS / 128), blk, 0,
                          stream>>>(h3, w4t, b4, outp, 3 * OUT_DIM, HID);

    // ---- segment sums: block-sorted scatter + run-walking reduce ----
    // section 0 (idx0)
    for (int h = 0; h < 2; ++h) {
        scatter_sort_kernel<<<SBLOCKS, blk, 0, stream>>>(idx0, outp, h * HALF,
                                                         P, offs);
        reduce_sorted_kernel<<<BINS, blk, 0, stream>>>(P, offs, s0, nullptr,
                                                       nullptr, nullptr, h);
    }
    // section 1 (idx0); last pass packs r01 from s0 (final) and s1
    for (int h = 0; h < 2; ++h) {
        scatter_sort_kernel<<<SBLOCKS, blk, 0, stream>>>(
            idx0, outp + (size_t)EDGES, h * HALF, P, offs);
        reduce_sorted_kernel<<<BINS, blk, 0, stream>>>(P, offs, s1, s0, r01,
                                                       nullptr, h == 0 ? 0 : 2);
    }
    // section 2 (idx1); last pass writes r2
    for (int h = 0; h < 2; ++h) {
        scatter_sort_kernel<<<SBLOCKS, blk, 0, stream>>>(
            idx1, outp + 2 * (size_t)EDGES, h * HALF, P, offs);
        reduce_sorted_kernel<<<BINS, blk, 0, stream>>>(P, offs, s2, nullptr,
                                                       nullptr, r2,
                                                       h == 0 ? 0 : 3);
    }

    // ---- normalize (split so each pass's random table fits one L2) ----
    segdiv01_kernel<<<EDGES / 1024, blk, 0, stream>>>(outp, idx0, r01);
    segdiv2_kernel<<<EDGES / 1024, blk, 0, stream>>>(outp, idx1, r2);
}

// Round 12
// 475.377 us; speedup vs baseline: 1.6199x; 1.0014x over previous
//
#include <hip/hip_runtime.h>
#include <math.h>

#define B_GRAPHS 8192
#define OUT_DIM 1024
#define NU 128
#define NS 8
#define IN_DIM 1160          // OUT_DIM + NU + NS
#define KPAD1 1216           // IN_DIM padded to multiple of 64
#define HID 256
#define NSEG (B_GRAPHS * NU)        // 1048576 = 2^20
#define EDGES (B_GRAPHS * OUT_DIM)  // 8388608 = 2^23

// ---- binning parameters ----
#define BINS 512                    // seg >> 11
#define SEGS_PER_BIN 2048
#define HALF (EDGES / 2)            // 4194304 edges per pass
#define SCHUNK 8192                 // edges per scatter block -> 512 blocks
#define SBLOCKS (HALF / SCHUNK)     // 512
#define EPT (SCHUNK / 256)          // 32 edges per thread

typedef __attribute__((ext_vector_type(8))) short short8;
typedef __attribute__((ext_vector_type(4))) float f32x4;
typedef __attribute__((ext_vector_type(4))) int i32x4;

__device__ __forceinline__ unsigned short f2bf(float f) {
    unsigned u = __float_as_uint(f);
    const unsigned r = (u >> 16) & 1u;
    return (unsigned short)((u + 0x7fffu + r) >> 16);   // RNE
}
__device__ __forceinline__ float bf2f(unsigned short b) {
    return __uint_as_float((unsigned)b << 16);
}

// ================= prep: fp32 -> bf16 conversions ==========================
__global__ __launch_bounds__(256) void convert_feats_kernel(
    const float* __restrict__ u2s, const float* __restrict__ usr,
    const float* __restrict__ srv, unsigned short* __restrict__ F)
{
    const int t = blockIdx.x * 256 + threadIdx.x;   // 8192*152 threads
    const int row = t / 152;
    const int g = t - row * 152;
    const int col = g * 8;
    float v[8];
    if (g < 128) {
        const float4 a = *(const float4*)&u2s[(size_t)row * OUT_DIM + col];
        const float4 b = *(const float4*)&u2s[(size_t)row * OUT_DIM + col + 4];
        v[0]=a.x; v[1]=a.y; v[2]=a.z; v[3]=a.w; v[4]=b.x; v[5]=b.y; v[6]=b.z; v[7]=b.w;
    } else if (g < 144) {
        const int c = col - OUT_DIM;
        const float4 a = *(const float4*)&usr[(size_t)row * NU + c];
        const float4 b = *(const float4*)&usr[(size_t)row * NU + c + 4];
        v[0]=a.x; v[1]=a.y; v[2]=a.z; v[3]=a.w; v[4]=b.x; v[5]=b.y; v[6]=b.z; v[7]=b.w;
    } else if (g == 144) {
        const float4 a = *(const float4*)&srv[(size_t)row * NS];
        const float4 b = *(const float4*)&srv[(size_t)row * NS + 4];
        v[0]=a.x; v[1]=a.y; v[2]=a.z; v[3]=a.w; v[4]=b.x; v[5]=b.y; v[6]=b.z; v[7]=b.w;
    } else {
        for (int i = 0; i < 8; ++i) v[i] = 0.f;
    }
    unsigned short o[8];
    for (int i = 0; i < 8; ++i) o[i] = f2bf(v[i]);
    *reinterpret_cast<short8*>(&F[(size_t)row * KPAD1 + col]) =
        *reinterpret_cast<const short8*>(o);
}

__global__ __launch_bounds__(256) void convert_wT_kernel(
    const float* __restrict__ W, unsigned short* __restrict__ WT,
    int K, int N, int Kpad)
{
    const int t = blockIdx.x * 256 + threadIdx.x;
    if (t >= N * Kpad) return;
    const int n = t / Kpad;
    const int k = t - n * Kpad;
    WT[t] = (k < K) ? f2bf(W[(size_t)k * N + n]) : (unsigned short)0;
}

// ================= bf16 MFMA GEMM (r5-proven) ==============================
template <int EPI>
__global__ __launch_bounds__(256) void gemm_bf16_kernel(
    const unsigned short* __restrict__ A, const unsigned short* __restrict__ BT,
    const float* __restrict__ bias, void* __restrict__ outv, int N, int K)
{
    __shared__ unsigned short As[128 * 64];
    __shared__ unsigned short Bs[64 * 64];

    const int tid = threadIdx.x;
    const int lane = tid & 63;
    const int wid = tid >> 6;
    const int wm = wid >> 1;
    const int wn = wid & 1;
    const int m0 = blockIdx.y * 128;
    const int n0 = blockIdx.x * 64;

    const int srow = lane >> 3;
    const int schunk = lane & 7;
    const int sswz = schunk ^ srow;

    f32x4 acc[4][2];
#pragma unroll
    for (int i = 0; i < 4; ++i)
#pragma unroll
        for (int j = 0; j < 2; ++j) acc[i][j] = (f32x4)0.f;

    for (int k0 = 0; k0 < K; k0 += 64) {
#pragma unroll
        for (int i = 0; i < 4; ++i) {
            const int r = wid * 32 + i * 8 + srow;
            const short8 v = *reinterpret_cast<const short8*>(
                &A[(size_t)(m0 + r) * K + k0 + sswz * 8]);
            *reinterpret_cast<short8*>(&As[r * 64 + schunk * 8]) = v;
        }
#pragma unroll
        for (int i = 0; i < 2; ++i) {
            const int r = wid * 16 + i * 8 + srow;
            const short8 v = *reinterpret_cast<const short8*>(
                &BT[(size_t)(n0 + r) * K + k0 + sswz * 8]);
            *reinterpret_cast<short8*>(&Bs[r * 64 + schunk * 8]) = v;
        }
        __syncthreads();

#pragma unroll
        for (int ks = 0; ks < 2; ++ks) {
            short8 af[4], bf[2];
            const int c = ks * 4 + (lane >> 4);
#pragma unroll
            for (int fm = 0; fm < 4; ++fm) {
                const int r = wm * 64 + fm * 16 + (lane & 15);
                af[fm] = *reinterpret_cast<const short8*>(
                    &As[r * 64 + (c ^ (r & 7)) * 8]);
            }
#pragma unroll
            for (int fn = 0; fn < 2; ++fn) {
                const int r = wn * 32 + fn * 16 + (lane & 15);
                bf[fn] = *reinterpret_cast<const short8*>(
                    &Bs[r * 64 + (c ^ (r & 7)) * 8]);
            }
#pragma unroll
            for (int fm = 0; fm < 4; ++fm)
#pragma unroll
                for (int fn = 0; fn < 2; ++fn)
                    acc[fm][fn] = __builtin_amdgcn_mfma_f32_16x16x32_bf16(
                        af[fm], bf[fn], acc[fm][fn], 0, 0, 0);
        }
        __syncthreads();
    }

    // C/D layout: col = lane&15, row = (lane>>4)*4 + reg
#pragma unroll
    for (int fn = 0; fn < 2; ++fn) {
        const int col = n0 + wn * 32 + fn * 16 + (lane & 15);
        const float bv = bias[col];
#pragma unroll
        for (int fm = 0; fm < 4; ++fm) {
            const int rbase = m0 + wm * 64 + fm * 16 + (lane >> 4) * 4;
#pragma unroll
            for (int e = 0; e < 4; ++e) {
                const float v = acc[fm][fn][e] + bv;
                if (EPI == 0) {
                    unsigned short* h = (unsigned short*)outv;
                    h[(size_t)(rbase + e) * N + col] = f2bf(fmaxf(v, 0.f));
                } else {
                    float* out = (float*)outv;
                    const int p = col >> 10;
                    const int w = col & 1023;
                    out[(size_t)p * EDGES + (size_t)(rbase + e) * OUT_DIM + w] =
                        __expf(v);
                }
            }
        }
    }
}

// ==== scatter sections 0+1 combined: u64 record, block counting sort =======
// record = seg_low(11) << 32 | bf16(e0) << 16 | bf16(e1)
__global__ __launch_bounds__(256) void scatter01_sort_kernel(
    const int* __restrict__ idx, const float* __restrict__ v0,
    const float* __restrict__ v1, int w0,
    unsigned long long* __restrict__ P, unsigned* __restrict__ offs)
{
    __shared__ unsigned hist[BINS];
    __shared__ unsigned lofs[BINS];
    __shared__ unsigned scanbuf[256];
    __shared__ alignas(16) unsigned long long recs[SCHUNK];   // 64 KB

    const int tid = threadIdx.x;
    const int blk = blockIdx.x;
    const int base = w0 + blk * SCHUNK;

    for (int b = tid; b < BINS; b += 256) hist[b] = 0;
    __syncthreads();

    unsigned val_r[EPT];     // packed bf16(e0)<<16 | bf16(e1)
    unsigned meta_r[EPT];    // bin << 16 | seg_low
#pragma unroll
    for (int i = 0; i < EPT; ++i) {
        const int w = base + i * 256 + tid;
        const int seg = __builtin_nontemporal_load(&idx[w]);
        const float e0 = __builtin_nontemporal_load(&v0[w]);
        const float e1 = __builtin_nontemporal_load(&v1[w]);
        const unsigned bin = (unsigned)seg >> 11;
        meta_r[i] = (bin << 16) | ((unsigned)seg & 2047u);
        val_r[i] = ((unsigned)f2bf(e0) << 16) | f2bf(e1);
        atomicAdd(&hist[bin], 1u);
    }
    __syncthreads();

    // exclusive scan over 512 bins (pairs per thread)
    const unsigned h0 = hist[2 * tid];
    const unsigned h1 = hist[2 * tid + 1];
    const unsigned pairsum = h0 + h1;
    scanbuf[tid] = pairsum;
    __syncthreads();
    for (int d = 1; d < 256; d <<= 1) {
        const unsigned v = (tid >= d) ? scanbuf[tid - d] : 0u;
        __syncthreads();
        scanbuf[tid] += v;
        __syncthreads();
    }
    const unsigned excl = scanbuf[tid] - pairsum;
    hist[2 * tid] = excl;
    hist[2 * tid + 1] = excl + h0;
    lofs[2 * tid] = 0;
    lofs[2 * tid + 1] = 0;
    offs[(size_t)blk * BINS + 2 * tid] = excl;
    offs[(size_t)blk * BINS + 2 * tid + 1] = excl + h0;
    __syncthreads();

#pragma unroll
    for (int i = 0; i < EPT; ++i) {
        const unsigned bin = meta_r[i] >> 16;
        const unsigned p = hist[bin] + atomicAdd(&lofs[bin], 1u);
        recs[p] = ((unsigned long long)(meta_r[i] & 2047u) << 32) | val_r[i];
    }
    __syncthreads();

    const ulonglong2* rs = reinterpret_cast<const ulonglong2*>(recs);
    ulonglong2* dst = reinterpret_cast<ulonglong2*>(&P[(size_t)blk * SCHUNK]);
#pragma unroll
    for (int i = 0; i < SCHUNK / 512; ++i)    // 16 iters of 16B stores
        dst[i * 256 + tid] = rs[i * 256 + tid];
}

__global__ __launch_bounds__(256) void reduce01_sorted_kernel(
    const unsigned long long* __restrict__ P, const unsigned* __restrict__ offs,
    float2* __restrict__ s01, unsigned* __restrict__ r01, int last)
{
    __shared__ float sub0[SEGS_PER_BIN];
    __shared__ float sub1[SEGS_PER_BIN];
    const int b = blockIdx.x;
    const int tid = threadIdx.x;
    for (int i = tid; i < SEGS_PER_BIN; i += 256) { sub0[i] = 0.f; sub1[i] = 0.f; }
    __syncthreads();

    for (int blk = tid; blk < SBLOCKS; blk += 256) {
        const unsigned st = offs[(size_t)blk * BINS + b];
        const unsigned en =
            (b == BINS - 1) ? SCHUNK : offs[(size_t)blk * BINS + b + 1];
        const unsigned long long* rec = &P[(size_t)blk * SCHUNK];
        for (unsigned i = st; i < en; ++i) {
            const unsigned long long r = rec[i];
            const int sl = (int)(r >> 32);
            const unsigned lo = (unsigned)r;
            atomicAdd(&sub0[sl], __uint_as_float(lo & 0xffff0000u));
            atomicAdd(&sub1[sl], __uint_as_float(lo << 16));
        }
    }
    __syncthreads();

    for (int i = tid; i < SEGS_PER_BIN; i += 256) {
        const int seg = b * SEGS_PER_BIN + i;
        if (!last) {
            s01[seg] = make_float2(sub0[i], sub1[i]);
        } else {
            const float2 p = s01[seg];
            const float s0f = sub0[i] + p.x;
            const float s1f = sub1[i] + p.y;
            r01[seg] = ((unsigned)f2bf(1.f / s0f) << 16) | f2bf(1.f / s1f);
        }
    }
}

// ==== section-2 scatter/reduce: u32 records (r10-proven) ===================
__global__ __launch_bounds__(256) void scatter2_sort_kernel(
    const int* __restrict__ idx, const float* __restrict__ vals, int w0,
    unsigned* __restrict__ P, unsigned* __restrict__ offs)
{
    __shared__ unsigned hist[BINS];
    __shared__ unsigned lofs[BINS];
    __shared__ unsigned scanbuf[256];
    __shared__ alignas(16) unsigned recs[SCHUNK];   // 32 KB

    const int tid = threadIdx.x;
    const int blk = blockIdx.x;
    const int base = w0 + blk * SCHUNK;

    for (int b = tid; b < BINS; b += 256) hist[b] = 0;
    __syncthreads();

    unsigned rec_r[EPT];
    unsigned short bin_r[EPT];
#pragma unroll
    for (int i = 0; i < EPT; ++i) {
        const int w = base + i * 256 + tid;
        const int seg = __builtin_nontemporal_load(&idx[w]);
        const float e = __builtin_nontemporal_load(&vals[w]);
        bin_r[i] = (unsigned short)((unsigned)seg >> 11);
        rec_r[i] = (((unsigned)seg & 2047u) << 16) | f2bf(e);
        atomicAdd(&hist[bin_r[i]], 1u);
    }
    __syncthreads();

    const unsigned h0 = hist[2 * tid];
    const unsigned h1 = hist[2 * tid + 1];
    const unsigned pairsum = h0 + h1;
    scanbuf[tid] = pairsum;
    __syncthreads();
    for (int d = 1; d < 256; d <<= 1) {
        const unsigned v = (tid >= d) ? scanbuf[tid - d] : 0u;
        __syncthreads();
        scanbuf[tid] += v;
        __syncthreads();
    }
    const unsigned excl = scanbuf[tid] - pairsum;
    hist[2 * tid] = excl;
    hist[2 * tid + 1] = excl + h0;
    lofs[2 * tid] = 0;
    lofs[2 * tid + 1] = 0;
    offs[(size_t)blk * BINS + 2 * tid] = excl;
    offs[(size_t)blk * BINS + 2 * tid + 1] = excl + h0;
    __syncthreads();

#pragma unroll
    for (int i = 0; i < EPT; ++i) {
        const unsigned p = hist[bin_r[i]] + atomicAdd(&lofs[bin_r[i]], 1u);
        recs[p] = rec_r[i];
    }
    __syncthreads();

    const uint4* rs = reinterpret_cast<const uint4*>(recs);
    uint4* dst = reinterpret_cast<uint4*>(&P[(size_t)blk * SCHUNK]);
#pragma unroll
    for (int i = 0; i < SCHUNK / 1024; ++i)
        dst[i * 256 + tid] = rs[i * 256 + tid];
}

__global__ __launch_bounds__(256) void reduce2_sorted_kernel(
    const unsigned* __restrict__ P, const unsigned* __restrict__ offs,
    float* __restrict__ s2, unsigned short* __restrict__ r2, int last)
{
    __shared__ float sub[SEGS_PER_BIN];
    const int b = blockIdx.x;
    const int tid = threadIdx.x;
    for (int i = tid; i < SEGS_PER_BIN; i += 256) sub[i] = 0.f;
    __syncthreads();

    for (int blk = tid; blk < SBLOCKS; blk += 256) {
        const unsigned st = offs[(size_t)blk * BINS + b];
        const unsigned en =
            (b == BINS - 1) ? SCHUNK : offs[(size_t)blk * BINS + b + 1];
        const unsigned* rec = &P[(size_t)blk * SCHUNK];
        for (unsigned i = st; i < en; ++i) {
            const unsigned r = rec[i];
            atomicAdd(&sub[r >> 16], __uint_as_float(r << 16));
        }
    }
    __syncthreads();

    for (int i = tid; i < SEGS_PER_BIN; i += 256) {
        const int seg = b * SEGS_PER_BIN + i;
        if (!last) s2[seg] = sub[i];
        else       r2[seg] = f2bf(1.f / (sub[i] + s2[seg]));
    }
}

// ============ normalize: NT streaming keeps r tables L2-resident ===========
__global__ __launch_bounds__(256) void segdiv01_kernel(
    float* __restrict__ vals, const int* __restrict__ idx0,
    const unsigned* __restrict__ r01)
{
    const int w4 = (blockIdx.x * 256 + threadIdx.x) * 4;
    if (w4 >= EDGES) return;
    const i32x4 iv =
        __builtin_nontemporal_load(reinterpret_cast<const i32x4*>(&idx0[w4]));
    f32x4 a =
        __builtin_nontemporal_load(reinterpret_cast<const f32x4*>(&vals[w4]));
    f32x4 b = __builtin_nontemporal_load(
        reinterpret_cast<const f32x4*>(&vals[(size_t)EDGES + w4]));
#pragma unroll
    for (int j = 0; j < 4; ++j) {
        const unsigned p = r01[iv[j]];           // hot 4 MiB table: normal load
        a[j] *= __uint_as_float(p & 0xffff0000u);
        b[j] *= __uint_as_float(p << 16);
    }
    __builtin_nontemporal_store(a, reinterpret_cast<f32x4*>(&vals[w4]));
    __builtin_nontemporal_store(
        b, reinterpret_cast<f32x4*>(&vals[(size_t)EDGES + w4]));
}

__global__ __launch_bounds__(256) void segdiv2_kernel(
    float* __restrict__ vals, const int* __restrict__ idx1,
    const unsigned short* __restrict__ r2)
{
    const int w4 = (blockIdx.x * 256 + threadIdx.x) * 4;
    if (w4 >= EDGES) return;
    const i32x4 iv =
        __builtin_nontemporal_load(reinterpret_cast<const i32x4*>(&idx1[w4]));
    f32x4 c = __builtin_nontemporal_load(
        reinterpret_cast<const f32x4*>(&vals[2 * (size_t)EDGES + w4]));
#pragma unroll
    for (int j = 0; j < 4; ++j) c[j] *= bf2f(r2[iv[j]]);
    __builtin_nontemporal_store(
        c, reinterpret_cast<f32x4*>(&vals[2 * (size_t)EDGES + w4]));
}

// ===========================================================================
extern "C" void kernel_launch(void* const* d_in, const int* in_sizes, int n_in,
                              void* d_out, int out_size, void* d_ws,
                              size_t ws_size, hipStream_t stream) {
    const float* u2s = (const float*)d_in[0];
    const float* usr = (const float*)d_in[1];
    const float* srv = (const float*)d_in[2];
    const int* edge = (const int*)d_in[3];
    const float* W1 = (const float*)d_in[4];
    const float* b1 = (const float*)d_in[5];
    const float* W2 = (const float*)d_in[6];
    const float* b2 = (const float*)d_in[7];
    const float* W3 = (const float*)d_in[8];
    const float* b3 = (const float*)d_in[9];
    const float* W4 = (const float*)d_in[10];
    const float* b4 = (const float*)d_in[11];

    const int* idx0 = edge;
    const int* idx1 = edge + EDGES;

    // ws layout (peak 47 MiB; 48 MiB proven in round 1):
    //  phase1: F [0,19.9) | h1 [20,24) | h2 [24,28) | h3 [28,32) | wT [41,43.4)
    //  phase2: P [0,32) | offs [32,33) | s01 [33,41) | r01 [41,45) | r2 [45,47)
    //          s2 [33,37) (aliases s01 once dead)
    char* ws = (char*)d_ws;
    unsigned short* F = (unsigned short*)ws;
    unsigned short* h1 = (unsigned short*)(ws + 20ull * 1024 * 1024);
    unsigned short* h2 = (unsigned short*)(ws + 24ull * 1024 * 1024);
    unsigned short* h3 = (unsigned short*)(ws + 28ull * 1024 * 1024);
    unsigned short* w1t = (unsigned short*)(ws + 41ull * 1024 * 1024);
    unsigned short* w2t = w1t + (size_t)HID * KPAD1;
    unsigned short* w3t = w2t + (size_t)HID * HID;
    unsigned short* w4t = w3t + (size_t)HID * HID;

    unsigned long long* P64 = (unsigned long long*)ws;
    unsigned* P32 = (unsigned*)ws;
    unsigned* offs = (unsigned*)(ws + 32ull * 1024 * 1024);
    float2* s01 = (float2*)(ws + 33ull * 1024 * 1024);
    float* s2 = (float*)(ws + 33ull * 1024 * 1024);      // aliases dead s01
    unsigned* r01 = (unsigned*)(ws + 41ull * 1024 * 1024);
    unsigned short* r2 = (unsigned short*)(ws + 45ull * 1024 * 1024);

    float* outp = (float*)d_out;
    const dim3 blk(256);

    // ---- prep: conversions ----
    convert_feats_kernel<<<(B_GRAPHS * 152) / 256, blk, 0, stream>>>(u2s, usr,
                                                                     srv, F);
    convert_wT_kernel<<<(HID * KPAD1 + 255) / 256, blk, 0, stream>>>(
        W1, w1t, IN_DIM, HID, KPAD1);
    convert_wT_kernel<<<(HID * HID + 255) / 256, blk, 0, stream>>>(
        W2, w2t, HID, HID, HID);
    convert_wT_kernel<<<(HID * HID + 255) / 256, blk, 0, stream>>>(
        W3, w3t, HID, HID, HID);
    convert_wT_kernel<<<(3 * OUT_DIM * HID + 255) / 256, blk, 0, stream>>>(
        W4, w4t, HID, 3 * OUT_DIM, HID);

    // ---- MLP (bf16 MFMA) ----
    gemm_bf16_kernel<0><<<dim3(HID / 64, B_GRAPHS / 128), blk, 0, stream>>>(
        F, w1t, b1, h1, HID, KPAD1);
    gemm_bf16_kernel<0><<<dim3(HID / 64, B_GRAPHS / 128), blk, 0, stream>>>(
        h1, w2t, b2, h2, HID, HID);
    gemm_bf16_kernel<0><<<dim3(HID / 64, B_GRAPHS / 128), blk, 0, stream>>>(
        h2, w3t, b3, h3, HID, HID);
    gemm_bf16_kernel<1><<<dim3(3 * OUT_DIM / 64, B_GRAPHS / 128), blk, 0,
                          stream>>>(h3, w4t, b4, outp, 3 * OUT_DIM, HID);

    // ---- segment sums ----
    // sections 0+1 (idx0, u64 records): 2 halves; last reduce packs r01
    for (int h = 0; h < 2; ++h) {
        scatter01_sort_kernel<<<SBLOCKS, blk, 0, stream>>>(
            idx0, outp, outp + (size_t)EDGES, h * HALF, P64, offs);
        reduce01_sorted_kernel<<<BINS, blk, 0, stream>>>(P64, offs, s01, r01,
                                                         h);
    }
    // section 2 (idx1, u32 records): 2 halves; last reduce writes r2
    for (int h = 0; h < 2; ++h) {
        scatter2_sort_kernel<<<SBLOCKS, blk, 0, stream>>>(
            idx1, outp + 2 * (size_t)EDGES, h * HALF, P32, offs);
        reduce2_sorted_kernel<<<BINS, blk, 0, stream>>>(P32, offs, s2, r2, h);
    }

    // ---- normalize (NT streaming; r tables stay L2-resident) ----
    segdiv01_kernel<<<EDGES / 1024, blk, 0, stream>>>(outp, idx0, r01);
    segdiv2_kernel<<<EDGES / 1024, blk, 0, stream>>>(outp, idx1, r2);
}

// Round 13
// 457.183 us; speedup vs baseline: 1.6844x; 1.0398x over previous
//
#include <hip/hip_runtime.h>
#include <math.h>

#define B_GRAPHS 8192
#define OUT_DIM 1024
#define NU 128
#define NS 8
#define IN_DIM 1160          // OUT_DIM + NU + NS
#define KPAD1 1216           // IN_DIM padded to multiple of 64
#define HID 256
#define NSEG (B_GRAPHS * NU)        // 1048576 = 2^20
#define EDGES (B_GRAPHS * OUT_DIM)  // 8388608 = 2^23

// ---- binning parameters ----
#define BINS 512                    // seg >> 11
#define SEGS_PER_BIN 2048
#define HALF (EDGES / 2)            // 4194304 edges per pass
#define SCHUNK 8192                 // edges per scatter block -> 512 blocks
#define SBLOCKS (HALF / SCHUNK)     // 512
#define EPT (SCHUNK / 256)          // 32 edges per thread

typedef __attribute__((ext_vector_type(8))) short short8;
typedef __attribute__((ext_vector_type(4))) float f32x4;
typedef __attribute__((ext_vector_type(4))) int i32x4;

__device__ __forceinline__ unsigned short f2bf(float f) {
    unsigned u = __float_as_uint(f);
    const unsigned r = (u >> 16) & 1u;
    return (unsigned short)((u + 0x7fffu + r) >> 16);   // RNE
}
__device__ __forceinline__ float bf2f(unsigned short b) {
    return __uint_as_float((unsigned)b << 16);
}

// async global->LDS direct load, 16B per lane (wave-linear LDS dest)
__device__ __forceinline__ void gload_lds16(const void* g, void* l) {
    __builtin_amdgcn_global_load_lds(
        (const __attribute__((address_space(1))) unsigned int*)g,
        (__attribute__((address_space(3))) unsigned int*)l, 16, 0, 0);
}

// ================= prep: fp32 -> bf16 conversions ==========================
__global__ __launch_bounds__(256) void convert_feats_kernel(
    const float* __restrict__ u2s, const float* __restrict__ usr,
    const float* __restrict__ srv, unsigned short* __restrict__ F)
{
    const int t = blockIdx.x * 256 + threadIdx.x;   // 8192*152 threads
    const int row = t / 152;
    const int g = t - row * 152;
    const int col = g * 8;
    float v[8];
    if (g < 128) {
        const float4 a = *(const float4*)&u2s[(size_t)row * OUT_DIM + col];
        const float4 b = *(const float4*)&u2s[(size_t)row * OUT_DIM + col + 4];
        v[0]=a.x; v[1]=a.y; v[2]=a.z; v[3]=a.w; v[4]=b.x; v[5]=b.y; v[6]=b.z; v[7]=b.w;
    } else if (g < 144) {
        const int c = col - OUT_DIM;
        const float4 a = *(const float4*)&usr[(size_t)row * NU + c];
        const float4 b = *(const float4*)&usr[(size_t)row * NU + c + 4];
        v[0]=a.x; v[1]=a.y; v[2]=a.z; v[3]=a.w; v[4]=b.x; v[5]=b.y; v[6]=b.z; v[7]=b.w;
    } else if (g == 144) {
        const float4 a = *(const float4*)&srv[(size_t)row * NS];
        const float4 b = *(const float4*)&srv[(size_t)row * NS + 4];
        v[0]=a.x; v[1]=a.y; v[2]=a.z; v[3]=a.w; v[4]=b.x; v[5]=b.y; v[6]=b.z; v[7]=b.w;
    } else {
        for (int i = 0; i < 8; ++i) v[i] = 0.f;
    }
    unsigned short o[8];
    for (int i = 0; i < 8; ++i) o[i] = f2bf(v[i]);
    *reinterpret_cast<short8*>(&F[(size_t)row * KPAD1 + col]) =
        *reinterpret_cast<const short8*>(o);
}

__global__ __launch_bounds__(256) void convert_wT_kernel(
    const float* __restrict__ W, unsigned short* __restrict__ WT,
    int K, int N, int Kpad)
{
    const int t = blockIdx.x * 256 + threadIdx.x;
    if (t >= N * Kpad) return;
    const int n = t / Kpad;
    const int k = t - n * Kpad;
    WT[t] = (k < K) ? f2bf(W[(size_t)k * N + n]) : (unsigned short)0;
}

// ================= bf16 MFMA GEMM + global_load_lds staging ================
// LDS dest is wave-linear (lane l -> base + l*16B); the XOR swizzle is applied
// on the per-lane GLOBAL source address (m173 pattern).
template <int EPI>
__global__ __launch_bounds__(256) void gemm_bf16_kernel(
    const unsigned short* __restrict__ A, const unsigned short* __restrict__ BT,
    const float* __restrict__ bias, void* __restrict__ outv, int N, int K)
{
    __shared__ alignas(16) unsigned short As[128 * 64];
    __shared__ alignas(16) unsigned short Bs[64 * 64];

    const int tid = threadIdx.x;
    const int lane = tid & 63;
    const int wid = tid >> 6;
    const int wm = wid >> 1;
    const int wn = wid & 1;
    const int m0 = blockIdx.y * 128;
    const int n0 = blockIdx.x * 64;

    const int srow = lane >> 3;
    const int schunk = lane & 7;
    const int sswz = schunk ^ srow;

    f32x4 acc[4][2];
#pragma unroll
    for (int i = 0; i < 4; ++i)
#pragma unroll
        for (int j = 0; j < 2; ++j) acc[i][j] = (f32x4)0.f;

    for (int k0 = 0; k0 < K; k0 += 64) {
        // stage A: wave covers rows [wid*32, wid*32+32), 8 rows per issue
#pragma unroll
        for (int i = 0; i < 4; ++i) {
            const int r = wid * 32 + i * 8 + srow;
            gload_lds16(&A[(size_t)(m0 + r) * K + k0 + sswz * 8],
                        &As[(wid * 32 + i * 8) * 64]);
        }
        // stage B: wave covers rows [wid*16, wid*16+16)
#pragma unroll
        for (int i = 0; i < 2; ++i) {
            const int r = wid * 16 + i * 8 + srow;
            gload_lds16(&BT[(size_t)(n0 + r) * K + k0 + sswz * 8],
                        &Bs[(wid * 16 + i * 8) * 64]);
        }
        __syncthreads();

#pragma unroll
        for (int ks = 0; ks < 2; ++ks) {
            short8 af[4], bf[2];
            const int c = ks * 4 + (lane >> 4);
#pragma unroll
            for (int fm = 0; fm < 4; ++fm) {
                const int r = wm * 64 + fm * 16 + (lane & 15);
                af[fm] = *reinterpret_cast<const short8*>(
                    &As[r * 64 + (c ^ (r & 7)) * 8]);
            }
#pragma unroll
            for (int fn = 0; fn < 2; ++fn) {
                const int r = wn * 32 + fn * 16 + (lane & 15);
                bf[fn] = *reinterpret_cast<const short8*>(
                    &Bs[r * 64 + (c ^ (r & 7)) * 8]);
            }
#pragma unroll
            for (int fm = 0; fm < 4; ++fm)
#pragma unroll
                for (int fn = 0; fn < 2; ++fn)
                    acc[fm][fn] = __builtin_amdgcn_mfma_f32_16x16x32_bf16(
                        af[fm], bf[fn], acc[fm][fn], 0, 0, 0);
        }
        __syncthreads();
    }

    // C/D layout: col = lane&15, row = (lane>>4)*4 + reg
#pragma unroll
    for (int fn = 0; fn < 2; ++fn) {
        const int col = n0 + wn * 32 + fn * 16 + (lane & 15);
        const float bv = bias[col];
#pragma unroll
        for (int fm = 0; fm < 4; ++fm) {
            const int rbase = m0 + wm * 64 + fm * 16 + (lane >> 4) * 4;
#pragma unroll
            for (int e = 0; e < 4; ++e) {
                const float v = acc[fm][fn][e] + bv;
                if (EPI == 0) {
                    unsigned short* h = (unsigned short*)outv;
                    h[(size_t)(rbase + e) * N + col] = f2bf(fmaxf(v, 0.f));
                } else {
                    float* out = (float*)outv;
                    const int p = col >> 10;
                    const int w = col & 1023;
                    out[(size_t)p * EDGES + (size_t)(rbase + e) * OUT_DIM + w] =
                        __expf(v);
                }
            }
        }
    }
}

// ==== scatter sections 0+1 combined: u64 record, block counting sort =======
// record = seg_low(11) << 32 | bf16(e0) << 16 | bf16(e1)
__global__ __launch_bounds__(256) void scatter01_sort_kernel(
    const int* __restrict__ idx, const float* __restrict__ v0,
    const float* __restrict__ v1, int w0,
    unsigned long long* __restrict__ P, unsigned* __restrict__ offs)
{
    __shared__ unsigned hist[BINS];
    __shared__ unsigned lofs[BINS];
    __shared__ unsigned scanbuf[256];
    __shared__ alignas(16) unsigned long long recs[SCHUNK];   // 64 KB

    const int tid = threadIdx.x;
    const int blk = blockIdx.x;
    const int base = w0 + blk * SCHUNK;

    for (int b = tid; b < BINS; b += 256) hist[b] = 0;
    __syncthreads();

    unsigned val_r[EPT];     // packed bf16(e0)<<16 | bf16(e1)
    unsigned meta_r[EPT];    // bin << 16 | seg_low
#pragma unroll
    for (int i = 0; i < EPT; ++i) {
        const int w = base + i * 256 + tid;
        const int seg = __builtin_nontemporal_load(&idx[w]);
        const float e0 = __builtin_nontemporal_load(&v0[w]);
        const float e1 = __builtin_nontemporal_load(&v1[w]);
        const unsigned bin = (unsigned)seg >> 11;
        meta_r[i] = (bin << 16) | ((unsigned)seg & 2047u);
        val_r[i] = ((unsigned)f2bf(e0) << 16) | f2bf(e1);
        atomicAdd(&hist[bin], 1u);
    }
    __syncthreads();

    // exclusive scan over 512 bins (pairs per thread)
    const unsigned h0 = hist[2 * tid];
    const unsigned h1 = hist[2 * tid + 1];
    const unsigned pairsum = h0 + h1;
    scanbuf[tid] = pairsum;
    __syncthreads();
    for (int d = 1; d < 256; d <<= 1) {
        const unsigned v = (tid >= d) ? scanbuf[tid - d] : 0u;
        __syncthreads();
        scanbuf[tid] += v;
        __syncthreads();
    }
    const unsigned excl = scanbuf[tid] - pairsum;
    hist[2 * tid] = excl;
    hist[2 * tid + 1] = excl + h0;
    lofs[2 * tid] = 0;
    lofs[2 * tid + 1] = 0;
    offs[(size_t)blk * BINS + 2 * tid] = excl;
    offs[(size_t)blk * BINS + 2 * tid + 1] = excl + h0;
    __syncthreads();

#pragma unroll
    for (int i = 0; i < EPT; ++i) {
        const unsigned bin = meta_r[i] >> 16;
        const unsigned p = hist[bin] + atomicAdd(&lofs[bin], 1u);
        recs[p] = ((unsigned long long)(meta_r[i] & 2047u) << 32) | val_r[i];
    }
    __syncthreads();

    const ulonglong2* rs = reinterpret_cast<const ulonglong2*>(recs);
    ulonglong2* dst = reinterpret_cast<ulonglong2*>(&P[(size_t)blk * SCHUNK]);
#pragma unroll
    for (int i = 0; i < SCHUNK / 512; ++i)    // 16 iters of 16B stores
        dst[i * 256 + tid] = rs[i * 256 + tid];
}

__global__ __launch_bounds__(256) void reduce01_sorted_kernel(
    const unsigned long long* __restrict__ P, const unsigned* __restrict__ offs,
    float2* __restrict__ s01, unsigned* __restrict__ r01, int last)
{
    __shared__ float sub0[SEGS_PER_BIN];
    __shared__ float sub1[SEGS_PER_BIN];
    const int b = blockIdx.x;
    const int tid = threadIdx.x;
    for (int i = tid; i < SEGS_PER_BIN; i += 256) { sub0[i] = 0.f; sub1[i] = 0.f; }
    __syncthreads();

    for (int blk = tid; blk < SBLOCKS; blk += 256) {
        const unsigned st = offs[(size_t)blk * BINS + b];
        const unsigned en =
            (b == BINS - 1) ? SCHUNK : offs[(size_t)blk * BINS + b + 1];
        const unsigned long long* rec = &P[(size_t)blk * SCHUNK];
        for (unsigned i = st; i < en; ++i) {
            const unsigned long long r = rec[i];
            const int sl = (int)(r >> 32);
            const unsigned lo = (unsigned)r;
            atomicAdd(&sub0[sl], __uint_as_float(lo & 0xffff0000u));
            atomicAdd(&sub1[sl], __uint_as_float(lo << 16));
        }
    }
    __syncthreads();

    for (int i = tid; i < SEGS_PER_BIN; i += 256) {
        const int seg = b * SEGS_PER_BIN + i;
        if (!last) {
            s01[seg] = make_float2(sub0[i], sub1[i]);
        } else {
            const float2 p = s01[seg];
            const float s0f = sub0[i] + p.x;
            const float s1f = sub1[i] + p.y;
            r01[seg] = ((unsigned)f2bf(1.f / s0f) << 16) | f2bf(1.f / s1f);
        }
    }
}

// ==== section-2 scatter/reduce: u32 records ================================
__global__ __launch_bounds__(256) void scatter2_sort_kernel(
    const int* __restrict__ idx, const float* __restrict__ vals, int w0,
    unsigned* __restrict__ P, unsigned* __restrict__ offs)
{
    __shared__ unsigned hist[BINS];
    __shared__ unsigned lofs[BINS];
    __shared__ unsigned scanbuf[256];
    __shared__ alignas(16) unsigned recs[SCHUNK];   // 32 KB

    const int tid = threadIdx.x;
    const int blk = blockIdx.x;
    const int base = w0 + blk * SCHUNK;

    for (int b = tid; b < BINS; b += 256) hist[b] = 0;
    __syncthreads();

    unsigned rec_r[EPT];
    unsigned short bin_r[EPT];
#pragma unroll
    for (int i = 0; i < EPT; ++i) {
        const int w = base + i * 256 + tid;
        const int seg = __builtin_nontemporal_load(&idx[w]);
        const float e = __builtin_nontemporal_load(&vals[w]);
        bin_r[i] = (unsigned short)((unsigned)seg >> 11);
        rec_r[i] = (((unsigned)seg & 2047u) << 16) | f2bf(e);
        atomicAdd(&hist[bin_r[i]], 1u);
    }
    __syncthreads();

    const unsigned h0 = hist[2 * tid];
    const unsigned h1 = hist[2 * tid + 1];
    const unsigned pairsum = h0 + h1;
    scanbuf[tid] = pairsum;
    __syncthreads();
    for (int d = 1; d < 256; d <<= 1) {
        const unsigned v = (tid >= d) ? scanbuf[tid - d] : 0u;
        __syncthreads();
        scanbuf[tid] += v;
        __syncthreads();
    }
    const unsigned excl = scanbuf[tid] - pairsum;
    hist[2 * tid] = excl;
    hist[2 * tid + 1] = excl + h0;
    lofs[2 * tid] = 0;
    lofs[2 * tid + 1] = 0;
    offs[(size_t)blk * BINS + 2 * tid] = excl;
    offs[(size_t)blk * BINS + 2 * tid + 1] = excl + h0;
    __syncthreads();

#pragma unroll
    for (int i = 0; i < EPT; ++i) {
        const unsigned p = hist[bin_r[i]] + atomicAdd(&lofs[bin_r[i]], 1u);
        recs[p] = rec_r[i];
    }
    __syncthreads();

    const uint4* rs = reinterpret_cast<const uint4*>(recs);
    uint4* dst = reinterpret_cast<uint4*>(&P[(size_t)blk * SCHUNK]);
#pragma unroll
    for (int i = 0; i < SCHUNK / 1024; ++i)
        dst[i * 256 + tid] = rs[i * 256 + tid];
}

__global__ __launch_bounds__(256) void reduce2_sorted_kernel(
    const unsigned* __restrict__ P, const unsigned* __restrict__ offs,
    float* __restrict__ s2, unsigned short* __restrict__ r2, int last)
{
    __shared__ float sub[SEGS_PER_BIN];
    const int b = blockIdx.x;
    const int tid = threadIdx.x;
    for (int i = tid; i < SEGS_PER_BIN; i += 256) sub[i] = 0.f;
    __syncthreads();

    for (int blk = tid; blk < SBLOCKS; blk += 256) {
        const unsigned st = offs[(size_t)blk * BINS + b];
        const unsigned en =
            (b == BINS - 1) ? SCHUNK : offs[(size_t)blk * BINS + b + 1];
        const unsigned* rec = &P[(size_t)blk * SCHUNK];
        for (unsigned i = st; i < en; ++i) {
            const unsigned r = rec[i];
            atomicAdd(&sub[r >> 16], __uint_as_float(r << 16));
        }
    }
    __syncthreads();

    for (int i = tid; i < SEGS_PER_BIN; i += 256) {
        const int seg = b * SEGS_PER_BIN + i;
        if (!last) s2[seg] = sub[i];
        else       r2[seg] = f2bf(1.f / (sub[i] + s2[seg]));
    }
}

// ============ normalize (plain loads; NT reverted — r10-proven timing) =====
__global__ __launch_bounds__(256) void segdiv01_kernel(
    float* __restrict__ vals, const int* __restrict__ idx0,
    const unsigned* __restrict__ r01)
{
    const int w4 = (blockIdx.x * 256 + threadIdx.x) * 4;
    if (w4 >= EDGES) return;
    const i32x4 iv = *reinterpret_cast<const i32x4*>(&idx0[w4]);
    f32x4 a = *reinterpret_cast<const f32x4*>(&vals[w4]);
    f32x4 b = *reinterpret_cast<const f32x4*>(&vals[(size_t)EDGES + w4]);
#pragma unroll
    for (int j = 0; j < 4; ++j) {
        const unsigned p = r01[iv[j]];
        a[j] *= __uint_as_float(p & 0xffff0000u);
        b[j] *= __uint_as_float(p << 16);
    }
    *reinterpret_cast<f32x4*>(&vals[w4]) = a;
    *reinterpret_cast<f32x4*>(&vals[(size_t)EDGES + w4]) = b;
}

__global__ __launch_bounds__(256) void segdiv2_kernel(
    float* __restrict__ vals, const int* __restrict__ idx1,
    const unsigned short* __restrict__ r2)
{
    const int w4 = (blockIdx.x * 256 + threadIdx.x) * 4;
    if (w4 >= EDGES) return;
    const i32x4 iv = *reinterpret_cast<const i32x4*>(&idx1[w4]);
    f32x4 c = *reinterpret_cast<const f32x4*>(&vals[2 * (size_t)EDGES + w4]);
#pragma unroll
    for (int j = 0; j < 4; ++j) c[j] *= bf2f(r2[iv[j]]);
    *reinterpret_cast<f32x4*>(&vals[2 * (size_t)EDGES + w4]) = c;
}

// ===========================================================================
extern "C" void kernel_launch(void* const* d_in, const int* in_sizes, int n_in,
                              void* d_out, int out_size, void* d_ws,
                              size_t ws_size, hipStream_t stream) {
    const float* u2s = (const float*)d_in[0];
    const float* usr = (const float*)d_in[1];
    const float* srv = (const float*)d_in[2];
    const int* edge = (const int*)d_in[3];
    const float* W1 = (const float*)d_in[4];
    const float* b1 = (const float*)d_in[5];
    const float* W2 = (const float*)d_in[6];
    const float* b2 = (const float*)d_in[7];
    const float* W3 = (const float*)d_in[8];
    const float* b3 = (const float*)d_in[9];
    const float* W4 = (const float*)d_in[10];
    const float* b4 = (const float*)d_in[11];

    const int* idx0 = edge;
    const int* idx1 = edge + EDGES;

    // ws layout (peak 47 MiB; 48 MiB proven in round 1):
    //  phase1: F [0,19.9) | h1 [20,24) | h2 [24,28) | h3 [28,32) | wT [41,43.4)
    //  phase2: P [0,32) | offs [32,33) | s01 [33,41) | r01 [41,45) | r2 [45,47)
    //          s2 [33,37) (aliases s01 once dead)
    char* ws = (char*)d_ws;
    unsigned short* F = (unsigned short*)ws;
    unsigned short* h1 = (unsigned short*)(ws + 20ull * 1024 * 1024);
    unsigned short* h2 = (unsigned short*)(ws + 24ull * 1024 * 1024);
    unsigned short* h3 = (unsigned short*)(ws + 28ull * 1024 * 1024);
    unsigned short* w1t = (unsigned short*)(ws + 41ull * 1024 * 1024);
    unsigned short* w2t = w1t + (size_t)HID * KPAD1;
    unsigned short* w3t = w2t + (size_t)HID * HID;
    unsigned short* w4t = w3t + (size_t)HID * HID;

    unsigned long long* P64 = (unsigned long long*)ws;
    unsigned* P32 = (unsigned*)ws;
    unsigned* offs = (unsigned*)(ws + 32ull * 1024 * 1024);
    float2* s01 = (float2*)(ws + 33ull * 1024 * 1024);
    float* s2 = (float*)(ws + 33ull * 1024 * 1024);      // aliases dead s01
    unsigned* r01 = (unsigned*)(ws + 41ull * 1024 * 1024);
    unsigned short* r2 = (unsigned short*)(ws + 45ull * 1024 * 1024);

    float* outp = (float*)d_out;
    const dim3 blk(256);

    // ---- prep: conversions ----
    convert_feats_kernel<<<(B_GRAPHS * 152) / 256, blk, 0, stream>>>(u2s, usr,
                                                                     srv, F);
    convert_wT_kernel<<<(HID * KPAD1 + 255) / 256, blk, 0, stream>>>(
        W1, w1t, IN_DIM, HID, KPAD1);
    convert_wT_kernel<<<(HID * HID + 255) / 256, blk, 0, stream>>>(
        W2, w2t, HID, HID, HID);
    convert_wT_kernel<<<(HID * HID + 255) / 256, blk, 0, stream>>>(
        W3, w3t, HID, HID, HID);
    convert_wT_kernel<<<(3 * OUT_DIM * HID + 255) / 256, blk, 0, stream>>>(
        W4, w4t, HID, 3 * OUT_DIM, HID);

    // ---- MLP (bf16 MFMA, global_load_lds staging) ----
    gemm_bf16_kernel<0><<<dim3(HID / 64, B_GRAPHS / 128), blk, 0, stream>>>(
        F, w1t, b1, h1, HID, KPAD1);
    gemm_bf16_kernel<0><<<dim3(HID / 64, B_GRAPHS / 128), blk, 0, stream>>>(
        h1, w2t, b2, h2, HID, HID);
    gemm_bf16_kernel<0><<<dim3(HID / 64, B_GRAPHS / 128), blk, 0, stream>>>(
        h2, w3t, b3, h3, HID, HID);
    gemm_bf16_kernel<1><<<dim3(3 * OUT_DIM / 64, B_GRAPHS / 128), blk, 0,
                          stream>>>(h3, w4t, b4, outp, 3 * OUT_DIM, HID);

    // ---- segment sums ----
    // sections 0+1 (idx0, u64 records): 2 halves; last reduce packs r01
    for (int h = 0; h < 2; ++h) {
        scatter01_sort_kernel<<<SBLOCKS, blk, 0, stream>>>(
            idx0, outp, outp + (size_t)EDGES, h * HALF, P64, offs);
        reduce01_sorted_kernel<<<BINS, blk, 0, stream>>>(P64, offs, s01, r01,
                                                         h);
    }
    // section 2 (idx1, u32 records): 2 halves; last reduce writes r2
    for (int h = 0; h < 2; ++h) {
        scatter2_sort_kernel<<<SBLOCKS, blk, 0, stream>>>(
            idx1, outp + 2 * (size_t)EDGES, h * HALF, P32, offs);
        reduce2_sorted_kernel<<<BINS, blk, 0, stream>>>(P32, offs, s2, r2, h);
    }

    // ---- normalize ----
    segdiv01_kernel<<<EDGES / 1024, blk, 0, stream>>>(outp, idx0, r01);
    segdiv2_kernel<<<EDGES / 1024, blk, 0, stream>>>(outp, idx1, r2);
}

// Round 14
// 446.042 us; speedup vs baseline: 1.7265x; 1.0250x over previous
//
#include <hip/hip_runtime.h>
#include <math.h>

#define B_GRAPHS 8192
#define OUT_DIM 1024
#define NU 128
#define NS 8
#define IN_DIM 1160          // OUT_DIM + NU + NS
#define KPAD1 1216           // IN_DIM padded to multiple of 64
#define HID 256
#define NSEG (B_GRAPHS * NU)        // 1048576 = 2^20
#define EDGES (B_GRAPHS * OUT_DIM)  // 8388608 = 2^23

// ---- binning parameters ----
#define BINS 512                    // seg >> 11
#define SEGS_PER_BIN 2048
#define HALF (EDGES / 2)            // 4194304 edges per pass
#define SCHUNK 4096                 // edges per scatter block -> 1024 blocks
#define SBLOCKS (HALF / SCHUNK)     // 1024
#define EPT (SCHUNK / 256)          // 16 edges per thread

typedef __attribute__((ext_vector_type(8))) short short8;
typedef __attribute__((ext_vector_type(4))) float f32x4;
typedef __attribute__((ext_vector_type(4))) int i32x4;

__device__ __forceinline__ unsigned short f2bf(float f) {
    unsigned u = __float_as_uint(f);
    const unsigned r = (u >> 16) & 1u;
    return (unsigned short)((u + 0x7fffu + r) >> 16);   // RNE
}
__device__ __forceinline__ float bf2f(unsigned short b) {
    return __uint_as_float((unsigned)b << 16);
}

// async global->LDS direct load, 16B per lane (wave-linear LDS dest)
__device__ __forceinline__ void gload_lds16(const void* g, void* l) {
    __builtin_amdgcn_global_load_lds(
        (const __attribute__((address_space(1))) unsigned int*)g,
        (__attribute__((address_space(3))) unsigned int*)l, 16, 0, 0);
}

// ================= prep: fp32 -> bf16 conversions ==========================
__global__ __launch_bounds__(256) void convert_feats_kernel(
    const float* __restrict__ u2s, const float* __restrict__ usr,
    const float* __restrict__ srv, unsigned short* __restrict__ F)
{
    const int t = blockIdx.x * 256 + threadIdx.x;   // 8192*152 threads
    const int row = t / 152;
    const int g = t - row * 152;
    const int col = g * 8;
    float v[8];
    if (g < 128) {
        const float4 a = *(const float4*)&u2s[(size_t)row * OUT_DIM + col];
        const float4 b = *(const float4*)&u2s[(size_t)row * OUT_DIM + col + 4];
        v[0]=a.x; v[1]=a.y; v[2]=a.z; v[3]=a.w; v[4]=b.x; v[5]=b.y; v[6]=b.z; v[7]=b.w;
    } else if (g < 144) {
        const int c = col - OUT_DIM;
        const float4 a = *(const float4*)&usr[(size_t)row * NU + c];
        const float4 b = *(const float4*)&usr[(size_t)row * NU + c + 4];
        v[0]=a.x; v[1]=a.y; v[2]=a.z; v[3]=a.w; v[4]=b.x; v[5]=b.y; v[6]=b.z; v[7]=b.w;
    } else if (g == 144) {
        const float4 a = *(const float4*)&srv[(size_t)row * NS];
        const float4 b = *(const float4*)&srv[(size_t)row * NS + 4];
        v[0]=a.x; v[1]=a.y; v[2]=a.z; v[3]=a.w; v[4]=b.x; v[5]=b.y; v[6]=b.z; v[7]=b.w;
    } else {
        for (int i = 0; i < 8; ++i) v[i] = 0.f;
    }
    unsigned short o[8];
    for (int i = 0; i < 8; ++i) o[i] = f2bf(v[i]);
    *reinterpret_cast<short8*>(&F[(size_t)row * KPAD1 + col]) =
        *reinterpret_cast<const short8*>(o);
}

__global__ __launch_bounds__(256) void convert_wT_kernel(
    const float* __restrict__ W, unsigned short* __restrict__ WT,
    int K, int N, int Kpad)
{
    const int t = blockIdx.x * 256 + threadIdx.x;
    if (t >= N * Kpad) return;
    const int n = t / Kpad;
    const int k = t - n * Kpad;
    WT[t] = (k < K) ? f2bf(W[(size_t)k * N + n]) : (unsigned short)0;
}

// ================= bf16 MFMA GEMM + global_load_lds staging ================
template <int EPI>
__global__ __launch_bounds__(256) void gemm_bf16_kernel(
    const unsigned short* __restrict__ A, const unsigned short* __restrict__ BT,
    const float* __restrict__ bias, void* __restrict__ outv, int N, int K)
{
    __shared__ alignas(16) unsigned short As[128 * 64];
    __shared__ alignas(16) unsigned short Bs[64 * 64];

    const int tid = threadIdx.x;
    const int lane = tid & 63;
    const int wid = tid >> 6;
    const int wm = wid >> 1;
    const int wn = wid & 1;
    const int m0 = blockIdx.y * 128;
    const int n0 = blockIdx.x * 64;

    const int srow = lane >> 3;
    const int schunk = lane & 7;
    const int sswz = schunk ^ srow;

    f32x4 acc[4][2];
#pragma unroll
    for (int i = 0; i < 4; ++i)
#pragma unroll
        for (int j = 0; j < 2; ++j) acc[i][j] = (f32x4)0.f;

    for (int k0 = 0; k0 < K; k0 += 64) {
#pragma unroll
        for (int i = 0; i < 4; ++i) {
            const int r = wid * 32 + i * 8 + srow;
            gload_lds16(&A[(size_t)(m0 + r) * K + k0 + sswz * 8],
                        &As[(wid * 32 + i * 8) * 64]);
        }
#pragma unroll
        for (int i = 0; i < 2; ++i) {
            const int r = wid * 16 + i * 8 + srow;
            gload_lds16(&BT[(size_t)(n0 + r) * K + k0 + sswz * 8],
                        &Bs[(wid * 16 + i * 8) * 64]);
        }
        __syncthreads();

#pragma unroll
        for (int ks = 0; ks < 2; ++ks) {
            short8 af[4], bf[2];
            const int c = ks * 4 + (lane >> 4);
#pragma unroll
            for (int fm = 0; fm < 4; ++fm) {
                const int r = wm * 64 + fm * 16 + (lane & 15);
                af[fm] = *reinterpret_cast<const short8*>(
                    &As[r * 64 + (c ^ (r & 7)) * 8]);
            }
#pragma unroll
            for (int fn = 0; fn < 2; ++fn) {
                const int r = wn * 32 + fn * 16 + (lane & 15);
                bf[fn] = *reinterpret_cast<const short8*>(
                    &Bs[r * 64 + (c ^ (r & 7)) * 8]);
            }
#pragma unroll
            for (int fm = 0; fm < 4; ++fm)
#pragma unroll
                for (int fn = 0; fn < 2; ++fn)
                    acc[fm][fn] = __builtin_amdgcn_mfma_f32_16x16x32_bf16(
                        af[fm], bf[fn], acc[fm][fn], 0, 0, 0);
        }
        __syncthreads();
    }

    // C/D layout: col = lane&15, row = (lane>>4)*4 + reg
#pragma unroll
    for (int fn = 0; fn < 2; ++fn) {
        const int col = n0 + wn * 32 + fn * 16 + (lane & 15);
        const float bv = bias[col];
#pragma unroll
        for (int fm = 0; fm < 4; ++fm) {
            const int rbase = m0 + wm * 64 + fm * 16 + (lane >> 4) * 4;
#pragma unroll
            for (int e = 0; e < 4; ++e) {
                const float v = acc[fm][fn][e] + bv;
                if (EPI == 0) {
                    unsigned short* h = (unsigned short*)outv;
                    h[(size_t)(rbase + e) * N + col] = f2bf(fmaxf(v, 0.f));
                } else {
                    float* out = (float*)outv;
                    const int p = col >> 10;
                    const int w = col & 1023;
                    out[(size_t)p * EDGES + (size_t)(rbase + e) * OUT_DIM + w] =
                        __expf(v);
                }
            }
        }
    }
}

// ==== scatter sections 0+1 combined: u64 record, block counting sort =======
// record = seg_low(11) << 32 | bf16(e0) << 16 | bf16(e1)
__global__ __launch_bounds__(256) void scatter01_sort_kernel(
    const int* __restrict__ idx, const float* __restrict__ v0,
    const float* __restrict__ v1, int w0,
    unsigned long long* __restrict__ P, unsigned* __restrict__ offs)
{
    __shared__ unsigned hist[BINS];
    __shared__ unsigned lofs[BINS];
    __shared__ unsigned scanbuf[256];
    __shared__ alignas(16) unsigned long long recs[SCHUNK];   // 32 KB

    const int tid = threadIdx.x;
    const int blk = blockIdx.x;
    const int base = w0 + blk * SCHUNK;

    for (int b = tid; b < BINS; b += 256) hist[b] = 0;
    __syncthreads();

    unsigned val_r[EPT];     // packed bf16(e0)<<16 | bf16(e1)
    unsigned meta_r[EPT];    // bin << 16 | seg_low
#pragma unroll
    for (int i = 0; i < EPT; ++i) {
        const int w = base + i * 256 + tid;
        const int seg = __builtin_nontemporal_load(&idx[w]);
        const float e0 = __builtin_nontemporal_load(&v0[w]);
        const float e1 = __builtin_nontemporal_load(&v1[w]);
        const unsigned bin = (unsigned)seg >> 11;
        meta_r[i] = (bin << 16) | ((unsigned)seg & 2047u);
        val_r[i] = ((unsigned)f2bf(e0) << 16) | f2bf(e1);
        atomicAdd(&hist[bin], 1u);
    }
    __syncthreads();

    // exclusive scan over 512 bins (pairs per thread)
    const unsigned h0 = hist[2 * tid];
    const unsigned h1 = hist[2 * tid + 1];
    const unsigned pairsum = h0 + h1;
    scanbuf[tid] = pairsum;
    __syncthreads();
    for (int d = 1; d < 256; d <<= 1) {
        const unsigned v = (tid >= d) ? scanbuf[tid - d] : 0u;
        __syncthreads();
        scanbuf[tid] += v;
        __syncthreads();
    }
    const unsigned excl = scanbuf[tid] - pairsum;
    hist[2 * tid] = excl;
    hist[2 * tid + 1] = excl + h0;
    lofs[2 * tid] = 0;
    lofs[2 * tid + 1] = 0;
    offs[(size_t)blk * BINS + 2 * tid] = excl;
    offs[(size_t)blk * BINS + 2 * tid + 1] = excl + h0;
    __syncthreads();

#pragma unroll
    for (int i = 0; i < EPT; ++i) {
        const unsigned bin = meta_r[i] >> 16;
        const unsigned p = hist[bin] + atomicAdd(&lofs[bin], 1u);
        recs[p] = ((unsigned long long)(meta_r[i] & 2047u) << 32) | val_r[i];
    }
    __syncthreads();

    const ulonglong2* rs = reinterpret_cast<const ulonglong2*>(recs);
    ulonglong2* dst = reinterpret_cast<ulonglong2*>(&P[(size_t)blk * SCHUNK]);
#pragma unroll
    for (int i = 0; i < SCHUNK / 512; ++i)    // 8 iters of 16B stores
        dst[i * 256 + tid] = rs[i * 256 + tid];
}

__global__ __launch_bounds__(256) void reduce01_sorted_kernel(
    const unsigned long long* __restrict__ P, const unsigned* __restrict__ offs,
    float2* __restrict__ s01, unsigned* __restrict__ r01, int last)
{
    __shared__ float sub0[SEGS_PER_BIN];
    __shared__ float sub1[SEGS_PER_BIN];
    const int b = blockIdx.x;
    const int tid = threadIdx.x;
    for (int i = tid; i < SEGS_PER_BIN; i += 256) { sub0[i] = 0.f; sub1[i] = 0.f; }
    __syncthreads();

    for (int blk = tid; blk < SBLOCKS; blk += 256) {
        const unsigned st = offs[(size_t)blk * BINS + b];
        const unsigned en =
            (b == BINS - 1) ? SCHUNK : offs[(size_t)blk * BINS + b + 1];
        const unsigned long long* rec = &P[(size_t)blk * SCHUNK];
        for (unsigned i = st; i < en; ++i) {
            const unsigned long long r = rec[i];
            const int sl = (int)(r >> 32);
            const unsigned lo = (unsigned)r;
            atomicAdd(&sub0[sl], __uint_as_float(lo & 0xffff0000u));
            atomicAdd(&sub1[sl], __uint_as_float(lo << 16));
        }
    }
    __syncthreads();

    for (int i = tid; i < SEGS_PER_BIN; i += 256) {
        const int seg = b * SEGS_PER_BIN + i;
        if (!last) {
            s01[seg] = make_float2(sub0[i], sub1[i]);
        } else {
            const float2 p = s01[seg];
            const float s0f = sub0[i] + p.x;
            const float s1f = sub1[i] + p.y;
            r01[seg] = ((unsigned)f2bf(1.f / s0f) << 16) | f2bf(1.f / s1f);
        }
    }
}

// ==== section-2 scatter/reduce: u32 records ================================
__global__ __launch_bounds__(256) void scatter2_sort_kernel(
    const int* __restrict__ idx, const float* __restrict__ vals, int w0,
    unsigned* __restrict__ P, unsigned* __restrict__ offs)
{
    __shared__ unsigned hist[BINS];
    __shared__ unsigned lofs[BINS];
    __shared__ unsigned scanbuf[256];
    __shared__ alignas(16) unsigned recs[SCHUNK];   // 16 KB

    const int tid = threadIdx.x;
    const int blk = blockIdx.x;
    const int base = w0 + blk * SCHUNK;

    for (int b = tid; b < BINS; b += 256) hist[b] = 0;
    __syncthreads();

    unsigned rec_r[EPT];
    unsigned short bin_r[EPT];
#pragma unroll
    for (int i = 0; i < EPT; ++i) {
        const int w = base + i * 256 + tid;
        const int seg = __builtin_nontemporal_load(&idx[w]);
        const float e = __builtin_nontemporal_load(&vals[w]);
        bin_r[i] = (unsigned short)((unsigned)seg >> 11);
        rec_r[i] = (((unsigned)seg & 2047u) << 16) | f2bf(e);
        atomicAdd(&hist[bin_r[i]], 1u);
    }
    __syncthreads();

    const unsigned h0 = hist[2 * tid];
    const unsigned h1 = hist[2 * tid + 1];
    const unsigned pairsum = h0 + h1;
    scanbuf[tid] = pairsum;
    __syncthreads();
    for (int d = 1; d < 256; d <<= 1) {
        const unsigned v = (tid >= d) ? scanbuf[tid - d] : 0u;
        __syncthreads();
        scanbuf[tid] += v;
        __syncthreads();
    }
    const unsigned excl = scanbuf[tid] - pairsum;
    hist[2 * tid] = excl;
    hist[2 * tid + 1] = excl + h0;
    lofs[2 * tid] = 0;
    lofs[2 * tid + 1] = 0;
    offs[(size_t)blk * BINS + 2 * tid] = excl;
    offs[(size_t)blk * BINS + 2 * tid + 1] = excl + h0;
    __syncthreads();

#pragma unroll
    for (int i = 0; i < EPT; ++i) {
        const unsigned p = hist[bin_r[i]] + atomicAdd(&lofs[bin_r[i]], 1u);
        recs[p] = rec_r[i];
    }
    __syncthreads();

    const uint4* rs = reinterpret_cast<const uint4*>(recs);
    uint4* dst = reinterpret_cast<uint4*>(&P[(size_t)blk * SCHUNK]);
#pragma unroll
    for (int i = 0; i < SCHUNK / 1024; ++i)   // 4 iters
        dst[i * 256 + tid] = rs[i * 256 + tid];
}

__global__ __launch_bounds__(256) void reduce2_sorted_kernel(
    const unsigned* __restrict__ P, const unsigned* __restrict__ offs,
    float* __restrict__ s2, unsigned short* __restrict__ r2, int last)
{
    __shared__ float sub[SEGS_PER_BIN];
    const int b = blockIdx.x;
    const int tid = threadIdx.x;
    for (int i = tid; i < SEGS_PER_BIN; i += 256) sub[i] = 0.f;
    __syncthreads();

    for (int blk = tid; blk < SBLOCKS; blk += 256) {
        const unsigned st = offs[(size_t)blk * BINS + b];
        const unsigned en =
            (b == BINS - 1) ? SCHUNK : offs[(size_t)blk * BINS + b + 1];
        const unsigned* rec = &P[(size_t)blk * SCHUNK];
        for (unsigned i = st; i < en; ++i) {
            const unsigned r = rec[i];
            atomicAdd(&sub[r >> 16], __uint_as_float(r << 16));
        }
    }
    __syncthreads();

    for (int i = tid; i < SEGS_PER_BIN; i += 256) {
        const int seg = b * SEGS_PER_BIN + i;
        if (!last) s2[seg] = sub[i];
        else       r2[seg] = f2bf(1.f / (sub[i] + s2[seg]));
    }
}

// ============ normalize (plain loads) ======================================
__global__ __launch_bounds__(256) void segdiv01_kernel(
    float* __restrict__ vals, const int* __restrict__ idx0,
    const unsigned* __restrict__ r01)
{
    const int w4 = (blockIdx.x * 256 + threadIdx.x) * 4;
    if (w4 >= EDGES) return;
    const i32x4 iv = *reinterpret_cast<const i32x4*>(&idx0[w4]);
    f32x4 a = *reinterpret_cast<const f32x4*>(&vals[w4]);
    f32x4 b = *reinterpret_cast<const f32x4*>(&vals[(size_t)EDGES + w4]);
#pragma unroll
    for (int j = 0; j < 4; ++j) {
        const unsigned p = r01[iv[j]];
        a[j] *= __uint_as_float(p & 0xffff0000u);
        b[j] *= __uint_as_float(p << 16);
    }
    *reinterpret_cast<f32x4*>(&vals[w4]) = a;
    *reinterpret_cast<f32x4*>(&vals[(size_t)EDGES + w4]) = b;
}

__global__ __launch_bounds__(256) void segdiv2_kernel(
    float* __restrict__ vals, const int* __restrict__ idx1,
    const unsigned short* __restrict__ r2)
{
    const int w4 = (blockIdx.x * 256 + threadIdx.x) * 4;
    if (w4 >= EDGES) return;
    const i32x4 iv = *reinterpret_cast<const i32x4*>(&idx1[w4]);
    f32x4 c = *reinterpret_cast<const f32x4*>(&vals[2 * (size_t)EDGES + w4]);
#pragma unroll
    for (int j = 0; j < 4; ++j) c[j] *= bf2f(r2[iv[j]]);
    *reinterpret_cast<f32x4*>(&vals[2 * (size_t)EDGES + w4]) = c;
}

// ===========================================================================
extern "C" void kernel_launch(void* const* d_in, const int* in_sizes, int n_in,
                              void* d_out, int out_size, void* d_ws,
                              size_t ws_size, hipStream_t stream) {
    const float* u2s = (const float*)d_in[0];
    const float* usr = (const float*)d_in[1];
    const float* srv = (const float*)d_in[2];
    const int* edge = (const int*)d_in[3];
    const float* W1 = (const float*)d_in[4];
    const float* b1 = (const float*)d_in[5];
    const float* W2 = (const float*)d_in[6];
    const float* b2 = (const float*)d_in[7];
    const float* W3 = (const float*)d_in[8];
    const float* b3 = (const float*)d_in[9];
    const float* W4 = (const float*)d_in[10];
    const float* b4 = (const float*)d_in[11];

    const int* idx0 = edge;
    const int* idx1 = edge + EDGES;

    // ws layout (peak 47 MiB; 48 MiB proven in round 1):
    //  phase1: F [0,19.9) | h1 [20,24) | h2 [24,28) | h3 [28,32) | wT [41,43.4)
    //  phase2: P [0,32) | offs [32,34) | s01 [34,42) | r01 [42,46) | r2 [46,47)
    //          s2 [34,38) (aliases s01 once dead)
    char* ws = (char*)d_ws;
    unsigned short* F = (unsigned short*)ws;
    unsigned short* h1 = (unsigned short*)(ws + 20ull * 1024 * 1024);
    unsigned short* h2 = (unsigned short*)(ws + 24ull * 1024 * 1024);
    unsigned short* h3 = (unsigned short*)(ws + 28ull * 1024 * 1024);
    unsigned short* w1t = (unsigned short*)(ws + 41ull * 1024 * 1024);
    unsigned short* w2t = w1t + (size_t)HID * KPAD1;
    unsigned short* w3t = w2t + (size_t)HID * HID;
    unsigned short* w4t = w3t + (size_t)HID * HID;

    unsigned long long* P64 = (unsigned long long*)ws;
    unsigned* P32 = (unsigned*)ws;
    unsigned* offs = (unsigned*)(ws + 32ull * 1024 * 1024);
    float2* s01 = (float2*)(ws + 34ull * 1024 * 1024);
    float* s2 = (float*)(ws + 34ull * 1024 * 1024);      // aliases dead s01
    unsigned* r01 = (unsigned*)(ws + 42ull * 1024 * 1024);
    unsigned short* r2 = (unsigned short*)(ws + 46ull * 1024 * 1024);

    float* outp = (float*)d_out;
    const dim3 blk(256);

    // ---- prep: conversions ----
    convert_feats_kernel<<<(B_GRAPHS * 152) / 256, blk, 0, stream>>>(u2s, usr,
                                                                     srv, F);
    convert_wT_kernel<<<(HID * KPAD1 + 255) / 256, blk, 0, stream>>>(
        W1, w1t, IN_DIM, HID, KPAD1);
    convert_wT_kernel<<<(HID * HID + 255) / 256, blk, 0, stream>>>(
        W2, w2t, HID, HID, HID);
    convert_wT_kernel<<<(HID * HID + 255) / 256, blk, 0, stream>>>(
        W3, w3t, HID, HID, HID);
    convert_wT_kernel<<<(3 * OUT_DIM * HID + 255) / 256, blk, 0, stream>>>(
        W4, w4t, HID, 3 * OUT_DIM, HID);

    // ---- MLP (bf16 MFMA, global_load_lds staging) ----
    gemm_bf16_kernel<0><<<dim3(HID / 64, B_GRAPHS / 128), blk, 0, stream>>>(
        F, w1t, b1, h1, HID, KPAD1);
    gemm_bf16_kernel<0><<<dim3(HID / 64, B_GRAPHS / 128), blk, 0, stream>>>(
        h1, w2t, b2, h2, HID, HID);
    gemm_bf16_kernel<0><<<dim3(HID / 64, B_GRAPHS / 128), blk, 0, stream>>>(
        h2, w3t, b3, h3, HID, HID);
    gemm_bf16_kernel<1><<<dim3(3 * OUT_DIM / 64, B_GRAPHS / 128), blk, 0,
                          stream>>>(h3, w4t, b4, outp, 3 * OUT_DIM, HID);

    // ---- segment sums ----
    // sections 0+1 (idx0, u64 records): 2 halves; last reduce packs r01
    for (int h = 0; h < 2; ++h) {
        scatter01_sort_kernel<<<SBLOCKS, blk, 0, stream>>>(
            idx0, outp, outp + (size_t)EDGES, h * HALF, P64, offs);
        reduce01_sorted_kernel<<<BINS, blk, 0, stream>>>(P64, offs, s01, r01,
                                                         h);
    }
    // section 2 (idx1, u32 records): 2 halves; last reduce writes r2
    for (int h = 0; h < 2; ++h) {
        scatter2_sort_kernel<<<SBLOCKS, blk, 0, stream>>>(
            idx1, outp + 2 * (size_t)EDGES, h * HALF, P32, offs);
        reduce2_sorted_kernel<<<BINS, blk, 0, stream>>>(P32, offs, s2, r2, h);
    }

    // ---- normalize ----
    segdiv01_kernel<<<EDGES / 1024, blk, 0, stream>>>(outp, idx0, r01);
    segdiv2_kernel<<<EDGES / 1024, blk, 0, stream>>>(outp, idx1, r2);
}

// Round 15
// 437.490 us; speedup vs baseline: 1.7602x; 1.0195x over previous
//
#include <hip/hip_runtime.h>
#include <math.h>

#define B_GRAPHS 8192
#define OUT_DIM 1024
#define NU 128
#define NS 8
#define IN_DIM 1160          // OUT_DIM + NU + NS
#define KPAD1 1216           // IN_DIM padded to multiple of 64
#define HID 256
#define NSEG (B_GRAPHS * NU)        // 1048576 = 2^20
#define EDGES (B_GRAPHS * OUT_DIM)  // 8388608 = 2^23

// ---- binning parameters ----
#define BINS 512                    // seg >> 11
#define SEGS_PER_BIN 2048
#define HALF (EDGES / 2)            // 4194304 edges per pass
#define SCHUNK 4096                 // edges per scatter block -> 1024 blocks
#define SBLOCKS (HALF / SCHUNK)     // 1024
#define EPT (SCHUNK / 256)          // 16 edges per thread

typedef __attribute__((ext_vector_type(8))) short short8;
typedef __attribute__((ext_vector_type(4))) float f32x4;
typedef __attribute__((ext_vector_type(4))) int i32x4;

__device__ __forceinline__ unsigned short f2bf(float f) {
    unsigned u = __float_as_uint(f);
    const unsigned r = (u >> 16) & 1u;
    return (unsigned short)((u + 0x7fffu + r) >> 16);   // RNE
}
__device__ __forceinline__ float bf2f(unsigned short b) {
    return __uint_as_float((unsigned)b << 16);
}

// async global->LDS direct load, 16B per lane (wave-linear LDS dest)
__device__ __forceinline__ void gload_lds16(const void* g, void* l) {
    __builtin_amdgcn_global_load_lds(
        (const __attribute__((address_space(1))) unsigned int*)g,
        (__attribute__((address_space(3))) unsigned int*)l, 16, 0, 0);
}

// ================= prep: fp32 -> bf16 conversions ==========================
__global__ __launch_bounds__(256) void convert_feats_kernel(
    const float* __restrict__ u2s, const float* __restrict__ usr,
    const float* __restrict__ srv, unsigned short* __restrict__ F)
{
    const int t = blockIdx.x * 256 + threadIdx.x;   // 8192*152 threads
    const int row = t / 152;
    const int g = t - row * 152;
    const int col = g * 8;
    float v[8];
    if (g < 128) {
        const float4 a = *(const float4*)&u2s[(size_t)row * OUT_DIM + col];
        const float4 b = *(const float4*)&u2s[(size_t)row * OUT_DIM + col + 4];
        v[0]=a.x; v[1]=a.y; v[2]=a.z; v[3]=a.w; v[4]=b.x; v[5]=b.y; v[6]=b.z; v[7]=b.w;
    } else if (g < 144) {
        const int c = col - OUT_DIM;
        const float4 a = *(const float4*)&usr[(size_t)row * NU + c];
        const float4 b = *(const float4*)&usr[(size_t)row * NU + c + 4];
        v[0]=a.x; v[1]=a.y; v[2]=a.z; v[3]=a.w; v[4]=b.x; v[5]=b.y; v[6]=b.z; v[7]=b.w;
    } else if (g == 144) {
        const float4 a = *(const float4*)&srv[(size_t)row * NS];
        const float4 b = *(const float4*)&srv[(size_t)row * NS + 4];
        v[0]=a.x; v[1]=a.y; v[2]=a.z; v[3]=a.w; v[4]=b.x; v[5]=b.y; v[6]=b.z; v[7]=b.w;
    } else {
        for (int i = 0; i < 8; ++i) v[i] = 0.f;
    }
    unsigned short o[8];
    for (int i = 0; i < 8; ++i) o[i] = f2bf(v[i]);
    *reinterpret_cast<short8*>(&F[(size_t)row * KPAD1 + col]) =
        *reinterpret_cast<const short8*>(o);
}

__global__ __launch_bounds__(256) void convert_wT_kernel(
    const float* __restrict__ W, unsigned short* __restrict__ WT,
    int K, int N, int Kpad)
{
    const int t = blockIdx.x * 256 + threadIdx.x;
    if (t >= N * Kpad) return;
    const int n = t / Kpad;
    const int k = t - n * Kpad;
    WT[t] = (k < K) ? f2bf(W[(size_t)k * N + n]) : (unsigned short)0;
}

// ================= bf16 MFMA GEMM + global_load_lds staging ================
template <int EPI>
__global__ __launch_bounds__(256) void gemm_bf16_kernel(
    const unsigned short* __restrict__ A, const unsigned short* __restrict__ BT,
    const float* __restrict__ bias, void* __restrict__ outv, int N, int K)
{
    __shared__ alignas(16) unsigned short As[128 * 64];
    __shared__ alignas(16) unsigned short Bs[64 * 64];

    const int tid = threadIdx.x;
    const int lane = tid & 63;
    const int wid = tid >> 6;
    const int wm = wid >> 1;
    const int wn = wid & 1;
    const int m0 = blockIdx.y * 128;
    const int n0 = blockIdx.x * 64;

    const int srow = lane >> 3;
    const int schunk = lane & 7;
    const int sswz = schunk ^ srow;

    f32x4 acc[4][2];
#pragma unroll
    for (int i = 0; i < 4; ++i)
#pragma unroll
        for (int j = 0; j < 2; ++j) acc[i][j] = (f32x4)0.f;

    for (int k0 = 0; k0 < K; k0 += 64) {
#pragma unroll
        for (int i = 0; i < 4; ++i) {
            const int r = wid * 32 + i * 8 + srow;
            gload_lds16(&A[(size_t)(m0 + r) * K + k0 + sswz * 8],
                        &As[(wid * 32 + i * 8) * 64]);
        }
#pragma unroll
        for (int i = 0; i < 2; ++i) {
            const int r = wid * 16 + i * 8 + srow;
            gload_lds16(&BT[(size_t)(n0 + r) * K + k0 + sswz * 8],
                        &Bs[(wid * 16 + i * 8) * 64]);
        }
        __syncthreads();

#pragma unroll
        for (int ks = 0; ks < 2; ++ks) {
            short8 af[4], bf[2];
            const int c = ks * 4 + (lane >> 4);
#pragma unroll
            for (int fm = 0; fm < 4; ++fm) {
                const int r = wm * 64 + fm * 16 + (lane & 15);
                af[fm] = *reinterpret_cast<const short8*>(
                    &As[r * 64 + (c ^ (r & 7)) * 8]);
            }
#pragma unroll
            for (int fn = 0; fn < 2; ++fn) {
                const int r = wn * 32 + fn * 16 + (lane & 15);
                bf[fn] = *reinterpret_cast<const short8*>(
                    &Bs[r * 64 + (c ^ (r & 7)) * 8]);
            }
#pragma unroll
            for (int fm = 0; fm < 4; ++fm)
#pragma unroll
                for (int fn = 0; fn < 2; ++fn)
                    acc[fm][fn] = __builtin_amdgcn_mfma_f32_16x16x32_bf16(
                        af[fm], bf[fn], acc[fm][fn], 0, 0, 0);
        }
        __syncthreads();
    }

    // C/D layout: col = lane&15, row = (lane>>4)*4 + reg
#pragma unroll
    for (int fn = 0; fn < 2; ++fn) {
        const int col = n0 + wn * 32 + fn * 16 + (lane & 15);
        const float bv = bias[col];
#pragma unroll
        for (int fm = 0; fm < 4; ++fm) {
            const int rbase = m0 + wm * 64 + fm * 16 + (lane >> 4) * 4;
#pragma unroll
            for (int e = 0; e < 4; ++e) {
                const float v = acc[fm][fn][e] + bv;
                if (EPI == 0) {
                    unsigned short* h = (unsigned short*)outv;
                    h[(size_t)(rbase + e) * N + col] = f2bf(fmaxf(v, 0.f));
                } else {
                    float* out = (float*)outv;
                    const int p = col >> 10;
                    const int w = col & 1023;
                    out[(size_t)p * EDGES + (size_t)(rbase + e) * OUT_DIM + w] =
                        __expf(v);
                }
            }
        }
    }
}

// ==== scatter sections 0+1 combined: u64 record, block counting sort =======
// record = seg_low(11) << 32 | bf16(e0) << 16 | bf16(e1).  Plain loads (NT
// reverted — r12 showed NT streams run ~2.4 TB/s vs ~3.8+ cached).
__global__ __launch_bounds__(256) void scatter01_sort_kernel(
    const int* __restrict__ idx, const float* __restrict__ v0,
    const float* __restrict__ v1, int w0,
    unsigned long long* __restrict__ P, unsigned* __restrict__ offs)
{
    __shared__ unsigned hist[BINS];
    __shared__ unsigned lofs[BINS];
    __shared__ unsigned scanbuf[256];
    __shared__ alignas(16) unsigned long long recs[SCHUNK];   // 32 KB

    const int tid = threadIdx.x;
    const int blk = blockIdx.x;
    const int base = w0 + blk * SCHUNK;

    for (int b = tid; b < BINS; b += 256) hist[b] = 0;
    __syncthreads();

    unsigned val_r[EPT];     // packed bf16(e0)<<16 | bf16(e1)
    unsigned meta_r[EPT];    // bin << 16 | seg_low
#pragma unroll
    for (int i = 0; i < EPT; ++i) {
        const int w = base + i * 256 + tid;
        const int seg = idx[w];
        const float e0 = v0[w];
        const float e1 = v1[w];
        const unsigned bin = (unsigned)seg >> 11;
        meta_r[i] = (bin << 16) | ((unsigned)seg & 2047u);
        val_r[i] = ((unsigned)f2bf(e0) << 16) | f2bf(e1);
        atomicAdd(&hist[bin], 1u);
    }
    __syncthreads();

    // exclusive scan over 512 bins (pairs per thread)
    const unsigned h0 = hist[2 * tid];
    const unsigned h1 = hist[2 * tid + 1];
    const unsigned pairsum = h0 + h1;
    scanbuf[tid] = pairsum;
    __syncthreads();
    for (int d = 1; d < 256; d <<= 1) {
        const unsigned v = (tid >= d) ? scanbuf[tid - d] : 0u;
        __syncthreads();
        scanbuf[tid] += v;
        __syncthreads();
    }
    const unsigned excl = scanbuf[tid] - pairsum;
    hist[2 * tid] = excl;
    hist[2 * tid + 1] = excl + h0;
    lofs[2 * tid] = 0;
    lofs[2 * tid + 1] = 0;
    offs[(size_t)blk * BINS + 2 * tid] = excl;
    offs[(size_t)blk * BINS + 2 * tid + 1] = excl + h0;
    __syncthreads();

#pragma unroll
    for (int i = 0; i < EPT; ++i) {
        const unsigned bin = meta_r[i] >> 16;
        const unsigned p = hist[bin] + atomicAdd(&lofs[bin], 1u);
        recs[p] = ((unsigned long long)(meta_r[i] & 2047u) << 32) | val_r[i];
    }
    __syncthreads();

    const ulonglong2* rs = reinterpret_cast<const ulonglong2*>(recs);
    ulonglong2* dst = reinterpret_cast<ulonglong2*>(&P[(size_t)blk * SCHUNK]);
#pragma unroll
    for (int i = 0; i < SCHUNK / 512; ++i)    // 8 iters of 16B stores
        dst[i * 256 + tid] = rs[i * 256 + tid];
}

// last pass writes per-section reciprocal tables r0, r1 (bf16 u16, 2 MiB each)
__global__ __launch_bounds__(256) void reduce01_sorted_kernel(
    const unsigned long long* __restrict__ P, const unsigned* __restrict__ offs,
    float2* __restrict__ s01, unsigned short* __restrict__ r0,
    unsigned short* __restrict__ r1, int last)
{
    __shared__ float sub0[SEGS_PER_BIN];
    __shared__ float sub1[SEGS_PER_BIN];
    const int b = blockIdx.x;
    const int tid = threadIdx.x;
    for (int i = tid; i < SEGS_PER_BIN; i += 256) { sub0[i] = 0.f; sub1[i] = 0.f; }
    __syncthreads();

    for (int blk = tid; blk < SBLOCKS; blk += 256) {
        const unsigned st = offs[(size_t)blk * BINS + b];
        const unsigned en =
            (b == BINS - 1) ? SCHUNK : offs[(size_t)blk * BINS + b + 1];
        const unsigned long long* rec = &P[(size_t)blk * SCHUNK];
        for (unsigned i = st; i < en; ++i) {
            const unsigned long long r = rec[i];
            const int sl = (int)(r >> 32);
            const unsigned lo = (unsigned)r;
            atomicAdd(&sub0[sl], __uint_as_float(lo & 0xffff0000u));
            atomicAdd(&sub1[sl], __uint_as_float(lo << 16));
        }
    }
    __syncthreads();

    for (int i = tid; i < SEGS_PER_BIN; i += 256) {
        const int seg = b * SEGS_PER_BIN + i;
        if (!last) {
            s01[seg] = make_float2(sub0[i], sub1[i]);
        } else {
            const float2 p = s01[seg];
            r0[seg] = f2bf(1.f / (sub0[i] + p.x));
            r1[seg] = f2bf(1.f / (sub1[i] + p.y));
        }
    }
}

// ==== section-2 scatter/reduce: u32 records ================================
__global__ __launch_bounds__(256) void scatter2_sort_kernel(
    const int* __restrict__ idx, const float* __restrict__ vals, int w0,
    unsigned* __restrict__ P, unsigned* __restrict__ offs)
{
    __shared__ unsigned hist[BINS];
    __shared__ unsigned lofs[BINS];
    __shared__ unsigned scanbuf[256];
    __shared__ alignas(16) unsigned recs[SCHUNK];   // 16 KB

    const int tid = threadIdx.x;
    const int blk = blockIdx.x;
    const int base = w0 + blk * SCHUNK;

    for (int b = tid; b < BINS; b += 256) hist[b] = 0;
    __syncthreads();

    unsigned rec_r[EPT];
    unsigned short bin_r[EPT];
#pragma unroll
    for (int i = 0; i < EPT; ++i) {
        const int w = base + i * 256 + tid;
        const int seg = idx[w];
        const float e = vals[w];
        bin_r[i] = (unsigned short)((unsigned)seg >> 11);
        rec_r[i] = (((unsigned)seg & 2047u) << 16) | f2bf(e);
        atomicAdd(&hist[bin_r[i]], 1u);
    }
    __syncthreads();

    const unsigned h0 = hist[2 * tid];
    const unsigned h1 = hist[2 * tid + 1];
    const unsigned pairsum = h0 + h1;
    scanbuf[tid] = pairsum;
    __syncthreads();
    for (int d = 1; d < 256; d <<= 1) {
        const unsigned v = (tid >= d) ? scanbuf[tid - d] : 0u;
        __syncthreads();
        scanbuf[tid] += v;
        __syncthreads();
    }
    const unsigned excl = scanbuf[tid] - pairsum;
    hist[2 * tid] = excl;
    hist[2 * tid + 1] = excl + h0;
    lofs[2 * tid] = 0;
    lofs[2 * tid + 1] = 0;
    offs[(size_t)blk * BINS + 2 * tid] = excl;
    offs[(size_t)blk * BINS + 2 * tid + 1] = excl + h0;
    __syncthreads();

#pragma unroll
    for (int i = 0; i < EPT; ++i) {
        const unsigned p = hist[bin_r[i]] + atomicAdd(&lofs[bin_r[i]], 1u);
        recs[p] = rec_r[i];
    }
    __syncthreads();

    const uint4* rs = reinterpret_cast<const uint4*>(recs);
    uint4* dst = reinterpret_cast<uint4*>(&P[(size_t)blk * SCHUNK]);
#pragma unroll
    for (int i = 0; i < SCHUNK / 1024; ++i)   // 4 iters
        dst[i * 256 + tid] = rs[i * 256 + tid];
}

__global__ __launch_bounds__(256) void reduce2_sorted_kernel(
    const unsigned* __restrict__ P, const unsigned* __restrict__ offs,
    float* __restrict__ s2, unsigned short* __restrict__ r2, int last)
{
    __shared__ float sub[SEGS_PER_BIN];
    const int b = blockIdx.x;
    const int tid = threadIdx.x;
    for (int i = tid; i < SEGS_PER_BIN; i += 256) sub[i] = 0.f;
    __syncthreads();

    for (int blk = tid; blk < SBLOCKS; blk += 256) {
        const unsigned st = offs[(size_t)blk * BINS + b];
        const unsigned en =
            (b == BINS - 1) ? SCHUNK : offs[(size_t)blk * BINS + b + 1];
        const unsigned* rec = &P[(size_t)blk * SCHUNK];
        for (unsigned i = st; i < en; ++i) {
            const unsigned r = rec[i];
            atomicAdd(&sub[r >> 16], __uint_as_float(r << 16));
        }
    }
    __syncthreads();

    for (int i = tid; i < SEGS_PER_BIN; i += 256) {
        const int seg = b * SEGS_PER_BIN + i;
        if (!last) s2[seg] = sub[i];
        else       r2[seg] = f2bf(1.f / (sub[i] + s2[seg]));
    }
}

// ============ normalize: one section per pass, 2 MiB table stays L2-hot ====
__global__ __launch_bounds__(256) void segdiv_sec_kernel(
    float* __restrict__ vals, const int* __restrict__ idx,
    const unsigned short* __restrict__ rtab)
{
    const int w4 = (blockIdx.x * 256 + threadIdx.x) * 4;
    if (w4 >= EDGES) return;
    const i32x4 iv = *reinterpret_cast<const i32x4*>(&idx[w4]);
    f32x4 a = *reinterpret_cast<const f32x4*>(&vals[w4]);
#pragma unroll
    for (int j = 0; j < 4; ++j) a[j] *= bf2f(rtab[iv[j]]);
    *reinterpret_cast<f32x4*>(&vals[w4]) = a;
}

// ===========================================================================
extern "C" void kernel_launch(void* const* d_in, const int* in_sizes, int n_in,
                              void* d_out, int out_size, void* d_ws,
                              size_t ws_size, hipStream_t stream) {
    const float* u2s = (const float*)d_in[0];
    const float* usr = (const float*)d_in[1];
    const float* srv = (const float*)d_in[2];
    const int* edge = (const int*)d_in[3];
    const float* W1 = (const float*)d_in[4];
    const float* b1 = (const float*)d_in[5];
    const float* W2 = (const float*)d_in[6];
    const float* b2 = (const float*)d_in[7];
    const float* W3 = (const float*)d_in[8];
    const float* b3 = (const float*)d_in[9];
    const float* W4 = (const float*)d_in[10];
    const float* b4 = (const float*)d_in[11];

    const int* idx0 = edge;
    const int* idx1 = edge + EDGES;

    // ws layout (peak 48 MiB; 48 MiB proven in round 1):
    //  phase1: F [0,19.9) | h1 [20,24) | h2 [24,28) | h3 [28,32) | wT [41,43.4)
    //  phase2: P [0,32) | offs [32,34) | s01 [34,42) | r0 [42,44) | r1 [44,46)
    //          r2 [46,48) | s2 [34,38) (aliases s01 once dead)
    char* ws = (char*)d_ws;
    unsigned short* F = (unsigned short*)ws;
    unsigned short* h1 = (unsigned short*)(ws + 20ull * 1024 * 1024);
    unsigned short* h2 = (unsigned short*)(ws + 24ull * 1024 * 1024);
    unsigned short* h3 = (unsigned short*)(ws + 28ull * 1024 * 1024);
    unsigned short* w1t = (unsigned short*)(ws + 41ull * 1024 * 1024);
    unsigned short* w2t = w1t + (size_t)HID * KPAD1;
    unsigned short* w3t = w2t + (size_t)HID * HID;
    unsigned short* w4t = w3t + (size_t)HID * HID;

    unsigned long long* P64 = (unsigned long long*)ws;
    unsigned* P32 = (unsigned*)ws;
    unsigned* offs = (unsigned*)(ws + 32ull * 1024 * 1024);
    float2* s01 = (float2*)(ws + 34ull * 1024 * 1024);
    float* s2 = (float*)(ws + 34ull * 1024 * 1024);      // aliases dead s01
    unsigned short* r0 = (unsigned short*)(ws + 42ull * 1024 * 1024);
    unsigned short* r1 = (unsigned short*)(ws + 44ull * 1024 * 1024);
    unsigned short* r2 = (unsigned short*)(ws + 46ull * 1024 * 1024);

    float* outp = (float*)d_out;
    const dim3 blk(256);

    // ---- prep: conversions ----
    convert_feats_kernel<<<(B_GRAPHS * 152) / 256, blk, 0, stream>>>(u2s, usr,
                                                                     srv, F);
    convert_wT_kernel<<<(HID * KPAD1 + 255) / 256, blk, 0, stream>>>(
        W1, w1t, IN_DIM, HID, KPAD1);
    convert_wT_kernel<<<(HID * HID + 255) / 256, blk, 0, stream>>>(
        W2, w2t, HID, HID, HID);
    convert_wT_kernel<<<(HID * HID + 255) / 256, blk, 0, stream>>>(
        W3, w3t, HID, HID, HID);
    convert_wT_kernel<<<(3 * OUT_DIM * HID + 255) / 256, blk, 0, stream>>>(
        W4, w4t, HID, 3 * OUT_DIM, HID);

    // ---- MLP (bf16 MFMA, global_load_lds staging) ----
    gemm_bf16_kernel<0><<<dim3(HID / 64, B_GRAPHS / 128), blk, 0, stream>>>(
        F, w1t, b1, h1, HID, KPAD1);
    gemm_bf16_kernel<0><<<dim3(HID / 64, B_GRAPHS / 128), blk, 0, stream>>>(
        h1, w2t, b2, h2, HID, HID);
    gemm_bf16_kernel<0><<<dim3(HID / 64, B_GRAPHS / 128), blk, 0, stream>>>(
        h2, w3t, b3, h3, HID, HID);
    gemm_bf16_kernel<1><<<dim3(3 * OUT_DIM / 64, B_GRAPHS / 128), blk, 0,
                          stream>>>(h3, w4t, b4, outp, 3 * OUT_DIM, HID);

    // ---- segment sums ----
    // sections 0+1 (idx0, u64 records): 2 halves; last reduce writes r0,r1
    for (int h = 0; h < 2; ++h) {
        scatter01_sort_kernel<<<SBLOCKS, blk, 0, stream>>>(
            idx0, outp, outp + (size_t)EDGES, h * HALF, P64, offs);
        reduce01_sorted_kernel<<<BINS, blk, 0, stream>>>(P64, offs, s01, r0,
                                                         r1, h);
    }
    // section 2 (idx1, u32 records): 2 halves; last reduce writes r2
    for (int h = 0; h < 2; ++h) {
        scatter2_sort_kernel<<<SBLOCKS, blk, 0, stream>>>(
            idx1, outp + 2 * (size_t)EDGES, h * HALF, P32, offs);
        reduce2_sorted_kernel<<<BINS, blk, 0, stream>>>(P32, offs, s2, r2, h);
    }

    // ---- normalize: one pass per section, each table fits one L2 ----
    segdiv_sec_kernel<<<EDGES / 1024, blk, 0, stream>>>(outp, idx0, r0);
    segdiv_sec_kernel<<<EDGES / 1024, blk, 0, stream>>>(outp + (size_t)EDGES,
                                                        idx0, r1);
    segdiv_sec_kernel<<<EDGES / 1024, blk, 0, stream>>>(
        outp + 2 * (size_t)EDGES, idx1, r2);
}

// Round 16
// 423.191 us; speedup vs baseline: 1.8197x; 1.0338x over previous
//
#include <hip/hip_runtime.h>
#include <math.h>

#define B_GRAPHS 8192
#define OUT_DIM 1024
#define NU 128
#define NS 8
#define IN_DIM 1160          // OUT_DIM + NU + NS
#define KPAD1 1216           // IN_DIM padded to multiple of 64
#define HID 256
#define NSEG (B_GRAPHS * NU)        // 1048576 = 2^20
#define EDGES (B_GRAPHS * OUT_DIM)  // 8388608 = 2^23

// ---- binning parameters ----
#define BINS 512                    // seg >> 11
#define SEGS_PER_BIN 2048
#define HALF (EDGES / 2)            // 4194304 edges per pass
#define SCHUNK 4096                 // edges per scatter block -> 1024 blocks
#define SBLOCKS (HALF / SCHUNK)     // 1024
#define EPT (SCHUNK / 256)          // 16 edges per thread

typedef __attribute__((ext_vector_type(8))) short short8;
typedef __attribute__((ext_vector_type(4))) float f32x4;
typedef __attribute__((ext_vector_type(4))) int i32x4;

__device__ __forceinline__ unsigned short f2bf(float f) {
    unsigned u = __float_as_uint(f);
    const unsigned r = (u >> 16) & 1u;
    return (unsigned short)((u + 0x7fffu + r) >> 16);   // RNE
}
__device__ __forceinline__ float bf2f(unsigned short b) {
    return __uint_as_float((unsigned)b << 16);
}

// async global->LDS direct load, 16B per lane (wave-linear LDS dest)
__device__ __forceinline__ void gload_lds16(const void* g, void* l) {
    __builtin_amdgcn_global_load_lds(
        (const __attribute__((address_space(1))) unsigned int*)g,
        (__attribute__((address_space(3))) unsigned int*)l, 16, 0, 0);
}

// ================= prep: fp32 -> bf16 conversions ==========================
__global__ __launch_bounds__(256) void convert_feats_kernel(
    const float* __restrict__ u2s, const float* __restrict__ usr,
    const float* __restrict__ srv, unsigned short* __restrict__ F)
{
    const int t = blockIdx.x * 256 + threadIdx.x;   // 8192*152 threads
    const int row = t / 152;
    const int g = t - row * 152;
    const int col = g * 8;
    float v[8];
    if (g < 128) {
        const float4 a = *(const float4*)&u2s[(size_t)row * OUT_DIM + col];
        const float4 b = *(const float4*)&u2s[(size_t)row * OUT_DIM + col + 4];
        v[0]=a.x; v[1]=a.y; v[2]=a.z; v[3]=a.w; v[4]=b.x; v[5]=b.y; v[6]=b.z; v[7]=b.w;
    } else if (g < 144) {
        const int c = col - OUT_DIM;
        const float4 a = *(const float4*)&usr[(size_t)row * NU + c];
        const float4 b = *(const float4*)&usr[(size_t)row * NU + c + 4];
        v[0]=a.x; v[1]=a.y; v[2]=a.z; v[3]=a.w; v[4]=b.x; v[5]=b.y; v[6]=b.z; v[7]=b.w;
    } else if (g == 144) {
        const float4 a = *(const float4*)&srv[(size_t)row * NS];
        const float4 b = *(const float4*)&srv[(size_t)row * NS + 4];
        v[0]=a.x; v[1]=a.y; v[2]=a.z; v[3]=a.w; v[4]=b.x; v[5]=b.y; v[6]=b.z; v[7]=b.w;
    } else {
        for (int i = 0; i < 8; ++i) v[i] = 0.f;
    }
    unsigned short o[8];
    for (int i = 0; i < 8; ++i) o[i] = f2bf(v[i]);
    *reinterpret_cast<short8*>(&F[(size_t)row * KPAD1 + col]) =
        *reinterpret_cast<const short8*>(o);
}

// all four W[K][N] -> WT[N][Kpad] conversions in one launch
#define W1_ELEMS (HID * KPAD1)            // 311296
#define W23_ELEMS (HID * HID)             // 65536
#define W4_ELEMS (3 * OUT_DIM * HID)      // 786432
#define WT_TOTAL (W1_ELEMS + 2 * W23_ELEMS + W4_ELEMS)   // 1228800

__global__ __launch_bounds__(256) void convert_wT_all_kernel(
    const float* __restrict__ W1, const float* __restrict__ W2,
    const float* __restrict__ W3, const float* __restrict__ W4,
    unsigned short* __restrict__ w1t, unsigned short* __restrict__ w2t,
    unsigned short* __restrict__ w3t, unsigned short* __restrict__ w4t)
{
    int t = blockIdx.x * 256 + threadIdx.x;
    if (t >= WT_TOTAL) return;
    const float* W;
    unsigned short* WT;
    int K, N, Kpad;
    if (t < W1_ELEMS) {
        W = W1; WT = w1t; K = IN_DIM; N = HID; Kpad = KPAD1;
    } else if (t < W1_ELEMS + W23_ELEMS) {
        t -= W1_ELEMS;
        W = W2; WT = w2t; K = HID; N = HID; Kpad = HID;
    } else if (t < W1_ELEMS + 2 * W23_ELEMS) {
        t -= W1_ELEMS + W23_ELEMS;
        W = W3; WT = w3t; K = HID; N = HID; Kpad = HID;
    } else {
        t -= W1_ELEMS + 2 * W23_ELEMS;
        W = W4; WT = w4t; K = HID; N = 3 * OUT_DIM; Kpad = HID;
    }
    const int n = t / Kpad;
    const int k = t - n * Kpad;
    WT[t] = (k < K) ? f2bf(W[(size_t)k * N + n]) : (unsigned short)0;
}

// ================= bf16 MFMA GEMM + global_load_lds staging ================
// BM = FM*32 (FM=4 -> 128 rows, FM=2 -> 64 rows). BN=64, 4 waves (2x2),
// wave computes (FM*16) x 32 via acc[FM][2]. Swizzle on global source.
template <int FM, int EPI>
__global__ __launch_bounds__(256) void gemm_bf16_kernel(
    const unsigned short* __restrict__ A, const unsigned short* __restrict__ BT,
    const float* __restrict__ bias, void* __restrict__ outv, int N, int K)
{
    __shared__ alignas(16) unsigned short As[FM * 32 * 64];
    __shared__ alignas(16) unsigned short Bs[64 * 64];

    const int tid = threadIdx.x;
    const int lane = tid & 63;
    const int wid = tid >> 6;
    const int wm = wid >> 1;
    const int wn = wid & 1;
    const int m0 = blockIdx.y * (FM * 32);
    const int n0 = blockIdx.x * 64;

    const int srow = lane >> 3;
    const int schunk = lane & 7;
    const int sswz = schunk ^ srow;

    f32x4 acc[FM][2];
#pragma unroll
    for (int i = 0; i < FM; ++i)
#pragma unroll
        for (int j = 0; j < 2; ++j) acc[i][j] = (f32x4)0.f;

    for (int k0 = 0; k0 < K; k0 += 64) {
        // stage A: wave covers rows [wid*FM*8, wid*FM*8 + FM*8)
#pragma unroll
        for (int i = 0; i < FM; ++i) {
            const int r = wid * (FM * 8) + i * 8 + srow;
            gload_lds16(&A[(size_t)(m0 + r) * K + k0 + sswz * 8],
                        &As[(wid * (FM * 8) + i * 8) * 64]);
        }
        // stage B: wave covers rows [wid*16, wid*16+16)
#pragma unroll
        for (int i = 0; i < 2; ++i) {
            const int r = wid * 16 + i * 8 + srow;
            gload_lds16(&BT[(size_t)(n0 + r) * K + k0 + sswz * 8],
                        &Bs[(wid * 16 + i * 8) * 64]);
        }
        __syncthreads();

#pragma unroll
        for (int ks = 0; ks < 2; ++ks) {
            short8 af[FM], bf[2];
            const int c = ks * 4 + (lane >> 4);
#pragma unroll
            for (int fm = 0; fm < FM; ++fm) {
                const int r = wm * (FM * 16) + fm * 16 + (lane & 15);
                af[fm] = *reinterpret_cast<const short8*>(
                    &As[r * 64 + (c ^ (r & 7)) * 8]);
            }
#pragma unroll
            for (int fn = 0; fn < 2; ++fn) {
                const int r = wn * 32 + fn * 16 + (lane & 15);
                bf[fn] = *reinterpret_cast<const short8*>(
                    &Bs[r * 64 + (c ^ (r & 7)) * 8]);
            }
#pragma unroll
            for (int fm = 0; fm < FM; ++fm)
#pragma unroll
                for (int fn = 0; fn < 2; ++fn)
                    acc[fm][fn] = __builtin_amdgcn_mfma_f32_16x16x32_bf16(
                        af[fm], bf[fn], acc[fm][fn], 0, 0, 0);
        }
        __syncthreads();
    }

    // C/D layout: col = lane&15, row = (lane>>4)*4 + reg
#pragma unroll
    for (int fn = 0; fn < 2; ++fn) {
        const int col = n0 + wn * 32 + fn * 16 + (lane & 15);
        const float bv = bias[col];
#pragma unroll
        for (int fm = 0; fm < FM; ++fm) {
            const int rbase = m0 + wm * (FM * 16) + fm * 16 + (lane >> 4) * 4;
#pragma unroll
            for (int e = 0; e < 4; ++e) {
                const float v = acc[fm][fn][e] + bv;
                if (EPI == 0) {
                    unsigned short* h = (unsigned short*)outv;
                    h[(size_t)(rbase + e) * N + col] = f2bf(fmaxf(v, 0.f));
                } else {
                    float* out = (float*)outv;
                    const int p = col >> 10;
                    const int w = col & 1023;
                    out[(size_t)p * EDGES + (size_t)(rbase + e) * OUT_DIM + w] =
                        __expf(v);
                }
            }
        }
    }
}

// ==== scatter sections 0+1 combined: u64 record, block counting sort =======
// record = seg_low(11) << 32 | bf16(e0) << 16 | bf16(e1)
__global__ __launch_bounds__(256) void scatter01_sort_kernel(
    const int* __restrict__ idx, const float* __restrict__ v0,
    const float* __restrict__ v1, int w0,
    unsigned long long* __restrict__ P, unsigned* __restrict__ offs)
{
    __shared__ unsigned hist[BINS];
    __shared__ unsigned lofs[BINS];
    __shared__ unsigned scanbuf[256];
    __shared__ alignas(16) unsigned long long recs[SCHUNK];   // 32 KB

    const int tid = threadIdx.x;
    const int blk = blockIdx.x;
    const int base = w0 + blk * SCHUNK;

    for (int b = tid; b < BINS; b += 256) hist[b] = 0;
    __syncthreads();

    unsigned val_r[EPT];     // packed bf16(e0)<<16 | bf16(e1)
    unsigned meta_r[EPT];    // bin << 16 | seg_low
#pragma unroll
    for (int i = 0; i < EPT; ++i) {
        const int w = base + i * 256 + tid;
        const int seg = idx[w];
        const float e0 = v0[w];
        const float e1 = v1[w];
        const unsigned bin = (unsigned)seg >> 11;
        meta_r[i] = (bin << 16) | ((unsigned)seg & 2047u);
        val_r[i] = ((unsigned)f2bf(e0) << 16) | f2bf(e1);
        atomicAdd(&hist[bin], 1u);
    }
    __syncthreads();

    // exclusive scan over 512 bins (pairs per thread)
    const unsigned h0 = hist[2 * tid];
    const unsigned h1 = hist[2 * tid + 1];
    const unsigned pairsum = h0 + h1;
    scanbuf[tid] = pairsum;
    __syncthreads();
    for (int d = 1; d < 256; d <<= 1) {
        const unsigned v = (tid >= d) ? scanbuf[tid - d] : 0u;
        __syncthreads();
        scanbuf[tid] += v;
        __syncthreads();
    }
    const unsigned excl = scanbuf[tid] - pairsum;
    hist[2 * tid] = excl;
    hist[2 * tid + 1] = excl + h0;
    lofs[2 * tid] = 0;
    lofs[2 * tid + 1] = 0;
    offs[(size_t)blk * BINS + 2 * tid] = excl;
    offs[(size_t)blk * BINS + 2 * tid + 1] = excl + h0;
    __syncthreads();

#pragma unroll
    for (int i = 0; i < EPT; ++i) {
        const unsigned bin = meta_r[i] >> 16;
        const unsigned p = hist[bin] + atomicAdd(&lofs[bin], 1u);
        recs[p] = ((unsigned long long)(meta_r[i] & 2047u) << 32) | val_r[i];
    }
    __syncthreads();

    const ulonglong2* rs = reinterpret_cast<const ulonglong2*>(recs);
    ulonglong2* dst = reinterpret_cast<ulonglong2*>(&P[(size_t)blk * SCHUNK]);
#pragma unroll
    for (int i = 0; i < SCHUNK / 512; ++i)    // 8 iters of 16B stores
        dst[i * 256 + tid] = rs[i * 256 + tid];
}

// last pass writes per-section reciprocal tables r0, r1 (bf16 u16, 2 MiB each)
__global__ __launch_bounds__(256) void reduce01_sorted_kernel(
    const unsigned long long* __restrict__ P, const unsigned* __restrict__ offs,
    float2* __restrict__ s01, unsigned short* __restrict__ r0,
    unsigned short* __restrict__ r1, int last)
{
    __shared__ float sub0[SEGS_PER_BIN];
    __shared__ float sub1[SEGS_PER_BIN];
    const int b = blockIdx.x;
    const int tid = threadIdx.x;
    for (int i = tid; i < SEGS_PER_BIN; i += 256) { sub0[i] = 0.f; sub1[i] = 0.f; }
    __syncthreads();

    for (int blk = tid; blk < SBLOCKS; blk += 256) {
        const unsigned st = offs[(size_t)blk * BINS + b];
        const unsigned en =
            (b == BINS - 1) ? SCHUNK : offs[(size_t)blk * BINS + b + 1];
        const unsigned long long* rec = &P[(size_t)blk * SCHUNK];
        for (unsigned i = st; i < en; ++i) {
            const unsigned long long r = rec[i];
            const int sl = (int)(r >> 32);
            const unsigned lo = (unsigned)r;
            atomicAdd(&sub0[sl], __uint_as_float(lo & 0xffff0000u));
            atomicAdd(&sub1[sl], __uint_as_float(lo << 16));
        }
    }
    __syncthreads();

    for (int i = tid; i < SEGS_PER_BIN; i += 256) {
        const int seg = b * SEGS_PER_BIN + i;
        if (!last) {
            s01[seg] = make_float2(sub0[i], sub1[i]);
        } else {
            const float2 p = s01[seg];
            r0[seg] = f2bf(1.f / (sub0[i] + p.x));
            r1[seg] = f2bf(1.f / (sub1[i] + p.y));
        }
    }
}

// ==== section-2 scatter/reduce: u32 records ================================
__global__ __launch_bounds__(256) void scatter2_sort_kernel(
    const int* __restrict__ idx, const float* __restrict__ vals, int w0,
    unsigned* __restrict__ P, unsigned* __restrict__ offs)
{
    __shared__ unsigned hist[BINS];
    __shared__ unsigned lofs[BINS];
    __shared__ unsigned scanbuf[256];
    __shared__ alignas(16) unsigned recs[SCHUNK];   // 16 KB

    const int tid = threadIdx.x;
    const int blk = blockIdx.x;
    const int base = w0 + blk * SCHUNK;

    for (int b = tid; b < BINS; b += 256) hist[b] = 0;
    __syncthreads();

    unsigned rec_r[EPT];
    unsigned short bin_r[EPT];
#pragma unroll
    for (int i = 0; i < EPT; ++i) {
        const int w = base + i * 256 + tid;
        const int seg = idx[w];
        const float e = vals[w];
        bin_r[i] = (unsigned short)((unsigned)seg >> 11);
        rec_r[i] = (((unsigned)seg & 2047u) << 16) | f2bf(e);
        atomicAdd(&hist[bin_r[i]], 1u);
    }
    __syncthreads();

    const unsigned h0 = hist[2 * tid];
    const unsigned h1 = hist[2 * tid + 1];
    const unsigned pairsum = h0 + h1;
    scanbuf[tid] = pairsum;
    __syncthreads();
    for (int d = 1; d < 256; d <<= 1) {
        const unsigned v = (tid >= d) ? scanbuf[tid - d] : 0u;
        __syncthreads();
        scanbuf[tid] += v;
        __syncthreads();
    }
    const unsigned excl = scanbuf[tid] - pairsum;
    hist[2 * tid] = excl;
    hist[2 * tid + 1] = excl + h0;
    lofs[2 * tid] = 0;
    lofs[2 * tid + 1] = 0;
    offs[(size_t)blk * BINS + 2 * tid] = excl;
    offs[(size_t)blk * BINS + 2 * tid + 1] = excl + h0;
    __syncthreads();

#pragma unroll
    for (int i = 0; i < EPT; ++i) {
        const unsigned p = hist[bin_r[i]] + atomicAdd(&lofs[bin_r[i]], 1u);
        recs[p] = rec_r[i];
    }
    __syncthreads();

    const uint4* rs = reinterpret_cast<const uint4*>(recs);
    uint4* dst = reinterpret_cast<uint4*>(&P[(size_t)blk * SCHUNK]);
#pragma unroll
    for (int i = 0; i < SCHUNK / 1024; ++i)   // 4 iters
        dst[i * 256 + tid] = rs[i * 256 + tid];
}

__global__ __launch_bounds__(256) void reduce2_sorted_kernel(
    const unsigned* __restrict__ P, const unsigned* __restrict__ offs,
    float* __restrict__ s2, unsigned short* __restrict__ r2, int last)
{
    __shared__ float sub[SEGS_PER_BIN];
    const int b = blockIdx.x;
    const int tid = threadIdx.x;
    for (int i = tid; i < SEGS_PER_BIN; i += 256) sub[i] = 0.f;
    __syncthreads();

    for (int blk = tid; blk < SBLOCKS; blk += 256) {
        const unsigned st = offs[(size_t)blk * BINS + b];
        const unsigned en =
            (b == BINS - 1) ? SCHUNK : offs[(size_t)blk * BINS + b + 1];
        const unsigned* rec = &P[(size_t)blk * SCHUNK];
        for (unsigned i = st; i < en; ++i) {
            const unsigned r = rec[i];
            atomicAdd(&sub[r >> 16], __uint_as_float(r << 16));
        }
    }
    __syncthreads();

    for (int i = tid; i < SEGS_PER_BIN; i += 256) {
        const int seg = b * SEGS_PER_BIN + i;
        if (!last) s2[seg] = sub[i];
        else       r2[seg] = f2bf(1.f / (sub[i] + s2[seg]));
    }
}

// ============ normalize: one section per pass, 2 MiB table stays L2-hot ====
__global__ __launch_bounds__(256) void segdiv_sec_kernel(
    float* __restrict__ vals, const int* __restrict__ idx,
    const unsigned short* __restrict__ rtab)
{
    const int w4 = (blockIdx.x * 256 + threadIdx.x) * 4;
    if (w4 >= EDGES) return;
    const i32x4 iv = *reinterpret_cast<const i32x4*>(&idx[w4]);
    f32x4 a = *reinterpret_cast<const f32x4*>(&vals[w4]);
#pragma unroll
    for (int j = 0; j < 4; ++j) a[j] *= bf2f(rtab[iv[j]]);
    *reinterpret_cast<f32x4*>(&vals[w4]) = a;
}

// ===========================================================================
extern "C" void kernel_launch(void* const* d_in, const int* in_sizes, int n_in,
                              void* d_out, int out_size, void* d_ws,
                              size_t ws_size, hipStream_t stream) {
    const float* u2s = (const float*)d_in[0];
    const float* usr = (const float*)d_in[1];
    const float* srv = (const float*)d_in[2];
    const int* edge = (const int*)d_in[3];
    const float* W1 = (const float*)d_in[4];
    const float* b1 = (const float*)d_in[5];
    const float* W2 = (const float*)d_in[6];
    const float* b2 = (const float*)d_in[7];
    const float* W3 = (const float*)d_in[8];
    const float* b3 = (const float*)d_in[9];
    const float* W4 = (const float*)d_in[10];
    const float* b4 = (const float*)d_in[11];

    const int* idx0 = edge;
    const int* idx1 = edge + EDGES;

    // ws layout (peak 48 MiB; 48 MiB proven in round 1):
    //  phase1: F [0,19.9) | h1 [20,24) | h2 [24,28) | h3 [28,32) | wT [41,43.4)
    //  phase2: P [0,32) | offs [32,34) | s01 [34,42) | r0 [42,44) | r1 [44,46)
    //          r2 [46,48) | s2 [34,38) (aliases s01 once dead)
    char* ws = (char*)d_ws;
    unsigned short* F = (unsigned short*)ws;
    unsigned short* h1 = (unsigned short*)(ws + 20ull * 1024 * 1024);
    unsigned short* h2 = (unsigned short*)(ws + 24ull * 1024 * 1024);
    unsigned short* h3 = (unsigned short*)(ws + 28ull * 1024 * 1024);
    unsigned short* w1t = (unsigned short*)(ws + 41ull * 1024 * 1024);
    unsigned short* w2t = w1t + (size_t)HID * KPAD1;
    unsigned short* w3t = w2t + (size_t)HID * HID;
    unsigned short* w4t = w3t + (size_t)HID * HID;

    unsigned long long* P64 = (unsigned long long*)ws;
    unsigned* P32 = (unsigned*)ws;
    unsigned* offs = (unsigned*)(ws + 32ull * 1024 * 1024);
    float2* s01 = (float2*)(ws + 34ull * 1024 * 1024);
    float* s2 = (float*)(ws + 34ull * 1024 * 1024);      // aliases dead s01
    unsigned short* r0 = (unsigned short*)(ws + 42ull * 1024 * 1024);
    unsigned short* r1 = (unsigned short*)(ws + 44ull * 1024 * 1024);
    unsigned short* r2 = (unsigned short*)(ws + 46ull * 1024 * 1024);

    float* outp = (float*)d_out;
    const dim3 blk(256);

    // ---- prep: conversions (2 launches) ----
    convert_feats_kernel<<<(B_GRAPHS * 152) / 256, blk, 0, stream>>>(u2s, usr,
                                                                     srv, F);
    convert_wT_all_kernel<<<(WT_TOTAL + 255) / 256, blk, 0, stream>>>(
        W1, W2, W3, W4, w1t, w2t, w3t, w4t);

    // ---- MLP (bf16 MFMA, global_load_lds staging) ----
    // gemm1-3: BM=64 (FM=2) -> 512 blocks, 2/CU; gemm4: BM=128 (FM=4)
    gemm_bf16_kernel<2, 0><<<dim3(HID / 64, B_GRAPHS / 64), blk, 0, stream>>>(
        F, w1t, b1, h1, HID, KPAD1);
    gemm_bf16_kernel<2, 0><<<dim3(HID / 64, B_GRAPHS / 64), blk, 0, stream>>>(
        h1, w2t, b2, h2, HID, HID);
    gemm_bf16_kernel<2, 0><<<dim3(HID / 64, B_GRAPHS / 64), blk, 0, stream>>>(
        h2, w3t, b3, h3, HID, HID);
    gemm_bf16_kernel<4, 1><<<dim3(3 * OUT_DIM / 64, B_GRAPHS / 128), blk, 0,
                             stream>>>(h3, w4t, b4, outp, 3 * OUT_DIM, HID);

    // ---- segment sums ----
    // sections 0+1 (idx0, u64 records): 2 halves; last reduce writes r0,r1
    for (int h = 0; h < 2; ++h) {
        scatter01_sort_kernel<<<SBLOCKS, blk, 0, stream>>>(
            idx0, outp, outp + (size_t)EDGES, h * HALF, P64, offs);
        reduce01_sorted_kernel<<<BINS, blk, 0, stream>>>(P64, offs, s01, r0,
                                                         r1, h);
    }
    // section 2 (idx1, u32 records): 2 halves; last reduce writes r2
    for (int h = 0; h < 2; ++h) {
        scatter2_sort_kernel<<<SBLOCKS, blk, 0, stream>>>(
            idx1, outp + 2 * (size_t)EDGES, h * HALF, P32, offs);
        reduce2_sorted_kernel<<<BINS, blk, 0, stream>>>(P32, offs, s2, r2, h);
    }

    // ---- normalize: one pass per section, each table fits one L2 ----
    segdiv_sec_kernel<<<EDGES / 1024, blk, 0, stream>>>(outp, idx0, r0);
    segdiv_sec_kernel<<<EDGES / 1024, blk, 0, stream>>>(outp + (size_t)EDGES,
                                                        idx0, r1);
    segdiv_sec_kernel<<<EDGES / 1024, blk, 0, stream>>>(
        outp + 2 * (size_t)EDGES, idx1, r2);
}

// Round 17
// 419.499 us; speedup vs baseline: 1.8357x; 1.0088x over previous
//
#include <hip/hip_runtime.h>
#include <math.h>

#define B_GRAPHS 8192
#define OUT_DIM 1024
#define NU 128
#define NS 8
#define IN_DIM 1160          // OUT_DIM + NU + NS
#define KPAD1 1216           // IN_DIM padded to multiple of 64
#define HID 256
#define NSEG (B_GRAPHS * NU)        // 1048576 = 2^20
#define EDGES (B_GRAPHS * OUT_DIM)  // 8388608 = 2^23

// ---- binning parameters ----
#define BINS 512                    // seg >> 11
#define SEGS_PER_BIN 2048
#define HALF (EDGES / 2)            // 4194304 edges per pass
#define SCHUNK 4096                 // edges per scatter block -> 1024 blocks
#define SBLOCKS (HALF / SCHUNK)     // 1024
#define EPT (SCHUNK / 256)          // 16 edges per thread
#define VPT (EPT / 4)               // 4 vector(x4) iterations per thread

typedef __attribute__((ext_vector_type(8))) short short8;
typedef __attribute__((ext_vector_type(4))) float f32x4;
typedef __attribute__((ext_vector_type(4))) int i32x4;

__device__ __forceinline__ unsigned short f2bf(float f) {
    unsigned u = __float_as_uint(f);
    const unsigned r = (u >> 16) & 1u;
    return (unsigned short)((u + 0x7fffu + r) >> 16);   // RNE
}
__device__ __forceinline__ float bf2f(unsigned short b) {
    return __uint_as_float((unsigned)b << 16);
}

// async global->LDS direct load, 16B per lane (wave-linear LDS dest)
__device__ __forceinline__ void gload_lds16(const void* g, void* l) {
    __builtin_amdgcn_global_load_lds(
        (const __attribute__((address_space(1))) unsigned int*)g,
        (__attribute__((address_space(3))) unsigned int*)l, 16, 0, 0);
}

// ================= prep: fp32 -> bf16 conversions ==========================
__global__ __launch_bounds__(256) void convert_feats_kernel(
    const float* __restrict__ u2s, const float* __restrict__ usr,
    const float* __restrict__ srv, unsigned short* __restrict__ F)
{
    const int t = blockIdx.x * 256 + threadIdx.x;   // 8192*152 threads
    const int row = t / 152;
    const int g = t - row * 152;
    const int col = g * 8;
    float v[8];
    if (g < 128) {
        const float4 a = *(const float4*)&u2s[(size_t)row * OUT_DIM + col];
        const float4 b = *(const float4*)&u2s[(size_t)row * OUT_DIM + col + 4];
        v[0]=a.x; v[1]=a.y; v[2]=a.z; v[3]=a.w; v[4]=b.x; v[5]=b.y; v[6]=b.z; v[7]=b.w;
    } else if (g < 144) {
        const int c = col - OUT_DIM;
        const float4 a = *(const float4*)&usr[(size_t)row * NU + c];
        const float4 b = *(const float4*)&usr[(size_t)row * NU + c + 4];
        v[0]=a.x; v[1]=a.y; v[2]=a.z; v[3]=a.w; v[4]=b.x; v[5]=b.y; v[6]=b.z; v[7]=b.w;
    } else if (g == 144) {
        const float4 a = *(const float4*)&srv[(size_t)row * NS];
        const float4 b = *(const float4*)&srv[(size_t)row * NS + 4];
        v[0]=a.x; v[1]=a.y; v[2]=a.z; v[3]=a.w; v[4]=b.x; v[5]=b.y; v[6]=b.z; v[7]=b.w;
    } else {
        for (int i = 0; i < 8; ++i) v[i] = 0.f;
    }
    unsigned short o[8];
    for (int i = 0; i < 8; ++i) o[i] = f2bf(v[i]);
    *reinterpret_cast<short8*>(&F[(size_t)row * KPAD1 + col]) =
        *reinterpret_cast<const short8*>(o);
}

// all four W[K][N] -> WT[N][Kpad] conversions in one launch
#define W1_ELEMS (HID * KPAD1)            // 311296
#define W23_ELEMS (HID * HID)             // 65536
#define W4_ELEMS (3 * OUT_DIM * HID)      // 786432
#define WT_TOTAL (W1_ELEMS + 2 * W23_ELEMS + W4_ELEMS)   // 1228800

__global__ __launch_bounds__(256) void convert_wT_all_kernel(
    const float* __restrict__ W1, const float* __restrict__ W2,
    const float* __restrict__ W3, const float* __restrict__ W4,
    unsigned short* __restrict__ w1t, unsigned short* __restrict__ w2t,
    unsigned short* __restrict__ w3t, unsigned short* __restrict__ w4t)
{
    int t = blockIdx.x * 256 + threadIdx.x;
    if (t >= WT_TOTAL) return;
    const float* W;
    unsigned short* WT;
    int K, N, Kpad;
    if (t < W1_ELEMS) {
        W = W1; WT = w1t; K = IN_DIM; N = HID; Kpad = KPAD1;
    } else if (t < W1_ELEMS + W23_ELEMS) {
        t -= W1_ELEMS;
        W = W2; WT = w2t; K = HID; N = HID; Kpad = HID;
    } else if (t < W1_ELEMS + 2 * W23_ELEMS) {
        t -= W1_ELEMS + W23_ELEMS;
        W = W3; WT = w3t; K = HID; N = HID; Kpad = HID;
    } else {
        t -= W1_ELEMS + 2 * W23_ELEMS;
        W = W4; WT = w4t; K = HID; N = 3 * OUT_DIM; Kpad = HID;
    }
    const int n = t / Kpad;
    const int k = t - n * Kpad;
    WT[t] = (k < K) ? f2bf(W[(size_t)k * N + n]) : (unsigned short)0;
}

// ================= bf16 MFMA GEMM + global_load_lds staging ================
// BM = FM*32. BN=64, 4 waves (2x2), wave computes (FM*16) x 32 via acc[FM][2].
template <int FM, int EPI>
__global__ __launch_bounds__(256) void gemm_bf16_kernel(
    const unsigned short* __restrict__ A, const unsigned short* __restrict__ BT,
    const float* __restrict__ bias, void* __restrict__ outv, int N, int K)
{
    __shared__ alignas(16) unsigned short As[FM * 32 * 64];
    __shared__ alignas(16) unsigned short Bs[64 * 64];

    const int tid = threadIdx.x;
    const int lane = tid & 63;
    const int wid = tid >> 6;
    const int wm = wid >> 1;
    const int wn = wid & 1;
    const int m0 = blockIdx.y * (FM * 32);
    const int n0 = blockIdx.x * 64;

    const int srow = lane >> 3;
    const int schunk = lane & 7;
    const int sswz = schunk ^ srow;

    f32x4 acc[FM][2];
#pragma unroll
    for (int i = 0; i < FM; ++i)
#pragma unroll
        for (int j = 0; j < 2; ++j) acc[i][j] = (f32x4)0.f;

    for (int k0 = 0; k0 < K; k0 += 64) {
#pragma unroll
        for (int i = 0; i < FM; ++i) {
            const int r = wid * (FM * 8) + i * 8 + srow;
            gload_lds16(&A[(size_t)(m0 + r) * K + k0 + sswz * 8],
                        &As[(wid * (FM * 8) + i * 8) * 64]);
        }
#pragma unroll
        for (int i = 0; i < 2; ++i) {
            const int r = wid * 16 + i * 8 + srow;
            gload_lds16(&BT[(size_t)(n0 + r) * K + k0 + sswz * 8],
                        &Bs[(wid * 16 + i * 8) * 64]);
        }
        __syncthreads();

#pragma unroll
        for (int ks = 0; ks < 2; ++ks) {
            short8 af[FM], bf[2];
            const int c = ks * 4 + (lane >> 4);
#pragma unroll
            for (int fm = 0; fm < FM; ++fm) {
                const int r = wm * (FM * 16) + fm * 16 + (lane & 15);
                af[fm] = *reinterpret_cast<const short8*>(
                    &As[r * 64 + (c ^ (r & 7)) * 8]);
            }
#pragma unroll
            for (int fn = 0; fn < 2; ++fn) {
                const int r = wn * 32 + fn * 16 + (lane & 15);
                bf[fn] = *reinterpret_cast<const short8*>(
                    &Bs[r * 64 + (c ^ (r & 7)) * 8]);
            }
#pragma unroll
            for (int fm = 0; fm < FM; ++fm)
#pragma unroll
                for (int fn = 0; fn < 2; ++fn)
                    acc[fm][fn] = __builtin_amdgcn_mfma_f32_16x16x32_bf16(
                        af[fm], bf[fn], acc[fm][fn], 0, 0, 0);
        }
        __syncthreads();
    }

    // C/D layout: col = lane&15, row = (lane>>4)*4 + reg
#pragma unroll
    for (int fn = 0; fn < 2; ++fn) {
        const int col = n0 + wn * 32 + fn * 16 + (lane & 15);
        const float bv = bias[col];
#pragma unroll
        for (int fm = 0; fm < FM; ++fm) {
            const int rbase = m0 + wm * (FM * 16) + fm * 16 + (lane >> 4) * 4;
#pragma unroll
            for (int e = 0; e < 4; ++e) {
                const float v = acc[fm][fn][e] + bv;
                if (EPI == 0) {
                    unsigned short* h = (unsigned short*)outv;
                    h[(size_t)(rbase + e) * N + col] = f2bf(fmaxf(v, 0.f));
                } else {
                    float* out = (float*)outv;
                    const int p = col >> 10;
                    const int w = col & 1023;
                    out[(size_t)p * EDGES + (size_t)(rbase + e) * OUT_DIM + w] =
                        __expf(v);
                }
            }
        }
    }
}

// ==== scatter sections 0+1 combined: u64 record, block counting sort =======
// record = seg_low(11) << 32 | bf16(e0) << 16 | bf16(e1)
// Vectorized front-end: thread loads i32x4/f32x4 (4 consecutive edges).
__global__ __launch_bounds__(256) void scatter01_sort_kernel(
    const int* __restrict__ idx, const float* __restrict__ v0,
    const float* __restrict__ v1, int w0,
    unsigned long long* __restrict__ P, unsigned* __restrict__ offs)
{
    __shared__ unsigned hist[BINS];
    __shared__ unsigned lofs[BINS];
    __shared__ unsigned scanbuf[256];
    __shared__ alignas(16) unsigned long long recs[SCHUNK];   // 32 KB

    const int tid = threadIdx.x;
    const int blk = blockIdx.x;
    const int base = w0 + blk * SCHUNK;

    for (int b = tid; b < BINS; b += 256) hist[b] = 0;
    __syncthreads();

    unsigned val_r[EPT];     // packed bf16(e0)<<16 | bf16(e1)
    unsigned meta_r[EPT];    // bin << 16 | seg_low
#pragma unroll
    for (int vv = 0; vv < VPT; ++vv) {
        const int w = base + vv * 1024 + tid * 4;
        const i32x4 sv = *reinterpret_cast<const i32x4*>(&idx[w]);
        const f32x4 e0v = *reinterpret_cast<const f32x4*>(&v0[w]);
        const f32x4 e1v = *reinterpret_cast<const f32x4*>(&v1[w]);
#pragma unroll
        for (int j = 0; j < 4; ++j) {
            const unsigned seg = (unsigned)sv[j];
            const unsigned bin = seg >> 11;
            meta_r[vv * 4 + j] = (bin << 16) | (seg & 2047u);
            val_r[vv * 4 + j] = ((unsigned)f2bf(e0v[j]) << 16) | f2bf(e1v[j]);
            atomicAdd(&hist[bin], 1u);
        }
    }
    __syncthreads();

    // exclusive scan over 512 bins (pairs per thread)
    const unsigned h0 = hist[2 * tid];
    const unsigned h1 = hist[2 * tid + 1];
    const unsigned pairsum = h0 + h1;
    scanbuf[tid] = pairsum;
    __syncthreads();
    for (int d = 1; d < 256; d <<= 1) {
        const unsigned v = (tid >= d) ? scanbuf[tid - d] : 0u;
        __syncthreads();
        scanbuf[tid] += v;
        __syncthreads();
    }
    const unsigned excl = scanbuf[tid] - pairsum;
    hist[2 * tid] = excl;
    hist[2 * tid + 1] = excl + h0;
    lofs[2 * tid] = 0;
    lofs[2 * tid + 1] = 0;
    offs[(size_t)blk * BINS + 2 * tid] = excl;
    offs[(size_t)blk * BINS + 2 * tid + 1] = excl + h0;
    __syncthreads();

#pragma unroll
    for (int i = 0; i < EPT; ++i) {
        const unsigned bin = meta_r[i] >> 16;
        const unsigned p = hist[bin] + atomicAdd(&lofs[bin], 1u);
        recs[p] = ((unsigned long long)(meta_r[i] & 2047u) << 32) | val_r[i];
    }
    __syncthreads();

    const ulonglong2* rs = reinterpret_cast<const ulonglong2*>(recs);
    ulonglong2* dst = reinterpret_cast<ulonglong2*>(&P[(size_t)blk * SCHUNK]);
#pragma unroll
    for (int i = 0; i < SCHUNK / 512; ++i)    // 8 iters of 16B stores
        dst[i * 256 + tid] = rs[i * 256 + tid];
}

// last pass writes per-section reciprocal tables r0, r1 (bf16 u16, 2 MiB each)
__global__ __launch_bounds__(256) void reduce01_sorted_kernel(
    const unsigned long long* __restrict__ P, const unsigned* __restrict__ offs,
    float2* __restrict__ s01, unsigned short* __restrict__ r0,
    unsigned short* __restrict__ r1, int last)
{
    __shared__ float sub0[SEGS_PER_BIN];
    __shared__ float sub1[SEGS_PER_BIN];
    const int b = blockIdx.x;
    const int tid = threadIdx.x;
    for (int i = tid; i < SEGS_PER_BIN; i += 256) { sub0[i] = 0.f; sub1[i] = 0.f; }
    __syncthreads();

    for (int blk = tid; blk < SBLOCKS; blk += 256) {
        const unsigned st = offs[(size_t)blk * BINS + b];
        const unsigned en =
            (b == BINS - 1) ? SCHUNK : offs[(size_t)blk * BINS + b + 1];
        const unsigned long long* rec = &P[(size_t)blk * SCHUNK];
        for (unsigned i = st; i < en; ++i) {
            const unsigned long long r = rec[i];
            const int sl = (int)(r >> 32);
            const unsigned lo = (unsigned)r;
            atomicAdd(&sub0[sl], __uint_as_float(lo & 0xffff0000u));
            atomicAdd(&sub1[sl], __uint_as_float(lo << 16));
        }
    }
    __syncthreads();

    for (int i = tid; i < SEGS_PER_BIN; i += 256) {
        const int seg = b * SEGS_PER_BIN + i;
        if (!last) {
            s01[seg] = make_float2(sub0[i], sub1[i]);
        } else {
            const float2 p = s01[seg];
            r0[seg] = f2bf(1.f / (sub0[i] + p.x));
            r1[seg] = f2bf(1.f / (sub1[i] + p.y));
        }
    }
}

// ==== section-2 scatter/reduce: u32 records ================================
__global__ __launch_bounds__(256) void scatter2_sort_kernel(
    const int* __restrict__ idx, const float* __restrict__ vals, int w0,
    unsigned* __restrict__ P, unsigned* __restrict__ offs)
{
    __shared__ unsigned hist[BINS];
    __shared__ unsigned lofs[BINS];
    __shared__ unsigned scanbuf[256];
    __shared__ alignas(16) unsigned recs[SCHUNK];   // 16 KB

    const int tid = threadIdx.x;
    const int blk = blockIdx.x;
    const int base = w0 + blk * SCHUNK;

    for (int b = tid; b < BINS; b += 256) hist[b] = 0;
    __syncthreads();

    unsigned rec_r[EPT];
    unsigned short bin_r[EPT];
#pragma unroll
    for (int vv = 0; vv < VPT; ++vv) {
        const int w = base + vv * 1024 + tid * 4;
        const i32x4 sv = *reinterpret_cast<const i32x4*>(&idx[w]);
        const f32x4 ev = *reinterpret_cast<const f32x4*>(&vals[w]);
#pragma unroll
        for (int j = 0; j < 4; ++j) {
            const unsigned seg = (unsigned)sv[j];
            bin_r[vv * 4 + j] = (unsigned short)(seg >> 11);
            rec_r[vv * 4 + j] = ((seg & 2047u) << 16) | f2bf(ev[j]);
            atomicAdd(&hist[seg >> 11], 1u);
        }
    }
    __syncthreads();

    const unsigned h0 = hist[2 * tid];
    const unsigned h1 = hist[2 * tid + 1];
    const unsigned pairsum = h0 + h1;
    scanbuf[tid] = pairsum;
    __syncthreads();
    for (int d = 1; d < 256; d <<= 1) {
        const unsigned v = (tid >= d) ? scanbuf[tid - d] : 0u;
        __syncthreads();
        scanbuf[tid] += v;
        __syncthreads();
    }
    const unsigned excl = scanbuf[tid] - pairsum;
    hist[2 * tid] = excl;
    hist[2 * tid + 1] = excl + h0;
    lofs[2 * tid] = 0;
    lofs[2 * tid + 1] = 0;
    offs[(size_t)blk * BINS + 2 * tid] = excl;
    offs[(size_t)blk * BINS + 2 * tid + 1] = excl + h0;
    __syncthreads();

#pragma unroll
    for (int i = 0; i < EPT; ++i) {
        const unsigned p = hist[bin_r[i]] + atomicAdd(&lofs[bin_r[i]], 1u);
        recs[p] = rec_r[i];
    }
    __syncthreads();

    const uint4* rs = reinterpret_cast<const uint4*>(recs);
    uint4* dst = reinterpret_cast<uint4*>(&P[(size_t)blk * SCHUNK]);
#pragma unroll
    for (int i = 0; i < SCHUNK / 1024; ++i)   // 4 iters
        dst[i * 256 + tid] = rs[i * 256 + tid];
}

__global__ __launch_bounds__(256) void reduce2_sorted_kernel(
    const unsigned* __restrict__ P, const unsigned* __restrict__ offs,
    float* __restrict__ s2, unsigned short* __restrict__ r2, int last)
{
    __shared__ float sub[SEGS_PER_BIN];
    const int b = blockIdx.x;
    const int tid = threadIdx.x;
    for (int i = tid; i < SEGS_PER_BIN; i += 256) sub[i] = 0.f;
    __syncthreads();

    for (int blk = tid; blk < SBLOCKS; blk += 256) {
        const unsigned st = offs[(size_t)blk * BINS + b];
        const unsigned en =
            (b == BINS - 1) ? SCHUNK : offs[(size_t)blk * BINS + b + 1];
        const unsigned* rec = &P[(size_t)blk * SCHUNK];
        for (unsigned i = st; i < en; ++i) {
            const unsigned r = rec[i];
            atomicAdd(&sub[r >> 16], __uint_as_float(r << 16));
        }
    }
    __syncthreads();

    for (int i = tid; i < SEGS_PER_BIN; i += 256) {
        const int seg = b * SEGS_PER_BIN + i;
        if (!last) s2[seg] = sub[i];
        else       r2[seg] = f2bf(1.f / (sub[i] + s2[seg]));
    }
}

// ============ normalize: one section per pass, 2 MiB table stays L2-hot ====
__global__ __launch_bounds__(256) void segdiv_sec_kernel(
    float* __restrict__ vals, const int* __restrict__ idx,
    const unsigned short* __restrict__ rtab)
{
    const int w4 = (blockIdx.x * 256 + threadIdx.x) * 4;
    if (w4 >= EDGES) return;
    const i32x4 iv = *reinterpret_cast<const i32x4*>(&idx[w4]);
    f32x4 a = *reinterpret_cast<const f32x4*>(&vals[w4]);
#pragma unroll
    for (int j = 0; j < 4; ++j) a[j] *= bf2f(rtab[iv[j]]);
    *reinterpret_cast<f32x4*>(&vals[w4]) = a;
}

// ===========================================================================
extern "C" void kernel_launch(void* const* d_in, const int* in_sizes, int n_in,
                              void* d_out, int out_size, void* d_ws,
                              size_t ws_size, hipStream_t stream) {
    const float* u2s = (const float*)d_in[0];
    const float* usr = (const float*)d_in[1];
    const float* srv = (const float*)d_in[2];
    const int* edge = (const int*)d_in[3];
    const float* W1 = (const float*)d_in[4];
    const float* b1 = (const float*)d_in[5];
    const float* W2 = (const float*)d_in[6];
    const float* b2 = (const float*)d_in[7];
    const float* W3 = (const float*)d_in[8];
    const float* b3 = (const float*)d_in[9];
    const float* W4 = (const float*)d_in[10];
    const float* b4 = (const float*)d_in[11];

    const int* idx0 = edge;
    const int* idx1 = edge + EDGES;

    // ws layout (peak 48 MiB; 48 MiB proven in round 1):
    //  phase1: F [0,19.9) | h1 [20,24) | h2 [24,28) | h3 [28,32) | wT [41,43.4)
    //  phase2: P [0,32) | offs [32,34) | s01 [34,42) | r0 [42,44) | r1 [44,46)
    //          r2 [46,48) | s2 [34,38) (aliases s01 once dead)
    char* ws = (char*)d_ws;
    unsigned short* F = (unsigned short*)ws;
    unsigned short* h1 = (unsigned short*)(ws + 20ull * 1024 * 1024);
    unsigned short* h2 = (unsigned short*)(ws + 24ull * 1024 * 1024);
    unsigned short* h3 = (unsigned short*)(ws + 28ull * 1024 * 1024);
    unsigned short* w1t = (unsigned short*)(ws + 41ull * 1024 * 1024);
    unsigned short* w2t = w1t + (size_t)HID * KPAD1;
    unsigned short* w3t = w2t + (size_t)HID * HID;
    unsigned short* w4t = w3t + (size_t)HID * HID;

    unsigned long long* P64 = (unsigned long long*)ws;
    unsigned* P32 = (unsigned*)ws;
    unsigned* offs = (unsigned*)(ws + 32ull * 1024 * 1024);
    float2* s01 = (float2*)(ws + 34ull * 1024 * 1024);
    float* s2 = (float*)(ws + 34ull * 1024 * 1024);      // aliases dead s01
    unsigned short* r0 = (unsigned short*)(ws + 42ull * 1024 * 1024);
    unsigned short* r1 = (unsigned short*)(ws + 44ull * 1024 * 1024);
    unsigned short* r2 = (unsigned short*)(ws + 46ull * 1024 * 1024);

    float* outp = (float*)d_out;
    const dim3 blk(256);

    // ---- prep: conversions (2 launches) ----
    convert_feats_kernel<<<(B_GRAPHS * 152) / 256, blk, 0, stream>>>(u2s, usr,
                                                                     srv, F);
    convert_wT_all_kernel<<<(WT_TOTAL + 255) / 256, blk, 0, stream>>>(
        W1, W2, W3, W4, w1t, w2t, w3t, w4t);

    // ---- MLP (bf16 MFMA, global_load_lds staging) ----
    gemm_bf16_kernel<2, 0><<<dim3(HID / 64, B_GRAPHS / 64), blk, 0, stream>>>(
        F, w1t, b1, h1, HID, KPAD1);
    gemm_bf16_kernel<2, 0><<<dim3(HID / 64, B_GRAPHS / 64), blk, 0, stream>>>(
        h1, w2t, b2, h2, HID, HID);
    gemm_bf16_kernel<2, 0><<<dim3(HID / 64, B_GRAPHS / 64), blk, 0, stream>>>(
        h2, w3t, b3, h3, HID, HID);
    gemm_bf16_kernel<4, 1><<<dim3(3 * OUT_DIM / 64, B_GRAPHS / 128), blk, 0,
                             stream>>>(h3, w4t, b4, outp, 3 * OUT_DIM, HID);

    // ---- segment sums ----
    // sections 0+1 (idx0, u64 records): 2 halves; last reduce writes r0,r1
    for (int h = 0; h < 2; ++h) {
        scatter01_sort_kernel<<<SBLOCKS, blk, 0, stream>>>(
            idx0, outp, outp + (size_t)EDGES, h * HALF, P64, offs);
        reduce01_sorted_kernel<<<BINS, blk, 0, stream>>>(P64, offs, s01, r0,
                                                         r1, h);
    }
    // section 2 (idx1, u32 records): 2 halves; last reduce writes r2
    for (int h = 0; h < 2; ++h) {
        scatter2_sort_kernel<<<SBLOCKS, blk, 0, stream>>>(
            idx1, outp + 2 * (size_t)EDGES, h * HALF, P32, offs);
        reduce2_sorted_kernel<<<BINS, blk, 0, stream>>>(P32, offs, s2, r2, h);
    }

    // ---- normalize: one pass per section, each table fits one L2 ----
    segdiv_sec_kernel<<<EDGES / 1024, blk, 0, stream>>>(outp, idx0, r0);
    segdiv_sec_kernel<<<EDGES / 1024, blk, 0, stream>>>(outp + (size_t)EDGES,
                                                        idx0, r1);
    segdiv_sec_kernel<<<EDGES / 1024, blk, 0, stream>>>(
        outp + 2 * (size_t)EDGES, idx1, r2);
}